// Round 4
// baseline (426.943 us; speedup 1.0000x reference)
//
#include <hip/hip_runtime.h>
#include <hip/hip_bf16.h>
#include <stdint.h>

typedef _Float16 f16;
typedef _Float16 f16x8 __attribute__((ext_vector_type(8)));
typedef _Float16 f16x4 __attribute__((ext_vector_type(4)));
typedef float f32x4 __attribute__((ext_vector_type(4)));

constexpr int B = 64, S = 197, HID = 768, NH = 12, DH = 64;
constexpr int M = B * S;          // 12608
constexpr int Mpad = 12672;       // 99*128
constexpr int BNS = B * NH * S;   // 151296
constexpr int VSTRIDE = 224;      // 7*32 >= 197
constexpr size_t NPH = (size_t)Mpad * HID;
constexpr size_t WSZ1 = (size_t)HID * HID;
constexpr size_t VTSZ = (size_t)B * NH * DH * VSTRIDE;

__device__ __forceinline__ f32x4 mfma16(f16x8 a, f16x8 b, f32x4 c) {
  return __builtin_amdgcn_mfma_f32_16x16x32_f16(a, b, c, 0, 0, 0);
}

__device__ __forceinline__ void gload16(const void* g, void* l) {
  __builtin_amdgcn_global_load_lds(
      (const __attribute__((address_space(1))) void*)g,
      (__attribute__((address_space(3))) void*)l, 16, 0, 0);
}

// bijective XCD-aware swizzle (m204)
__device__ __forceinline__ int xcd_swizzle(int wg, int nwg) {
  const int q = nwg >> 3, r = nwg & 7;
  const int x = wg & 7, p = wg >> 3;
  return (x < r ? x * (q + 1) : r * (q + 1) + (x - r) * q) + p;
}

// ---------------- zero fill (f16x8) ----------------
__global__ __launch_bounds__(256) void zero_kernel(f16* __restrict__ p, size_t n8) {
  const size_t i = (size_t)blockIdx.x * 256 + threadIdx.x;
  if (i < n8) reinterpret_cast<f16x8*>(p)[i] = f16x8{};
}

// ---------------- f32 -> f16 (padded, zero tail) ----------------
__global__ __launch_bounds__(256) void cvt_x_kernel(
    const float* __restrict__ xm, const float* __restrict__ xc,
    f16* __restrict__ ym, f16* __restrict__ yc) {
  const size_t i8 = ((size_t)blockIdx.x * 256 + threadIdx.x) * 8;
  f16x8 vm = {}, vc = {};
  if (i8 < (size_t)M * HID) {
    const float4 a0 = *reinterpret_cast<const float4*>(xm + i8);
    const float4 a1 = *reinterpret_cast<const float4*>(xm + i8 + 4);
    const float4 b0 = *reinterpret_cast<const float4*>(xc + i8);
    const float4 b1 = *reinterpret_cast<const float4*>(xc + i8 + 4);
    vm[0] = (f16)a0.x; vm[1] = (f16)a0.y; vm[2] = (f16)a0.z; vm[3] = (f16)a0.w;
    vm[4] = (f16)a1.x; vm[5] = (f16)a1.y; vm[6] = (f16)a1.z; vm[7] = (f16)a1.w;
    vc[0] = (f16)b0.x; vc[1] = (f16)b0.y; vc[2] = (f16)b0.z; vc[3] = (f16)b0.w;
    vc[4] = (f16)b1.x; vc[5] = (f16)b1.y; vc[6] = (f16)b1.z; vc[7] = (f16)b1.w;
  }
  *reinterpret_cast<f16x8*>(ym + i8) = vm;
  *reinterpret_cast<f16x8*>(yc + i8) = vc;
}

// ---------------- W [k][n] f32 -> Wt [n][k] f16 ----------------
struct WPtrs { const float* w[8]; };

__global__ __launch_bounds__(256) void cvt_w_kernel(WPtrs p, f16* __restrict__ wt) {
  __shared__ float tile[32][33];
  const int z = blockIdx.z;
  const float* W = p.w[z];
  f16* Wt = wt + (size_t)z * WSZ1;
  const int k0 = blockIdx.x * 32, n0 = blockIdx.y * 32;
  const int tx = threadIdx.x & 31, ty = threadIdx.x >> 5;
#pragma unroll
  for (int i = 0; i < 4; ++i)
    tile[ty + i * 8][tx] = W[(size_t)(k0 + ty + i * 8) * HID + n0 + tx];
  __syncthreads();
#pragma unroll
  for (int i = 0; i < 4; ++i)
    Wt[(size_t)(n0 + ty + i * 8) * HID + k0 + tx] = (f16)tile[tx][ty + i * 8];
}

// ---------------- shared MFMA GEMM core (128x128 tile, K=768) -------------
// global_load_lds staging, linear LDS + inverse-swizzled source, dbuf,
// counted vmcnt (T4): next-tile loads stay in flight across the barrier.
__device__ __forceinline__ void gemm_core(
    const f16* __restrict__ Abase, const f16* __restrict__ Btbase,
    int m0, int n0, int tid, char (*lds)[16384], f32x4 (&acc)[4][4]) {
  const int w = tid >> 6, lane = tid & 63;
  const int l15 = lane & 15, lg = lane >> 4;
  const int wr = (w >> 1) * 64, wc = (w & 1) * 64;
  const int srow = w * 32 + (lane >> 3);
  const int scb = ((lane & 7) * 16) ^ ((srow & 7) << 4);
  const char* gA = reinterpret_cast<const char*>(Abase + (size_t)(m0 + srow) * HID) + scb;
  const char* gB = reinterpret_cast<const char*>(Btbase + (size_t)(n0 + srow) * HID) + scb;

  // prologue: stage kt=0 into buf0
#pragma unroll
  for (int i = 0; i < 4; ++i) {
    gload16(gA + (size_t)i * 8 * 1536, lds[0] + w * 4096 + i * 1024);
    gload16(gB + (size_t)i * 8 * 1536, lds[1] + w * 4096 + i * 1024);
  }

  int cur = 0;
  for (int kt = 0; kt < 12; ++kt) {
    if (kt + 1 < 12) {  // stage next tile; keep its 8 loads in flight
      const size_t off = (size_t)(kt + 1) * 128;
#pragma unroll
      for (int i = 0; i < 4; ++i) {
        gload16(gA + off + (size_t)i * 8 * 1536, lds[2 - 2 * cur] + w * 4096 + i * 1024);
        gload16(gB + off + (size_t)i * 8 * 1536, lds[3 - 2 * cur] + w * 4096 + i * 1024);
      }
      // wait only for current tile's 8 loads (issued last iter); 8 newest in flight
      asm volatile("s_waitcnt vmcnt(8)\n\ts_barrier" ::: "memory");
    } else {
      asm volatile("s_waitcnt vmcnt(0)\n\ts_barrier" ::: "memory");
    }
    const char* cA = lds[2 * cur];
    const char* cB = lds[2 * cur + 1];
#pragma unroll
    for (int ks = 0; ks < 2; ++ks) {
      f16x8 af[4], bf[4];
#pragma unroll
      for (int fi = 0; fi < 4; ++fi) {
        const int row = wr + l15 + fi * 16;
        af[fi] = *reinterpret_cast<const f16x8*>(
            cA + row * 128 + ((ks * 64 + lg * 16) ^ ((row & 7) << 4)));
      }
#pragma unroll
      for (int fj = 0; fj < 4; ++fj) {
        const int row = wc + l15 + fj * 16;
        bf[fj] = *reinterpret_cast<const f16x8*>(
            cB + row * 128 + ((ks * 64 + lg * 16) ^ ((row & 7) << 4)));
      }
#pragma unroll
      for (int fi = 0; fi < 4; ++fi)
#pragma unroll
        for (int fj = 0; fj < 4; ++fj)
          acc[fi][fj] = mfma16(af[fi], bf[fj], acc[fi][fj]);
    }
    // all my LDS reads retired; then block-wide barrier so next iter's
    // gloads may overwrite this buffer. NO vmcnt drain here.
    asm volatile("s_waitcnt lgkmcnt(0)\n\ts_barrier" ::: "memory");
    cur ^= 1;
  }
}

// ---------------- projection GEMMs (z=0 mean, z=1 cov) ----------------
struct ProjArgs {
  const f16* A[2]; const f16* Bt[2];
  const float* bias[2][3];
  f16* out0[2];  // nsel 0: mq / sq   (scaled 0.5)
  f16* out1[2];  // nsel 1: mk / sk   (scaled 0.5)
  f16* vt[2];    // nsel 2: Vt mean / cov (transposed, unscaled)
};

__global__ __launch_bounds__(256, 2) void gemm_proj(ProjArgs g) {
  __shared__ char lds[4][16384];
  const int swz = xcd_swizzle(blockIdx.x, 99 * 18 * 2);
  const int x = swz % 99;
  const int t = swz / 99;
  const int y = t % 18, z = t / 18;
  const int m0 = x * 128, n0 = y * 128;

  f32x4 acc[4][4] = {};
  gemm_core(g.A[z], g.Bt[z], m0, n0, threadIdx.x, lds, acc);

  const int tid = threadIdx.x, w = tid >> 6, lane = tid & 63;
  const int l15 = lane & 15, lg = lane >> 4;
  const int wr = (w >> 1) * 64, wc = (w & 1) * 64;
  const int nsel = n0 / 768;
  const int ncol0 = (n0 - nsel * 768) + wc + l15;
  const int rbase = m0 + wr + lg * 4;
  const float* bias = g.bias[z][nsel];

  if (nsel < 2) {
    f16* Y = nsel ? g.out1[z] : g.out0[z];
#pragma unroll
    for (int fj = 0; fj < 4; ++fj) {
      const int col = ncol0 + fj * 16;
      const float bv = bias[col];
#pragma unroll
      for (int fi = 0; fi < 4; ++fi)
#pragma unroll
        for (int r = 0; r < 4; ++r) {
          const int row = rbase + fi * 16 + r;
          float v = acc[fi][fj][r] + bv;
          if (z == 1) { v = (v > 0.f) ? v + 1.f : __expf(v); v = sqrtf(v); }
          Y[(size_t)row * HID + col] = (f16)(v * 0.5f);
        }
    }
  } else {
    f16* VT = g.vt[z];
#pragma unroll
    for (int fj = 0; fj < 4; ++fj) {
      const int col = ncol0 + fj * 16;
      const float bv = bias[col];
      const int h = col >> 6, d = col & 63;
#pragma unroll
      for (int fi = 0; fi < 4; ++fi)
#pragma unroll
        for (int r = 0; r < 4; ++r) {
          const int row = rbase + fi * 16 + r;
          if (row < M) {
            float v = acc[fi][fj][r] + bv;
            if (z == 1) v = (v > 0.f) ? v + 1.f : __expf(v);
            const int bb = row / S, ss = row - bb * S;
            VT[((size_t)(bb * NH + h) * DH + d) * VSTRIDE + ss] = (f16)v;
          }
        }
    }
  }
}

// ---------------- output GEMMs (z=0 mean, z=1 cov), f32 out ---------------
struct OutArgs {
  const f16* A[2]; const f16* Bt[2]; const float* bias[2]; float* Y[2];
};

__global__ __launch_bounds__(256, 2) void gemm_out(OutArgs g) {
  __shared__ char lds[4][16384];
  const int swz = xcd_swizzle(blockIdx.x, 99 * 6 * 2);
  const int x = swz % 99;
  const int t = swz / 99;
  const int y = t % 6, z = t / 6;
  const int m0 = x * 128, n0 = y * 128;

  f32x4 acc[4][4] = {};
  gemm_core(g.A[z], g.Bt[z], m0, n0, threadIdx.x, lds, acc);

  const int tid = threadIdx.x, w = tid >> 6, lane = tid & 63;
  const int l15 = lane & 15, lg = lane >> 4;
  const int wr = (w >> 1) * 64, wc = (w & 1) * 64;
  const int rbase = m0 + wr + lg * 4;
  float* Y = g.Y[z];
#pragma unroll
  for (int fj = 0; fj < 4; ++fj) {
    const int col = n0 + wc + l15 + fj * 16;
    const float bv = g.bias[z][col];
#pragma unroll
    for (int fi = 0; fi < 4; ++fi)
#pragma unroll
      for (int r = 0; r < 4; ++r) {
        const int row = rbase + fi * 16 + r;
        if (row < M) Y[(size_t)row * HID + col] = acc[fi][fj][r] + bv;
      }
  }
}

// -------- per-(b,h,s) terms (inputs pre-scaled by 0.5) --------
__global__ __launch_bounds__(256) void sums_kernel(
    const f16* __restrict__ mq, const f16* __restrict__ sq,
    const f16* __restrict__ mk, const f16* __restrict__ sk,
    float* __restrict__ qterm, float* __restrict__ kterm) {
  const int w = threadIdx.x >> 6, lane = threadIdx.x & 63;
  const int t = blockIdx.x * 4 + w;
  const int b = t / (NH * S);
  const int rem = t - b * (NH * S);
  const int h = rem / S;
  const int s = rem - h * S;
  const size_t idx = (size_t)(b * S + s) * HID + h * DH + lane;
  const float a1 = (float)mq[idx], a2 = (float)sq[idx];
  const float a3 = (float)mk[idx], a4 = (float)sk[idx];
  float vq = a1 * a1 + a2 * a2;
  float vk = a3 * a3 + a4 * a4;
#pragma unroll
  for (int off = 32; off; off >>= 1) {
    vq += __shfl_down(vq, off, 64);
    vk += __shfl_down(vk, off, 64);
  }
  if (lane == 0) { qterm[t] = 0.5f * vq; kterm[t] = 0.5f * vk; }
}

// ---------------- fused Wasserstein attention ----------------
__global__ __launch_bounds__(256, 2) void attn_kernel(
    const f16* __restrict__ mq, const f16* __restrict__ sq,
    const f16* __restrict__ mk, const f16* __restrict__ sk,
    const f16* __restrict__ vtm, const f16* __restrict__ vtc,
    const float* __restrict__ qterm, const float* __restrict__ kterm,
    f16* __restrict__ mean_ctx, f16* __restrict__ cov_ctx) {
  __shared__ char Pb[64 * 512];  // P[q][j] f16, XOR-swizzled rows
  __shared__ float qt_s[64];
  __shared__ float kt_s[256];
  __shared__ float red_m[4][64];
  __shared__ float red_s[4][64];

  const int swz = xcd_swizzle(blockIdx.x, 3072);
  const int qtile = swz & 3, bh = swz >> 2;
  const int h = bh % NH, b = bh / NH;
  const int s0 = qtile * 64;
  const int tid = threadIdx.x, w = tid >> 6, lane = tid & 63;
  const int l15 = lane & 15, lg = lane >> 4;

  const size_t base = (size_t)(b * S) * HID + (size_t)h * DH;
  const int tb = bh * S;

  // Q fragments (B-operand): row = s0+fi*16+l15, k = lg*8 (+32)
  f16x8 qmf[4][2], qsf[4][2];
#pragma unroll
  for (int fi = 0; fi < 4; ++fi) {
    const size_t o = base + (size_t)(s0 + fi * 16 + l15) * HID + lg * 8;
    qmf[fi][0] = *reinterpret_cast<const f16x8*>(mq + o);
    qmf[fi][1] = *reinterpret_cast<const f16x8*>(mq + o + 32);
    qsf[fi][0] = *reinterpret_cast<const f16x8*>(sq + o);
    qsf[fi][1] = *reinterpret_cast<const f16x8*>(sq + o + 32);
  }
  if (tid < 64) qt_s[tid] = (s0 + tid < S) ? qterm[tb + s0 + tid] : 0.f;
  kt_s[tid] = (tid < S) ? kterm[tb + tid] : 0.f;
  __syncthreads();

  // scores^T: acc[fj][fi], rows = K tokens (wave-owned 64), cols = Q tokens
  f32x4 acc[4][4] = {};
  __builtin_amdgcn_s_setprio(1);
#pragma unroll
  for (int fj = 0; fj < 4; ++fj) {
    const size_t o = base + (size_t)(w * 64 + fj * 16 + l15) * HID + lg * 8;
    const f16x8 a0 = *reinterpret_cast<const f16x8*>(mk + o);
    const f16x8 a1 = *reinterpret_cast<const f16x8*>(mk + o + 32);
    const f16x8 c0 = *reinterpret_cast<const f16x8*>(sk + o);
    const f16x8 c1 = *reinterpret_cast<const f16x8*>(sk + o + 32);
#pragma unroll
    for (int fi = 0; fi < 4; ++fi) {
      acc[fj][fi] = mfma16(a0, qmf[fi][0], acc[fj][fi]);
      acc[fj][fi] = mfma16(c0, qsf[fi][0], acc[fj][fi]);
      acc[fj][fi] = mfma16(a1, qmf[fi][1], acc[fj][fi]);
      acc[fj][fi] = mfma16(c1, qsf[fi][1], acc[fj][fi]);
    }
  }
  __builtin_amdgcn_s_setprio(0);

  // issue Vt loads early (independent of softmax) -> registers
  const int d = w * 16 + l15;
  const size_t vbase = ((size_t)bh * DH + d) * VSTRIDE + lg * 8;
  f16x8 vmr[7], vcr[7];
#pragma unroll
  for (int ks = 0; ks < 7; ++ks) {
    vmr[ks] = *reinterpret_cast<const f16x8*>(vtm + vbase + ks * 32);
    vcr[ks] = *reinterpret_cast<const f16x8*>(vtc + vbase + ks * 32);
  }

  // transform + wave-partial row max (reduce over j: lanes differing in lg)
#pragma unroll
  for (int fi = 0; fi < 4; ++fi) {
    const float qv = qt_s[fi * 16 + l15];
    float mx = -1e30f;
#pragma unroll
    for (int fj = 0; fj < 4; ++fj)
#pragma unroll
      for (int r = 0; r < 4; ++r) {
        const int j = w * 64 + fj * 16 + lg * 4 + r;
        float sv = acc[fj][fi][r] - qv - kt_s[j];
        if (j >= S) sv = -1e30f;
        acc[fj][fi][r] = sv;
        mx = fmaxf(mx, sv);
      }
    mx = fmaxf(mx, __shfl_xor(mx, 16, 64));
    mx = fmaxf(mx, __shfl_xor(mx, 32, 64));
    if (lg == 0) red_m[w][fi * 16 + l15] = mx;
  }
  __syncthreads();

  // exp (unnormalized) -> P (b64 writes), partial sums
#pragma unroll
  for (int fi = 0; fi < 4; ++fi) {
    const int q = fi * 16 + l15;
    const float m = fmaxf(fmaxf(red_m[0][q], red_m[1][q]),
                          fmaxf(red_m[2][q], red_m[3][q]));
    const int xr = (q & 7) << 4;
    float sum = 0.f;
#pragma unroll
    for (int fj = 0; fj < 4; ++fj) {
      f16x4 p4;
#pragma unroll
      for (int r = 0; r < 4; ++r) {
        const float e = __expf(acc[fj][fi][r] - m);
        sum += e;
        p4[r] = (f16)e;
      }
      *reinterpret_cast<f16x4*>(
          Pb + q * 512 + ((2 * (w * 64 + fj * 16 + lg * 4)) ^ xr)) = p4;
    }
    sum += __shfl_xor(sum, 16, 64);
    sum += __shfl_xor(sum, 32, 64);
    if (lg == 0) red_s[w][q] = sum;
  }
  __syncthreads();

  // PV: A = P rows (q), B = Vt rows (d) from registers
  f32x4 macc[4] = {}, cacc[4] = {};
  __builtin_amdgcn_s_setprio(1);
#pragma unroll
  for (int ks = 0; ks < 7; ++ks) {
#pragma unroll
    for (int fi = 0; fi < 4; ++fi) {
      const int q = fi * 16 + l15;
      const f16x8 pa = *reinterpret_cast<const f16x8*>(
          Pb + q * 512 + ((2 * (ks * 32 + lg * 8)) ^ ((q & 7) << 4)));
      macc[fi] = mfma16(pa, vmr[ks], macc[fi]);
      const f16x8 pq = pa * pa;
      cacc[fi] = mfma16(pq, vcr[ks], cacc[fi]);
    }
  }
  __builtin_amdgcn_s_setprio(0);

  // epilogue: normalize by row sums
#pragma unroll
  for (int fi = 0; fi < 4; ++fi)
#pragma unroll
    for (int r = 0; r < 4; ++r) {
      const int qo = fi * 16 + lg * 4 + r;
      const int srow = s0 + qo;
      if (srow < S) {
        const float tot = red_s[0][qo] + red_s[1][qo] + red_s[2][qo] + red_s[3][qo];
        const float inv = 1.f / tot;
        const size_t oidx = (size_t)(b * S + srow) * HID + h * DH + d;
        mean_ctx[oidx] = (f16)(macc[fi][r] * inv);
        cov_ctx[oidx] = (f16)(cacc[fi][r] * inv * inv);
      }
    }
}

extern "C" void kernel_launch(void* const* d_in, const int* in_sizes, int n_in,
                              void* d_out, int out_size, void* d_ws, size_t ws_size,
                              hipStream_t stream) {
  const float* in_mean = (const float*)d_in[0];
  const float* in_cov = (const float*)d_in[1];
  const float* Wmq = (const float*)d_in[2];  const float* bmq = (const float*)d_in[3];
  const float* Wcq = (const float*)d_in[4];  const float* bcq = (const float*)d_in[5];
  const float* Wmk = (const float*)d_in[6];  const float* bmk = (const float*)d_in[7];
  const float* Wck = (const float*)d_in[8];  const float* bck = (const float*)d_in[9];
  const float* Wmv = (const float*)d_in[10]; const float* bmv = (const float*)d_in[11];
  const float* Wcv = (const float*)d_in[12]; const float* bcv = (const float*)d_in[13];
  const float* Wmd = (const float*)d_in[14]; const float* bmd = (const float*)d_in[15];
  const float* Wcd = (const float*)d_in[16]; const float* bcd = (const float*)d_in[17];

  const size_t need = (6 * NPH + 8 * WSZ1 + 2 * VTSZ) * sizeof(f16) +
                      2 * (size_t)BNS * sizeof(float);
  if (ws_size < need) return;

  f16* Xm = (f16*)d_ws;          // later: mean_ctx
  f16* Xc = Xm + NPH;            // later: cov_ctx
  f16* Wt = Xc + NPH;
  f16* mq = Wt + 8 * WSZ1;
  f16* mk = mq + NPH;
  f16* sq = mk + NPH;
  f16* sk = sq + NPH;
  f16* vtm = sk + NPH;
  f16* vtc = vtm + VTSZ;
  float* qterm = (float*)(vtc + VTSZ);
  float* kterm = qterm + BNS;
  f16* mean_ctx = Xm;
  f16* cov_ctx = Xc;

  float* out_mean = (float*)d_out;
  float* out_cov = out_mean + (size_t)M * HID;

  dim3 blk(256);

  zero_kernel<<<(2 * VTSZ / 8 + 255) / 256, blk, 0, stream>>>(vtm, 2 * VTSZ / 8);
  cvt_x_kernel<<<NPH / 2048, blk, 0, stream>>>(in_mean, in_cov, Xm, Xc);

  WPtrs wp;
  wp.w[0] = Wmq; wp.w[1] = Wmk; wp.w[2] = Wmv;
  wp.w[3] = Wcq; wp.w[4] = Wck; wp.w[5] = Wcv;
  wp.w[6] = Wmd; wp.w[7] = Wcd;
  cvt_w_kernel<<<dim3(24, 24, 8), blk, 0, stream>>>(wp, Wt);

  ProjArgs pa;
  pa.A[0] = Xm; pa.A[1] = Xc;
  pa.Bt[0] = Wt; pa.Bt[1] = Wt + 3 * WSZ1;
  pa.bias[0][0] = bmq; pa.bias[0][1] = bmk; pa.bias[0][2] = bmv;
  pa.bias[1][0] = bcq; pa.bias[1][1] = bck; pa.bias[1][2] = bcv;
  pa.out0[0] = mq; pa.out0[1] = sq;
  pa.out1[0] = mk; pa.out1[1] = sk;
  pa.vt[0] = vtm; pa.vt[1] = vtc;
  gemm_proj<<<99 * 18 * 2, blk, 0, stream>>>(pa);

  sums_kernel<<<BNS / 4, blk, 0, stream>>>(mq, sq, mk, sk, qterm, kterm);

  attn_kernel<<<3072, blk, 0, stream>>>(mq, sq, mk, sk, vtm, vtc,
                                        qterm, kterm, mean_ctx, cov_ctx);

  OutArgs oa;
  oa.A[0] = mean_ctx; oa.A[1] = cov_ctx;
  oa.Bt[0] = Wt + 6 * WSZ1; oa.Bt[1] = Wt + 7 * WSZ1;
  oa.bias[0] = bmd; oa.bias[1] = bcd;
  oa.Y[0] = out_mean; oa.Y[1] = out_cov;
  gemm_out<<<99 * 6 * 2, blk, 0, stream>>>(oa);
}

// Round 5
// 380.970 us; speedup vs baseline: 1.1207x; 1.1207x over previous
//
#include <hip/hip_runtime.h>
#include <hip/hip_bf16.h>
#include <stdint.h>

typedef _Float16 f16;
typedef _Float16 f16x8 __attribute__((ext_vector_type(8)));
typedef _Float16 f16x4 __attribute__((ext_vector_type(4)));
typedef float f32x4 __attribute__((ext_vector_type(4)));

constexpr int B = 64, S = 197, HID = 768, NH = 12, DH = 64;
constexpr int M = B * S;          // 12608
constexpr int Mpad = 12800;       // 50*256
constexpr int BNS = B * NH * S;   // 151296
constexpr int VSTRIDE = 224;      // 7*32 >= 197
constexpr size_t NPH = (size_t)Mpad * HID;
constexpr size_t MH = (size_t)M * HID;
constexpr size_t WSZ1 = (size_t)HID * HID;
constexpr size_t VTSZ = (size_t)B * NH * DH * VSTRIDE;

__device__ __forceinline__ f32x4 mfma16(f16x8 a, f16x8 b, f32x4 c) {
  return __builtin_amdgcn_mfma_f32_16x16x32_f16(a, b, c, 0, 0, 0);
}

__device__ __forceinline__ void gload16(const void* g, void* l) {
  __builtin_amdgcn_global_load_lds(
      (const __attribute__((address_space(1))) void*)g,
      (__attribute__((address_space(3))) void*)l, 16, 0, 0);
}

// bijective XCD-aware swizzle (m204)
__device__ __forceinline__ int xcd_swizzle(int wg, int nwg) {
  const int q = nwg >> 3, r = nwg & 7;
  const int x = wg & 7, p = wg >> 3;
  return (x < r ? x * (q + 1) : r * (q + 1) + (x - r) * q) + p;
}

// ---------------- zero fill (16B) ----------------
__global__ __launch_bounds__(256) void zero_kernel(char* __restrict__ p, size_t n16) {
  const size_t i = (size_t)blockIdx.x * 256 + threadIdx.x;
  if (i < n16) reinterpret_cast<int4*>(p)[i] = int4{0, 0, 0, 0};
}

// ---------------- f32 -> f16 (padded, zero tail) ----------------
__global__ __launch_bounds__(256) void cvt_x_kernel(
    const float* __restrict__ xm, const float* __restrict__ xc,
    f16* __restrict__ ym, f16* __restrict__ yc) {
  const size_t i8 = ((size_t)blockIdx.x * 256 + threadIdx.x) * 8;
  f16x8 vm = {}, vc = {};
  if (i8 < MH) {
    const float4 a0 = *reinterpret_cast<const float4*>(xm + i8);
    const float4 a1 = *reinterpret_cast<const float4*>(xm + i8 + 4);
    const float4 b0 = *reinterpret_cast<const float4*>(xc + i8);
    const float4 b1 = *reinterpret_cast<const float4*>(xc + i8 + 4);
    vm[0] = (f16)a0.x; vm[1] = (f16)a0.y; vm[2] = (f16)a0.z; vm[3] = (f16)a0.w;
    vm[4] = (f16)a1.x; vm[5] = (f16)a1.y; vm[6] = (f16)a1.z; vm[7] = (f16)a1.w;
    vc[0] = (f16)b0.x; vc[1] = (f16)b0.y; vc[2] = (f16)b0.z; vc[3] = (f16)b0.w;
    vc[4] = (f16)b1.x; vc[5] = (f16)b1.y; vc[6] = (f16)b1.z; vc[7] = (f16)b1.w;
  }
  *reinterpret_cast<f16x8*>(ym + i8) = vm;
  *reinterpret_cast<f16x8*>(yc + i8) = vc;
}

// ---------------- W [k][n] f32 -> Wt [n][k] f16 ----------------
struct WPtrs { const float* w[8]; };

__global__ __launch_bounds__(256) void cvt_w_kernel(WPtrs p, f16* __restrict__ wt) {
  __shared__ float tile[32][33];
  const int z = blockIdx.z;
  const float* W = p.w[z];
  f16* Wt = wt + (size_t)z * WSZ1;
  const int k0 = blockIdx.x * 32, n0 = blockIdx.y * 32;
  const int tx = threadIdx.x & 31, ty = threadIdx.x >> 5;
#pragma unroll
  for (int i = 0; i < 4; ++i)
    tile[ty + i * 8][tx] = W[(size_t)(k0 + ty + i * 8) * HID + n0 + tx];
  __syncthreads();
#pragma unroll
  for (int i = 0; i < 4; ++i)
    Wt[(size_t)(n0 + ty + i * 8) * HID + k0 + tx] = (f16)tile[tx][ty + i * 8];
}

// ---------------- shared MFMA GEMM core (256x256 tile, 512 thr, K=768) ----
// global_load_lds staging (linear LDS dest, inverse-swizzled source), dbuf,
// counted vmcnt: next tile's 8 loads stay in flight across the barrier.
__device__ __forceinline__ void gemm_core(
    const f16* __restrict__ Abase, const f16* __restrict__ Btbase,
    int m0, int n0, int tid, char (*lds)[32768], f32x4 (&acc)[8][4]) {
  const int w = tid >> 6, lane = tid & 63;
  const int l15 = lane & 15, lg = lane >> 4;
  const int wr = (w >> 2) * 128, wc = (w & 3) * 64;
  const int srow = w * 32 + (lane >> 3);
  const int scb = ((lane & 7) * 16) ^ ((srow & 7) << 4);
  const char* gA = reinterpret_cast<const char*>(Abase + (size_t)(m0 + srow) * HID) + scb;
  const char* gB = reinterpret_cast<const char*>(Btbase + (size_t)(n0 + srow) * HID) + scb;

  // prologue: stage kt=0 into buf0
#pragma unroll
  for (int i = 0; i < 4; ++i) {
    gload16(gA + (size_t)i * 8 * 1536, lds[0] + w * 4096 + i * 1024);
    gload16(gB + (size_t)i * 8 * 1536, lds[1] + w * 4096 + i * 1024);
  }

  int cur = 0;
  for (int kt = 0; kt < 12; ++kt) {
    if (kt + 1 < 12) {  // stage next tile; keep its 8 loads in flight
      const size_t off = (size_t)(kt + 1) * 128;
#pragma unroll
      for (int i = 0; i < 4; ++i) {
        gload16(gA + off + (size_t)i * 8 * 1536, lds[2 - 2 * cur] + w * 4096 + i * 1024);
        gload16(gB + off + (size_t)i * 8 * 1536, lds[3 - 2 * cur] + w * 4096 + i * 1024);
      }
      asm volatile("s_waitcnt vmcnt(8)\n\ts_barrier" ::: "memory");
    } else {
      asm volatile("s_waitcnt vmcnt(0)\n\ts_barrier" ::: "memory");
    }
    const char* cA = lds[2 * cur];
    const char* cB = lds[2 * cur + 1];
#pragma unroll
    for (int ks = 0; ks < 2; ++ks) {
      f16x8 af[8], bf[4];
#pragma unroll
      for (int fi = 0; fi < 8; ++fi) {
        const int row = wr + l15 + fi * 16;
        af[fi] = *reinterpret_cast<const f16x8*>(
            cA + row * 128 + ((ks * 64 + lg * 16) ^ ((row & 7) << 4)));
      }
#pragma unroll
      for (int fj = 0; fj < 4; ++fj) {
        const int row = wc + l15 + fj * 16;
        bf[fj] = *reinterpret_cast<const f16x8*>(
            cB + row * 128 + ((ks * 64 + lg * 16) ^ ((row & 7) << 4)));
      }
#pragma unroll
      for (int fi = 0; fi < 8; ++fi)
#pragma unroll
        for (int fj = 0; fj < 4; ++fj)
          acc[fi][fj] = mfma16(af[fi], bf[fj], acc[fi][fj]);
    }
    asm volatile("s_waitcnt lgkmcnt(0)\n\ts_barrier" ::: "memory");
    cur ^= 1;
  }
}

// ---------------- projection GEMMs (z=0 mean, z=1 cov) ----------------
struct ProjArgs {
  const f16* A[2]; const f16* Bt[2];
  const float* bias[2][3];
  f16* out0[2];  // nsel 0: mq / sq   (scaled 0.5, M rows)
  f16* out1[2];  // nsel 1: mk / sk   (scaled 0.5, M rows)
  f16* vt[2];    // nsel 2: Vt mean / cov (transposed, unscaled)
  float* qterm; float* kterm;  // fused row sums (atomic)
};

__global__ __launch_bounds__(512, 1) void gemm_proj(ProjArgs g) {
  __shared__ char lds[4][32768];
  const int swz = xcd_swizzle(blockIdx.x, 900);
  const int z = swz / 450;
  const int rest = swz - z * 450;
  const int x = rest / 9, y = rest - x * 9;  // y fastest: A panel L2-reuse
  const int m0 = x * 256, n0 = y * 256;

  f32x4 acc[8][4] = {};
  gemm_core(g.A[z], g.Bt[z], m0, n0, threadIdx.x, lds, acc);

  const int tid = threadIdx.x, w = tid >> 6, lane = tid & 63;
  const int l15 = lane & 15, lg = lane >> 4;
  const int wr = (w >> 2) * 128, wc = (w & 3) * 64;
  const int nsel = n0 / 768;
  const int colbase = (n0 - nsel * 768) + wc;  // multiple of 64
  const int rbase = m0 + wr + lg * 4;
  const float* bias = g.bias[z][nsel];
  const int hh = colbase >> 6;

  if (nsel < 2) {
    f16* Y = nsel ? g.out1[z] : g.out0[z];
    float* term = nsel ? g.kterm : g.qterm;
    float bv4[4];
#pragma unroll
    for (int fj = 0; fj < 4; ++fj) bv4[fj] = bias[colbase + l15 + fj * 16];
#pragma unroll
    for (int fi = 0; fi < 8; ++fi) {
#pragma unroll
      for (int r = 0; r < 4; ++r) {
        const int row = rbase + fi * 16 + r;
        float ssum = 0.f;
#pragma unroll
        for (int fj = 0; fj < 4; ++fj) {
          float v = acc[fi][fj][r] + bv4[fj];
          if (z == 1) { v = (v > 0.f) ? v + 1.f : __expf(v); v = sqrtf(v); }
          const f16 st = (f16)(v * 0.5f);
          if (row < M) Y[(size_t)row * HID + colbase + l15 + fj * 16] = st;
          const float sf = (float)st;
          ssum = fmaf(sf, sf, ssum);
        }
        ssum += __shfl_xor(ssum, 1, 64);
        ssum += __shfl_xor(ssum, 2, 64);
        ssum += __shfl_xor(ssum, 4, 64);
        ssum += __shfl_xor(ssum, 8, 64);
        if (l15 == 0 && row < M) {
          const int bb = row / S, ss = row - bb * S;
          atomicAdd(&term[(bb * NH + hh) * S + ss], 0.5f * ssum);
        }
      }
    }
  } else {
    f16* VT = g.vt[z];
#pragma unroll
    for (int fj = 0; fj < 4; ++fj) {
      const int col = colbase + l15 + fj * 16;
      const float bv = bias[col];
      const int dd = col & 63;
#pragma unroll
      for (int fi = 0; fi < 8; ++fi)
#pragma unroll
        for (int r = 0; r < 4; ++r) {
          const int row = rbase + fi * 16 + r;
          if (row < M) {
            float v = acc[fi][fj][r] + bv;
            if (z == 1) v = (v > 0.f) ? v + 1.f : __expf(v);
            const int bb = row / S, ss = row - bb * S;
            VT[((size_t)(bb * NH + hh) * DH + dd) * VSTRIDE + ss] = (f16)v;
          }
        }
    }
  }
}

// ---------------- output GEMMs (z=0 mean, z=1 cov), f32 out ---------------
struct OutArgs {
  const f16* A[2]; const f16* Bt[2]; const float* bias[2]; float* Y[2];
};

__global__ __launch_bounds__(512, 1) void gemm_out(OutArgs g) {
  __shared__ char lds[4][32768];
  const int swz = xcd_swizzle(blockIdx.x, 300);
  const int z = swz / 150;
  const int rest = swz - z * 150;
  const int x = rest / 3, y = rest - x * 3;
  const int m0 = x * 256, n0 = y * 256;

  f32x4 acc[8][4] = {};
  gemm_core(g.A[z], g.Bt[z], m0, n0, threadIdx.x, lds, acc);

  const int tid = threadIdx.x, w = tid >> 6, lane = tid & 63;
  const int l15 = lane & 15, lg = lane >> 4;
  const int wr = (w >> 2) * 128, wc = (w & 3) * 64;
  const int rbase = m0 + wr + lg * 4;
  float* Y = g.Y[z];
#pragma unroll
  for (int fj = 0; fj < 4; ++fj) {
    const int col = n0 + wc + l15 + fj * 16;
    const float bv = g.bias[z][col];
#pragma unroll
    for (int fi = 0; fi < 8; ++fi)
#pragma unroll
      for (int r = 0; r < 4; ++r) {
        const int row = rbase + fi * 16 + r;
        if (row < M) Y[(size_t)row * HID + col] = acc[fi][fj][r] + bv;
      }
  }
}

// ---------------- fused Wasserstein attention ----------------
__global__ __launch_bounds__(256, 2) void attn_kernel(
    const f16* __restrict__ mq, const f16* __restrict__ sq,
    const f16* __restrict__ mk, const f16* __restrict__ sk,
    const f16* __restrict__ vtm, const f16* __restrict__ vtc,
    const float* __restrict__ qterm, const float* __restrict__ kterm,
    f16* __restrict__ mean_ctx, f16* __restrict__ cov_ctx) {
  __shared__ char Pb[64 * 512];  // P[q][j] f16, XOR-swizzled rows
  __shared__ float qt_s[64];
  __shared__ float kt_s[256];
  __shared__ float red_m[4][64];
  __shared__ float red_s[4][64];

  const int swz = xcd_swizzle(blockIdx.x, 3072);
  const int qtile = swz & 3, bh = swz >> 2;
  const int h = bh % NH, b = bh / NH;
  const int s0 = qtile * 64;
  const int tid = threadIdx.x, w = tid >> 6, lane = tid & 63;
  const int l15 = lane & 15, lg = lane >> 4;

  const size_t base = (size_t)(b * S) * HID + (size_t)h * DH;
  const int tb = bh * S;

  // Q fragments (B-operand): row = s0+fi*16+l15, k = lg*8 (+32)
  f16x8 qmf[4][2], qsf[4][2];
#pragma unroll
  for (int fi = 0; fi < 4; ++fi) {
    const size_t o = base + (size_t)(s0 + fi * 16 + l15) * HID + lg * 8;
    qmf[fi][0] = *reinterpret_cast<const f16x8*>(mq + o);
    qmf[fi][1] = *reinterpret_cast<const f16x8*>(mq + o + 32);
    qsf[fi][0] = *reinterpret_cast<const f16x8*>(sq + o);
    qsf[fi][1] = *reinterpret_cast<const f16x8*>(sq + o + 32);
  }
  if (tid < 64) qt_s[tid] = (s0 + tid < S) ? qterm[tb + s0 + tid] : 0.f;
  kt_s[tid] = (tid < S) ? kterm[tb + tid] : 0.f;
  __syncthreads();

  // scores^T: acc[fj][fi], rows = K tokens (wave-owned 64), cols = Q tokens
  f32x4 acc[4][4] = {};
  __builtin_amdgcn_s_setprio(1);
#pragma unroll
  for (int fj = 0; fj < 4; ++fj) {
    const size_t o = base + (size_t)(w * 64 + fj * 16 + l15) * HID + lg * 8;
    const f16x8 a0 = *reinterpret_cast<const f16x8*>(mk + o);
    const f16x8 a1 = *reinterpret_cast<const f16x8*>(mk + o + 32);
    const f16x8 c0 = *reinterpret_cast<const f16x8*>(sk + o);
    const f16x8 c1 = *reinterpret_cast<const f16x8*>(sk + o + 32);
#pragma unroll
    for (int fi = 0; fi < 4; ++fi) {
      acc[fj][fi] = mfma16(a0, qmf[fi][0], acc[fj][fi]);
      acc[fj][fi] = mfma16(c0, qsf[fi][0], acc[fj][fi]);
      acc[fj][fi] = mfma16(a1, qmf[fi][1], acc[fj][fi]);
      acc[fj][fi] = mfma16(c1, qsf[fi][1], acc[fj][fi]);
    }
  }
  __builtin_amdgcn_s_setprio(0);

  // issue Vt loads early (independent of softmax) -> registers
  const int d = w * 16 + l15;
  const size_t vbase = ((size_t)bh * DH + d) * VSTRIDE + lg * 8;
  f16x8 vmr[7], vcr[7];
#pragma unroll
  for (int ks = 0; ks < 7; ++ks) {
    vmr[ks] = *reinterpret_cast<const f16x8*>(vtm + vbase + ks * 32);
    vcr[ks] = *reinterpret_cast<const f16x8*>(vtc + vbase + ks * 32);
  }

  // transform + wave-partial row max
#pragma unroll
  for (int fi = 0; fi < 4; ++fi) {
    const float qv = qt_s[fi * 16 + l15];
    float mx = -1e30f;
#pragma unroll
    for (int fj = 0; fj < 4; ++fj)
#pragma unroll
      for (int r = 0; r < 4; ++r) {
        const int j = w * 64 + fj * 16 + lg * 4 + r;
        float sv = acc[fj][fi][r] - qv - kt_s[j];
        if (j >= S) sv = -1e30f;
        acc[fj][fi][r] = sv;
        mx = fmaxf(mx, sv);
      }
    mx = fmaxf(mx, __shfl_xor(mx, 16, 64));
    mx = fmaxf(mx, __shfl_xor(mx, 32, 64));
    if (lg == 0) red_m[w][fi * 16 + l15] = mx;
  }
  __syncthreads();

  // exp (unnormalized) -> P (b64 writes), partial sums
#pragma unroll
  for (int fi = 0; fi < 4; ++fi) {
    const int q = fi * 16 + l15;
    const float m = fmaxf(fmaxf(red_m[0][q], red_m[1][q]),
                          fmaxf(red_m[2][q], red_m[3][q]));
    const int xr = (q & 7) << 4;
    float sum = 0.f;
#pragma unroll
    for (int fj = 0; fj < 4; ++fj) {
      f16x4 p4;
#pragma unroll
      for (int r = 0; r < 4; ++r) {
        const float e = __expf(acc[fj][fi][r] - m);
        sum += e;
        p4[r] = (f16)e;
      }
      *reinterpret_cast<f16x4*>(
          Pb + q * 512 + ((2 * (w * 64 + fj * 16 + lg * 4)) ^ xr)) = p4;
    }
    sum += __shfl_xor(sum, 16, 64);
    sum += __shfl_xor(sum, 32, 64);
    if (lg == 0) red_s[w][q] = sum;
  }
  __syncthreads();

  // PV: A = P rows (q), B = Vt rows (d) from registers
  f32x4 macc[4] = {}, cacc[4] = {};
  __builtin_amdgcn_s_setprio(1);
#pragma unroll
  for (int ks = 0; ks < 7; ++ks) {
#pragma unroll
    for (int fi = 0; fi < 4; ++fi) {
      const int q = fi * 16 + l15;
      const f16x8 pa = *reinterpret_cast<const f16x8*>(
          Pb + q * 512 + ((2 * (ks * 32 + lg * 8)) ^ ((q & 7) << 4)));
      macc[fi] = mfma16(pa, vmr[ks], macc[fi]);
      const f16x8 pq = pa * pa;
      cacc[fi] = mfma16(pq, vcr[ks], cacc[fi]);
    }
  }
  __builtin_amdgcn_s_setprio(0);

  // epilogue: normalize by row sums
#pragma unroll
  for (int fi = 0; fi < 4; ++fi)
#pragma unroll
    for (int r = 0; r < 4; ++r) {
      const int qo = fi * 16 + lg * 4 + r;
      const int srow = s0 + qo;
      if (srow < S) {
        const float tot = red_s[0][qo] + red_s[1][qo] + red_s[2][qo] + red_s[3][qo];
        const float inv = 1.f / tot;
        const size_t oidx = (size_t)(b * S + srow) * HID + h * DH + d;
        mean_ctx[oidx] = (f16)(macc[fi][r] * inv);
        cov_ctx[oidx] = (f16)(cacc[fi][r] * inv * inv);
      }
    }
}

extern "C" void kernel_launch(void* const* d_in, const int* in_sizes, int n_in,
                              void* d_out, int out_size, void* d_ws, size_t ws_size,
                              hipStream_t stream) {
  const float* in_mean = (const float*)d_in[0];
  const float* in_cov = (const float*)d_in[1];
  const float* Wmq = (const float*)d_in[2];  const float* bmq = (const float*)d_in[3];
  const float* Wcq = (const float*)d_in[4];  const float* bcq = (const float*)d_in[5];
  const float* Wmk = (const float*)d_in[6];  const float* bmk = (const float*)d_in[7];
  const float* Wck = (const float*)d_in[8];  const float* bck = (const float*)d_in[9];
  const float* Wmv = (const float*)d_in[10]; const float* bmv = (const float*)d_in[11];
  const float* Wcv = (const float*)d_in[12]; const float* bcv = (const float*)d_in[13];
  const float* Wmd = (const float*)d_in[14]; const float* bmd = (const float*)d_in[15];
  const float* Wcd = (const float*)d_in[16]; const float* bcd = (const float*)d_in[17];

  const size_t need = (2 * NPH + 8 * WSZ1 + 4 * MH + 2 * VTSZ) * sizeof(f16) +
                      2 * (size_t)BNS * sizeof(float);
  if (ws_size < need) return;

  f16* Xm = (f16*)d_ws;          // later: mean_ctx
  f16* Xc = Xm + NPH;            // later: cov_ctx
  f16* Wt = Xc + NPH;
  f16* mq = Wt + 8 * WSZ1;
  f16* mk = mq + MH;
  f16* sq = mk + MH;
  f16* sk = sq + MH;
  f16* vtm = sk + MH;
  f16* vtc = vtm + VTSZ;
  float* qterm = (float*)(vtc + VTSZ);
  float* kterm = qterm + BNS;
  f16* mean_ctx = Xm;
  f16* cov_ctx = Xc;

  float* out_mean = (float*)d_out;
  float* out_cov = out_mean + MH;

  dim3 blk(256);

  // zero Vt + qterm + kterm (contiguous region starting at vtm)
  const size_t zbytes = 2 * VTSZ * sizeof(f16) + 2 * (size_t)BNS * sizeof(float);
  const size_t n16 = zbytes / 16;
  zero_kernel<<<(int)((n16 + 255) / 256), blk, 0, stream>>>((char*)vtm, n16);

  cvt_x_kernel<<<(int)(NPH / 2048), blk, 0, stream>>>(in_mean, in_cov, Xm, Xc);

  WPtrs wp;
  wp.w[0] = Wmq; wp.w[1] = Wmk; wp.w[2] = Wmv;
  wp.w[3] = Wcq; wp.w[4] = Wck; wp.w[5] = Wcv;
  wp.w[6] = Wmd; wp.w[7] = Wcd;
  cvt_w_kernel<<<dim3(24, 24, 8), blk, 0, stream>>>(wp, Wt);

  ProjArgs pa;
  pa.A[0] = Xm; pa.A[1] = Xc;
  pa.Bt[0] = Wt; pa.Bt[1] = Wt + 3 * WSZ1;
  pa.bias[0][0] = bmq; pa.bias[0][1] = bmk; pa.bias[0][2] = bmv;
  pa.bias[1][0] = bcq; pa.bias[1][1] = bck; pa.bias[1][2] = bcv;
  pa.out0[0] = mq; pa.out0[1] = sq;
  pa.out1[0] = mk; pa.out1[1] = sk;
  pa.vt[0] = vtm; pa.vt[1] = vtc;
  pa.qterm = qterm; pa.kterm = kterm;
  gemm_proj<<<900, dim3(512), 0, stream>>>(pa);

  attn_kernel<<<3072, blk, 0, stream>>>(mq, sq, mk, sk, vtm, vtc,
                                        qterm, kterm, mean_ctx, cov_ctx);

  OutArgs oa;
  oa.A[0] = mean_ctx; oa.A[1] = cov_ctx;
  oa.Bt[0] = Wt + 6 * WSZ1; oa.Bt[1] = Wt + 7 * WSZ1;
  oa.bias[0] = bmd; oa.bias[1] = bcd;
  oa.Y[0] = out_mean; oa.Y[1] = out_cov;
  gemm_out<<<300, dim3(512), 0, stream>>>(oa);
}

// Round 6
// 376.367 us; speedup vs baseline: 1.1344x; 1.0122x over previous
//
#include <hip/hip_runtime.h>
#include <hip/hip_bf16.h>
#include <stdint.h>

typedef _Float16 f16;
typedef _Float16 f16x8 __attribute__((ext_vector_type(8)));
typedef _Float16 f16x4 __attribute__((ext_vector_type(4)));
typedef float f32x4 __attribute__((ext_vector_type(4)));

constexpr int B = 64, S = 197, HID = 768, NH = 12, DH = 64;
constexpr int M = B * S;          // 12608
constexpr int Mpad = 12800;       // 50*256
constexpr int BNS = B * NH * S;   // 151296
constexpr int VSTRIDE = 224;      // 7*32 >= 197
constexpr size_t NPH = (size_t)Mpad * HID;
constexpr size_t MH = (size_t)M * HID;
constexpr size_t WSZ1 = (size_t)HID * HID;
constexpr size_t VTSZ = (size_t)B * NH * DH * VSTRIDE;

__device__ __forceinline__ f32x4 mfma16(f16x8 a, f16x8 b, f32x4 c) {
  return __builtin_amdgcn_mfma_f32_16x16x32_f16(a, b, c, 0, 0, 0);
}

__device__ __forceinline__ void gload16(const void* g, void* l) {
  __builtin_amdgcn_global_load_lds(
      (const __attribute__((address_space(1))) void*)g,
      (__attribute__((address_space(3))) void*)l, 16, 0, 0);
}

// bijective XCD-aware swizzle (m204)
__device__ __forceinline__ int xcd_swizzle(int wg, int nwg) {
  const int q = nwg >> 3, r = nwg & 7;
  const int x = wg & 7, p = wg >> 3;
  return (x < r ? x * (q + 1) : r * (q + 1) + (x - r) * q) + p;
}

// ---------------- zero fill (16B) ----------------
__global__ __launch_bounds__(256) void zero_kernel(char* __restrict__ p, size_t n16) {
  const size_t i = (size_t)blockIdx.x * 256 + threadIdx.x;
  if (i < n16) reinterpret_cast<int4*>(p)[i] = int4{0, 0, 0, 0};
}

// ---------------- f32 -> f16 (padded, zero tail) ----------------
__global__ __launch_bounds__(256) void cvt_x_kernel(
    const float* __restrict__ xm, const float* __restrict__ xc,
    f16* __restrict__ ym, f16* __restrict__ yc) {
  const size_t i8 = ((size_t)blockIdx.x * 256 + threadIdx.x) * 8;
  f16x8 vm = {}, vc = {};
  if (i8 < MH) {
    const float4 a0 = *reinterpret_cast<const float4*>(xm + i8);
    const float4 a1 = *reinterpret_cast<const float4*>(xm + i8 + 4);
    const float4 b0 = *reinterpret_cast<const float4*>(xc + i8);
    const float4 b1 = *reinterpret_cast<const float4*>(xc + i8 + 4);
    vm[0] = (f16)a0.x; vm[1] = (f16)a0.y; vm[2] = (f16)a0.z; vm[3] = (f16)a0.w;
    vm[4] = (f16)a1.x; vm[5] = (f16)a1.y; vm[6] = (f16)a1.z; vm[7] = (f16)a1.w;
    vc[0] = (f16)b0.x; vc[1] = (f16)b0.y; vc[2] = (f16)b0.z; vc[3] = (f16)b0.w;
    vc[4] = (f16)b1.x; vc[5] = (f16)b1.y; vc[6] = (f16)b1.z; vc[7] = (f16)b1.w;
  }
  *reinterpret_cast<f16x8*>(ym + i8) = vm;
  *reinterpret_cast<f16x8*>(yc + i8) = vc;
}

// ---------------- W [k][n] f32 -> Wt [n][k] f16 ----------------
struct WPtrs { const float* w[8]; };

__global__ __launch_bounds__(256) void cvt_w_kernel(WPtrs p, f16* __restrict__ wt) {
  __shared__ float tile[32][33];
  const int z = blockIdx.z;
  const float* W = p.w[z];
  f16* Wt = wt + (size_t)z * WSZ1;
  const int k0 = blockIdx.x * 32, n0 = blockIdx.y * 32;
  const int tx = threadIdx.x & 31, ty = threadIdx.x >> 5;
#pragma unroll
  for (int i = 0; i < 4; ++i)
    tile[ty + i * 8][tx] = W[(size_t)(k0 + ty + i * 8) * HID + n0 + tx];
  __syncthreads();
#pragma unroll
  for (int i = 0; i < 4; ++i)
    Wt[(size_t)(n0 + ty + i * 8) * HID + k0 + tx] = (f16)tile[tx][ty + i * 8];
}

// ---------------- shared MFMA GEMM core (256x256 tile, 512 thr, K=768) ----
// BK=32, 3 LDS buffers (96 KB), counted-vmcnt pipeline: iter t stages tile
// t+2, computes tile t, waits vmcnt(4) (= tile t+1 landed, t+2 in flight),
// ONE s_barrier per K-tile. 64-B row stride => conflict-free without swizzle.
__device__ __forceinline__ void gemm_core(
    const f16* __restrict__ Abase, const f16* __restrict__ Btbase,
    int m0, int n0, int tid, char* lds, f32x4 (&acc)[8][4]) {
  const int w = tid >> 6, lane = tid & 63;
  const int l15 = lane & 15, lg = lane >> 4;
  const int wr = (w >> 2) * 128, wc = (w & 3) * 64;

  // staging: wave w covers rows w*32..w*32+31 (2 rounds of 16 rows)
  const int srow = w * 32 + (lane >> 2);
  const int scol = (lane & 3) * 16;  // bytes within the 64-B k-slice
  const char* gA = reinterpret_cast<const char*>(Abase + (size_t)(m0 + srow) * HID) + scol;
  const char* gB = reinterpret_cast<const char*>(Btbase + (size_t)(n0 + srow) * HID) + scol;
  const int wbase = w * 2048;  // wave-uniform LDS dest (HW adds lane*16)

#define STAGE_TILE(T, BUF)                                               \
  do {                                                                   \
    const size_t off_ = (size_t)(T) * 64;                                \
    char* la_ = lds + (BUF) * 32768 + wbase;                             \
    char* lb_ = la_ + 16384;                                             \
    gload16(gA + off_, la_);                                             \
    gload16(gA + off_ + (size_t)16 * 1536, la_ + 1024);                  \
    gload16(gB + off_, lb_);                                             \
    gload16(gB + off_ + (size_t)16 * 1536, lb_ + 1024);                  \
  } while (0)

  // prologue: tiles 0 and 1 in flight; wait tile 0 only
  STAGE_TILE(0, 0);
  STAGE_TILE(1, 1);
  asm volatile("s_waitcnt vmcnt(4)\n\ts_barrier" ::: "memory");

#pragma unroll
  for (int t = 0; t < 24; ++t) {
    if (t + 2 < 24) STAGE_TILE(t + 2, (t + 2) % 3);

    const char* cA = lds + (t % 3) * 32768;
    const char* cB = cA + 16384;
    f16x8 af[8], bf[4];
#pragma unroll
    for (int fi = 0; fi < 8; ++fi)
      af[fi] = *reinterpret_cast<const f16x8*>(cA + (wr + l15 + fi * 16) * 64 + lg * 16);
#pragma unroll
    for (int fj = 0; fj < 4; ++fj)
      bf[fj] = *reinterpret_cast<const f16x8*>(cB + (wc + l15 + fj * 16) * 64 + lg * 16);

    __builtin_amdgcn_s_setprio(1);
#pragma unroll
    for (int fi = 0; fi < 8; ++fi)
#pragma unroll
      for (int fj = 0; fj < 4; ++fj)
        acc[fi][fj] = mfma16(af[fi], bf[fj], acc[fi][fj]);
    __builtin_amdgcn_s_setprio(0);

    if (t + 2 < 24) {
      asm volatile("s_waitcnt vmcnt(4)\n\ts_barrier" ::: "memory");
    } else if (t + 1 < 24) {
      asm volatile("s_waitcnt vmcnt(0)\n\ts_barrier" ::: "memory");
    }
  }
#undef STAGE_TILE
}

// ---------------- projection GEMMs (z=0 mean, z=1 cov) ----------------
struct ProjArgs {
  const f16* A[2]; const f16* Bt[2];
  const float* bias[2][3];
  f16* out0[2];  // nsel 0: mq / sq   (scaled 0.5, M rows)
  f16* out1[2];  // nsel 1: mk / sk   (scaled 0.5, M rows)
  f16* vt[2];    // nsel 2: Vt mean / cov (transposed, unscaled)
  float* qterm; float* kterm;  // fused row sums (atomic)
};

__global__ __launch_bounds__(512, 1) void gemm_proj(ProjArgs g) {
  __shared__ alignas(16) char lds[98304];
  const int swz = xcd_swizzle(blockIdx.x, 900);
  const int z = swz / 450;
  const int rest = swz - z * 450;
  const int x = rest / 9, y = rest - x * 9;  // y fastest: A panel L2-reuse
  const int m0 = x * 256, n0 = y * 256;

  f32x4 acc[8][4] = {};
  gemm_core(g.A[z], g.Bt[z], m0, n0, threadIdx.x, lds, acc);

  const int tid = threadIdx.x, w = tid >> 6, lane = tid & 63;
  const int l15 = lane & 15, lg = lane >> 4;
  const int wr = (w >> 2) * 128, wc = (w & 3) * 64;
  const int nsel = n0 / 768;
  const int colbase = (n0 - nsel * 768) + wc;  // multiple of 64
  const int rbase = m0 + wr + lg * 4;
  const float* bias = g.bias[z][nsel];
  const int hh = colbase >> 6;

  if (nsel < 2) {
    f16* Y = nsel ? g.out1[z] : g.out0[z];
    float* term = nsel ? g.kterm : g.qterm;
    float bv4[4];
#pragma unroll
    for (int fj = 0; fj < 4; ++fj) bv4[fj] = bias[colbase + l15 + fj * 16];
#pragma unroll
    for (int fi = 0; fi < 8; ++fi) {
#pragma unroll
      for (int r = 0; r < 4; ++r) {
        const int row = rbase + fi * 16 + r;
        float ssum = 0.f;
#pragma unroll
        for (int fj = 0; fj < 4; ++fj) {
          float v = acc[fi][fj][r] + bv4[fj];
          if (z == 1) { v = (v > 0.f) ? v + 1.f : __expf(v); v = sqrtf(v); }
          const f16 st = (f16)(v * 0.5f);
          if (row < M) Y[(size_t)row * HID + colbase + l15 + fj * 16] = st;
          const float sf = (float)st;
          ssum = fmaf(sf, sf, ssum);
        }
        ssum += __shfl_xor(ssum, 1, 64);
        ssum += __shfl_xor(ssum, 2, 64);
        ssum += __shfl_xor(ssum, 4, 64);
        ssum += __shfl_xor(ssum, 8, 64);
        if (l15 == 0 && row < M) {
          const int bb = row / S, ss = row - bb * S;
          atomicAdd(&term[(bb * NH + hh) * S + ss], 0.5f * ssum);
        }
      }
    }
  } else {
    f16* VT = g.vt[z];
#pragma unroll
    for (int fj = 0; fj < 4; ++fj) {
      const int col = colbase + l15 + fj * 16;
      const float bv = bias[col];
      const int dd = col & 63;
#pragma unroll
      for (int fi = 0; fi < 8; ++fi)
#pragma unroll
        for (int r = 0; r < 4; ++r) {
          const int row = rbase + fi * 16 + r;
          if (row < M) {
            float v = acc[fi][fj][r] + bv;
            if (z == 1) v = (v > 0.f) ? v + 1.f : __expf(v);
            const int bb = row / S, ss = row - bb * S;
            VT[((size_t)(bb * NH + hh) * DH + dd) * VSTRIDE + ss] = (f16)v;
          }
        }
    }
  }
}

// ---------------- output GEMMs (z=0 mean, z=1 cov), f32 out ---------------
struct OutArgs {
  const f16* A[2]; const f16* Bt[2]; const float* bias[2]; float* Y[2];
};

__global__ __launch_bounds__(512, 1) void gemm_out(OutArgs g) {
  __shared__ alignas(16) char lds[98304];
  const int swz = xcd_swizzle(blockIdx.x, 300);
  const int z = swz / 150;
  const int rest = swz - z * 150;
  const int x = rest / 3, y = rest - x * 3;
  const int m0 = x * 256, n0 = y * 256;

  f32x4 acc[8][4] = {};
  gemm_core(g.A[z], g.Bt[z], m0, n0, threadIdx.x, lds, acc);

  const int tid = threadIdx.x, w = tid >> 6, lane = tid & 63;
  const int l15 = lane & 15, lg = lane >> 4;
  const int wr = (w >> 2) * 128, wc = (w & 3) * 64;
  const int rbase = m0 + wr + lg * 4;
  float* Y = g.Y[z];
#pragma unroll
  for (int fj = 0; fj < 4; ++fj) {
    const int col = n0 + wc + l15 + fj * 16;
    const float bv = g.bias[z][col];
#pragma unroll
    for (int fi = 0; fi < 8; ++fi)
#pragma unroll
      for (int r = 0; r < 4; ++r) {
        const int row = rbase + fi * 16 + r;
        if (row < M) Y[(size_t)row * HID + col] = acc[fi][fj][r] + bv;
      }
  }
}

// ---------------- fused Wasserstein attention ----------------
__global__ __launch_bounds__(256, 2) void attn_kernel(
    const f16* __restrict__ mq, const f16* __restrict__ sq,
    const f16* __restrict__ mk, const f16* __restrict__ sk,
    const f16* __restrict__ vtm, const f16* __restrict__ vtc,
    const float* __restrict__ qterm, const float* __restrict__ kterm,
    f16* __restrict__ mean_ctx, f16* __restrict__ cov_ctx) {
  __shared__ char Pb[64 * 512];  // P[q][j] f16, XOR-swizzled rows
  __shared__ float qt_s[64];
  __shared__ float kt_s[256];
  __shared__ float red_m[4][64];
  __shared__ float red_s[4][64];

  const int swz = xcd_swizzle(blockIdx.x, 3072);
  const int qtile = swz & 3, bh = swz >> 2;
  const int h = bh % NH, b = bh / NH;
  const int s0 = qtile * 64;
  const int tid = threadIdx.x, w = tid >> 6, lane = tid & 63;
  const int l15 = lane & 15, lg = lane >> 4;

  const size_t base = (size_t)(b * S) * HID + (size_t)h * DH;
  const int tb = bh * S;

  // Q fragments (B-operand): row = s0+fi*16+l15, k = lg*8 (+32)
  f16x8 qmf[4][2], qsf[4][2];
#pragma unroll
  for (int fi = 0; fi < 4; ++fi) {
    const size_t o = base + (size_t)(s0 + fi * 16 + l15) * HID + lg * 8;
    qmf[fi][0] = *reinterpret_cast<const f16x8*>(mq + o);
    qmf[fi][1] = *reinterpret_cast<const f16x8*>(mq + o + 32);
    qsf[fi][0] = *reinterpret_cast<const f16x8*>(sq + o);
    qsf[fi][1] = *reinterpret_cast<const f16x8*>(sq + o + 32);
  }
  if (tid < 64) qt_s[tid] = (s0 + tid < S) ? qterm[tb + s0 + tid] : 0.f;
  kt_s[tid] = (tid < S) ? kterm[tb + tid] : 0.f;
  __syncthreads();

  // scores^T: acc[fj][fi], rows = K tokens (wave-owned 64), cols = Q tokens
  f32x4 acc[4][4] = {};
  __builtin_amdgcn_s_setprio(1);
#pragma unroll
  for (int fj = 0; fj < 4; ++fj) {
    const size_t o = base + (size_t)(w * 64 + fj * 16 + l15) * HID + lg * 8;
    const f16x8 a0 = *reinterpret_cast<const f16x8*>(mk + o);
    const f16x8 a1 = *reinterpret_cast<const f16x8*>(mk + o + 32);
    const f16x8 c0 = *reinterpret_cast<const f16x8*>(sk + o);
    const f16x8 c1 = *reinterpret_cast<const f16x8*>(sk + o + 32);
#pragma unroll
    for (int fi = 0; fi < 4; ++fi) {
      acc[fj][fi] = mfma16(a0, qmf[fi][0], acc[fj][fi]);
      acc[fj][fi] = mfma16(c0, qsf[fi][0], acc[fj][fi]);
      acc[fj][fi] = mfma16(a1, qmf[fi][1], acc[fj][fi]);
      acc[fj][fi] = mfma16(c1, qsf[fi][1], acc[fj][fi]);
    }
  }
  __builtin_amdgcn_s_setprio(0);

  // issue Vt loads early (independent of softmax) -> registers
  const int d = w * 16 + l15;
  const size_t vbase = ((size_t)bh * DH + d) * VSTRIDE + lg * 8;
  f16x8 vmr[7], vcr[7];
#pragma unroll
  for (int ks = 0; ks < 7; ++ks) {
    vmr[ks] = *reinterpret_cast<const f16x8*>(vtm + vbase + ks * 32);
    vcr[ks] = *reinterpret_cast<const f16x8*>(vtc + vbase + ks * 32);
  }

  // transform + wave-partial row max
#pragma unroll
  for (int fi = 0; fi < 4; ++fi) {
    const float qv = qt_s[fi * 16 + l15];
    float mx = -1e30f;
#pragma unroll
    for (int fj = 0; fj < 4; ++fj)
#pragma unroll
      for (int r = 0; r < 4; ++r) {
        const int j = w * 64 + fj * 16 + lg * 4 + r;
        float sv = acc[fj][fi][r] - qv - kt_s[j];
        if (j >= S) sv = -1e30f;
        acc[fj][fi][r] = sv;
        mx = fmaxf(mx, sv);
      }
    mx = fmaxf(mx, __shfl_xor(mx, 16, 64));
    mx = fmaxf(mx, __shfl_xor(mx, 32, 64));
    if (lg == 0) red_m[w][fi * 16 + l15] = mx;
  }
  __syncthreads();

  // exp (unnormalized) -> P (b64 writes), partial sums
#pragma unroll
  for (int fi = 0; fi < 4; ++fi) {
    const int q = fi * 16 + l15;
    const float m = fmaxf(fmaxf(red_m[0][q], red_m[1][q]),
                          fmaxf(red_m[2][q], red_m[3][q]));
    const int xr = (q & 7) << 4;
    float sum = 0.f;
#pragma unroll
    for (int fj = 0; fj < 4; ++fj) {
      f16x4 p4;
#pragma unroll
      for (int r = 0; r < 4; ++r) {
        const float e = __expf(acc[fj][fi][r] - m);
        sum += e;
        p4[r] = (f16)e;
      }
      *reinterpret_cast<f16x4*>(
          Pb + q * 512 + ((2 * (w * 64 + fj * 16 + lg * 4)) ^ xr)) = p4;
    }
    sum += __shfl_xor(sum, 16, 64);
    sum += __shfl_xor(sum, 32, 64);
    if (lg == 0) red_s[w][q] = sum;
  }
  __syncthreads();

  // PV: A = P rows (q), B = Vt rows (d) from registers
  f32x4 macc[4] = {}, cacc[4] = {};
  __builtin_amdgcn_s_setprio(1);
#pragma unroll
  for (int ks = 0; ks < 7; ++ks) {
#pragma unroll
    for (int fi = 0; fi < 4; ++fi) {
      const int q = fi * 16 + l15;
      const f16x8 pa = *reinterpret_cast<const f16x8*>(
          Pb + q * 512 + ((2 * (ks * 32 + lg * 8)) ^ ((q & 7) << 4)));
      macc[fi] = mfma16(pa, vmr[ks], macc[fi]);
      const f16x8 pq = pa * pa;
      cacc[fi] = mfma16(pq, vcr[ks], cacc[fi]);
    }
  }
  __builtin_amdgcn_s_setprio(0);

  // epilogue: normalize by row sums
#pragma unroll
  for (int fi = 0; fi < 4; ++fi)
#pragma unroll
    for (int r = 0; r < 4; ++r) {
      const int qo = fi * 16 + lg * 4 + r;
      const int srow = s0 + qo;
      if (srow < S) {
        const float tot = red_s[0][qo] + red_s[1][qo] + red_s[2][qo] + red_s[3][qo];
        const float inv = 1.f / tot;
        const size_t oidx = (size_t)(b * S + srow) * HID + h * DH + d;
        mean_ctx[oidx] = (f16)(macc[fi][r] * inv);
        cov_ctx[oidx] = (f16)(cacc[fi][r] * inv * inv);
      }
    }
}

extern "C" void kernel_launch(void* const* d_in, const int* in_sizes, int n_in,
                              void* d_out, int out_size, void* d_ws, size_t ws_size,
                              hipStream_t stream) {
  const float* in_mean = (const float*)d_in[0];
  const float* in_cov = (const float*)d_in[1];
  const float* Wmq = (const float*)d_in[2];  const float* bmq = (const float*)d_in[3];
  const float* Wcq = (const float*)d_in[4];  const float* bcq = (const float*)d_in[5];
  const float* Wmk = (const float*)d_in[6];  const float* bmk = (const float*)d_in[7];
  const float* Wck = (const float*)d_in[8];  const float* bck = (const float*)d_in[9];
  const float* Wmv = (const float*)d_in[10]; const float* bmv = (const float*)d_in[11];
  const float* Wcv = (const float*)d_in[12]; const float* bcv = (const float*)d_in[13];
  const float* Wmd = (const float*)d_in[14]; const float* bmd = (const float*)d_in[15];
  const float* Wcd = (const float*)d_in[16]; const float* bcd = (const float*)d_in[17];

  const size_t need = (2 * NPH + 8 * WSZ1 + 4 * MH + 2 * VTSZ) * sizeof(f16) +
                      2 * (size_t)BNS * sizeof(float);
  if (ws_size < need) return;

  f16* Xm = (f16*)d_ws;          // later: mean_ctx
  f16* Xc = Xm + NPH;            // later: cov_ctx
  f16* Wt = Xc + NPH;
  f16* mq = Wt + 8 * WSZ1;
  f16* mk = mq + MH;
  f16* sq = mk + MH;
  f16* sk = sq + MH;
  f16* vtm = sk + MH;
  f16* vtc = vtm + VTSZ;
  float* qterm = (float*)(vtc + VTSZ);
  float* kterm = qterm + BNS;
  f16* mean_ctx = Xm;
  f16* cov_ctx = Xc;

  float* out_mean = (float*)d_out;
  float* out_cov = out_mean + MH;

  dim3 blk(256);

  // zero Vt + qterm + kterm (contiguous region starting at vtm)
  const size_t zbytes = 2 * VTSZ * sizeof(f16) + 2 * (size_t)BNS * sizeof(float);
  const size_t n16 = zbytes / 16;
  zero_kernel<<<(int)((n16 + 255) / 256), blk, 0, stream>>>((char*)vtm, n16);

  cvt_x_kernel<<<(int)(NPH / 2048), blk, 0, stream>>>(in_mean, in_cov, Xm, Xc);

  WPtrs wp;
  wp.w[0] = Wmq; wp.w[1] = Wmk; wp.w[2] = Wmv;
  wp.w[3] = Wcq; wp.w[4] = Wck; wp.w[5] = Wcv;
  wp.w[6] = Wmd; wp.w[7] = Wcd;
  cvt_w_kernel<<<dim3(24, 24, 8), blk, 0, stream>>>(wp, Wt);

  ProjArgs pa;
  pa.A[0] = Xm; pa.A[1] = Xc;
  pa.Bt[0] = Wt; pa.Bt[1] = Wt + 3 * WSZ1;
  pa.bias[0][0] = bmq; pa.bias[0][1] = bmk; pa.bias[0][2] = bmv;
  pa.bias[1][0] = bcq; pa.bias[1][1] = bck; pa.bias[1][2] = bcv;
  pa.out0[0] = mq; pa.out0[1] = sq;
  pa.out1[0] = mk; pa.out1[1] = sk;
  pa.vt[0] = vtm; pa.vt[1] = vtc;
  pa.qterm = qterm; pa.kterm = kterm;
  gemm_proj<<<900, dim3(512), 0, stream>>>(pa);

  attn_kernel<<<3072, blk, 0, stream>>>(mq, sq, mk, sk, vtm, vtc,
                                        qterm, kterm, mean_ctx, cov_ctx);

  OutArgs oa;
  oa.A[0] = mean_ctx; oa.A[1] = cov_ctx;
  oa.Bt[0] = Wt + 6 * WSZ1; oa.Bt[1] = Wt + 7 * WSZ1;
  oa.bias[0] = bmd; oa.bias[1] = bcd;
  oa.Y[0] = out_mean; oa.Y[1] = out_cov;
  gemm_out<<<300, dim3(512), 0, stream>>>(oa);
}

// Round 7
// 373.596 us; speedup vs baseline: 1.1428x; 1.0074x over previous
//
#include <hip/hip_runtime.h>
#include <hip/hip_bf16.h>
#include <stdint.h>

typedef _Float16 f16;
typedef _Float16 f16x8 __attribute__((ext_vector_type(8)));
typedef _Float16 f16x4 __attribute__((ext_vector_type(4)));
typedef float f32x4 __attribute__((ext_vector_type(4)));

constexpr int B = 64, S = 197, HID = 768, NH = 12, DH = 64;
constexpr int M = B * S;          // 12608
constexpr int Mpad = 12800;       // 50*256
constexpr int BNS = B * NH * S;   // 151296
constexpr int VSTRIDE = 224;      // 7*32 >= 197
constexpr size_t NPH = (size_t)Mpad * HID;
constexpr size_t MH = (size_t)M * HID;
constexpr size_t WSZ1 = (size_t)HID * HID;
constexpr size_t VTSZ = (size_t)B * NH * DH * VSTRIDE;

__device__ __forceinline__ f32x4 mfma16(f16x8 a, f16x8 b, f32x4 c) {
  return __builtin_amdgcn_mfma_f32_16x16x32_f16(a, b, c, 0, 0, 0);
}

__device__ __forceinline__ void gload16(const void* g, void* l) {
  __builtin_amdgcn_global_load_lds(
      (const __attribute__((address_space(1))) void*)g,
      (__attribute__((address_space(3))) void*)l, 16, 0, 0);
}

// bijective XCD-aware swizzle (m204)
__device__ __forceinline__ int xcd_swizzle(int wg, int nwg) {
  const int q = nwg >> 3, r = nwg & 7;
  const int x = wg & 7, p = wg >> 3;
  return (x < r ? x * (q + 1) : r * (q + 1) + (x - r) * q) + p;
}

// ---------------- zero fill (16B) ----------------
__global__ __launch_bounds__(256) void zero_kernel(char* __restrict__ p, size_t n16) {
  const size_t i = (size_t)blockIdx.x * 256 + threadIdx.x;
  if (i < n16) reinterpret_cast<int4*>(p)[i] = int4{0, 0, 0, 0};
}

// ---------------- f32 -> f16 (padded, zero tail) ----------------
__global__ __launch_bounds__(256) void cvt_x_kernel(
    const float* __restrict__ xm, const float* __restrict__ xc,
    f16* __restrict__ ym, f16* __restrict__ yc) {
  const size_t i8 = ((size_t)blockIdx.x * 256 + threadIdx.x) * 8;
  f16x8 vm = {}, vc = {};
  if (i8 < MH) {
    const float4 a0 = *reinterpret_cast<const float4*>(xm + i8);
    const float4 a1 = *reinterpret_cast<const float4*>(xm + i8 + 4);
    const float4 b0 = *reinterpret_cast<const float4*>(xc + i8);
    const float4 b1 = *reinterpret_cast<const float4*>(xc + i8 + 4);
    vm[0] = (f16)a0.x; vm[1] = (f16)a0.y; vm[2] = (f16)a0.z; vm[3] = (f16)a0.w;
    vm[4] = (f16)a1.x; vm[5] = (f16)a1.y; vm[6] = (f16)a1.z; vm[7] = (f16)a1.w;
    vc[0] = (f16)b0.x; vc[1] = (f16)b0.y; vc[2] = (f16)b0.z; vc[3] = (f16)b0.w;
    vc[4] = (f16)b1.x; vc[5] = (f16)b1.y; vc[6] = (f16)b1.z; vc[7] = (f16)b1.w;
  }
  *reinterpret_cast<f16x8*>(ym + i8) = vm;
  *reinterpret_cast<f16x8*>(yc + i8) = vc;
}

// ---------------- W [k][n] f32 -> Wt [n][k] f16 ----------------
struct WPtrs { const float* w[8]; };

__global__ __launch_bounds__(256) void cvt_w_kernel(WPtrs p, f16* __restrict__ wt) {
  __shared__ float tile[32][33];
  const int z = blockIdx.z;
  const float* W = p.w[z];
  f16* Wt = wt + (size_t)z * WSZ1;
  const int k0 = blockIdx.x * 32, n0 = blockIdx.y * 32;
  const int tx = threadIdx.x & 31, ty = threadIdx.x >> 5;
#pragma unroll
  for (int i = 0; i < 4; ++i)
    tile[ty + i * 8][tx] = W[(size_t)(k0 + ty + i * 8) * HID + n0 + tx];
  __syncthreads();
#pragma unroll
  for (int i = 0; i < 4; ++i)
    Wt[(size_t)(n0 + ty + i * 8) * HID + k0 + tx] = (f16)tile[tx][ty + i * 8];
}

// ---------------- shared MFMA GEMM core (256x256 tile, 512 thr, K=768) ----
// BK=32, 3 LDS buffers (96 KB), counted-vmcnt pipeline (stage t+2, compute t,
// vmcnt(4), ONE s_barrier per K-tile). Bank-conflict-free slot swizzle:
// phys slot p of row r holds k-slot (p ^ ((r>>1)&3)); staged via pre-swizzled
// per-lane global SOURCE (linear LDS dest), read via (lg ^ (l15>>1))&3.
__device__ __forceinline__ void gemm_core(
    const f16* __restrict__ Abase, const f16* __restrict__ Btbase,
    int m0, int n0, int tid, char* lds, f32x4 (&acc)[8][4]) {
  const int w = tid >> 6, lane = tid & 63;
  const int l15 = lane & 15, lg = lane >> 4;
  const int wr = (w >> 2) * 128, wc = (w & 3) * 64;

  // staging: wave w covers rows w*32..w*32+31 (2 rounds of 16 rows)
  const int srow = w * 32 + (lane >> 2);
  const int scol = (((lane & 3) ^ ((lane >> 3) & 3)) * 16);  // pre-swizzled src
  const char* gA = reinterpret_cast<const char*>(Abase + (size_t)(m0 + srow) * HID) + scol;
  const char* gB = reinterpret_cast<const char*>(Btbase + (size_t)(n0 + srow) * HID) + scol;
  const int wbase = w * 2048;  // wave-uniform LDS dest (HW adds lane*16)

  // fragment-read slot (bank-spread): same formula for A and B rows
  const int rslot = ((lg ^ (l15 >> 1)) & 3) * 16;

#define STAGE_TILE(T, BUF)                                               \
  do {                                                                   \
    const size_t off_ = (size_t)(T) * 64;                                \
    char* la_ = lds + (BUF) * 32768 + wbase;                             \
    char* lb_ = la_ + 16384;                                             \
    gload16(gA + off_, la_);                                             \
    gload16(gA + off_ + (size_t)16 * 1536, la_ + 1024);                  \
    gload16(gB + off_, lb_);                                             \
    gload16(gB + off_ + (size_t)16 * 1536, lb_ + 1024);                  \
  } while (0)

  // prologue: tiles 0 and 1 in flight; wait tile 0 only
  STAGE_TILE(0, 0);
  STAGE_TILE(1, 1);
  asm volatile("s_waitcnt vmcnt(4)\n\ts_barrier" ::: "memory");

#pragma unroll
  for (int t = 0; t < 24; ++t) {
    if (t + 2 < 24) STAGE_TILE(t + 2, (t + 2) % 3);

    const char* cA = lds + (t % 3) * 32768;
    const char* cB = cA + 16384;
    f16x8 af[8], bf[4];
#pragma unroll
    for (int fi = 0; fi < 8; ++fi)
      af[fi] = *reinterpret_cast<const f16x8*>(cA + (wr + l15 + fi * 16) * 64 + rslot);
#pragma unroll
    for (int fj = 0; fj < 4; ++fj)
      bf[fj] = *reinterpret_cast<const f16x8*>(cB + (wc + l15 + fj * 16) * 64 + rslot);

    __builtin_amdgcn_s_setprio(1);
#pragma unroll
    for (int fi = 0; fi < 8; ++fi)
#pragma unroll
      for (int fj = 0; fj < 4; ++fj)
        acc[fi][fj] = mfma16(af[fi], bf[fj], acc[fi][fj]);
    __builtin_amdgcn_s_setprio(0);

    if (t + 2 < 24) {
      asm volatile("s_waitcnt vmcnt(4)\n\ts_barrier" ::: "memory");
    } else if (t + 1 < 24) {
      asm volatile("s_waitcnt vmcnt(0)\n\ts_barrier" ::: "memory");
    }
  }
#undef STAGE_TILE
}

// ---------------- projection GEMMs (z=0 mean, z=1 cov) ----------------
struct ProjArgs {
  const f16* A[2]; const f16* Bt[2];
  const float* bias[2][3];
  f16* out0[2];  // nsel 0: mq / sq   (scaled 0.5, M rows)
  f16* out1[2];  // nsel 1: mk / sk   (scaled 0.5, M rows)
  f16* vt[2];    // nsel 2: Vt mean / cov (transposed, unscaled)
  float* qterm; float* kterm;  // fused row sums (atomic)
};

__global__ __launch_bounds__(512, 1) void gemm_proj(ProjArgs g) {
  __shared__ alignas(16) char lds[98304];
  const int swz = xcd_swizzle(blockIdx.x, 900);
  const int z = swz / 450;
  const int rest = swz - z * 450;
  const int x = rest / 9, y = rest - x * 9;  // y fastest: A panel L2-reuse
  const int m0 = x * 256, n0 = y * 256;

  f32x4 acc[8][4] = {};
  gemm_core(g.A[z], g.Bt[z], m0, n0, threadIdx.x, lds, acc);

  const int tid = threadIdx.x, w = tid >> 6, lane = tid & 63;
  const int l15 = lane & 15, lg = lane >> 4;
  const int wr = (w >> 2) * 128, wc = (w & 3) * 64;
  const int nsel = n0 / 768;
  const int colbase = (n0 - nsel * 768) + wc;  // multiple of 64
  const int rbase = m0 + wr + lg * 4;
  const float* bias = g.bias[z][nsel];
  const int hh = colbase >> 6;

  if (nsel < 2) {
    f16* Y = nsel ? g.out1[z] : g.out0[z];
    float* term = nsel ? g.kterm : g.qterm;
    float bv4[4];
#pragma unroll
    for (int fj = 0; fj < 4; ++fj) bv4[fj] = bias[colbase + l15 + fj * 16];
#pragma unroll
    for (int fi = 0; fi < 8; ++fi) {
#pragma unroll
      for (int r = 0; r < 4; ++r) {
        const int row = rbase + fi * 16 + r;
        float ssum = 0.f;
#pragma unroll
        for (int fj = 0; fj < 4; ++fj) {
          float v = acc[fi][fj][r] + bv4[fj];
          if (z == 1) { v = (v > 0.f) ? v + 1.f : __expf(v); v = sqrtf(v); }
          const f16 st = (f16)(v * 0.5f);
          if (row < M) Y[(size_t)row * HID + colbase + l15 + fj * 16] = st;
          const float sf = (float)st;
          ssum = fmaf(sf, sf, ssum);
        }
        ssum += __shfl_xor(ssum, 1, 64);
        ssum += __shfl_xor(ssum, 2, 64);
        ssum += __shfl_xor(ssum, 4, 64);
        ssum += __shfl_xor(ssum, 8, 64);
        if (l15 == 0 && row < M) {
          const int bb = row / S, ss = row - bb * S;
          atomicAdd(&term[(bb * NH + hh) * S + ss], 0.5f * ssum);
        }
      }
    }
  } else {
    f16* VT = g.vt[z];
#pragma unroll
    for (int fj = 0; fj < 4; ++fj) {
      const int col = colbase + l15 + fj * 16;
      const float bv = bias[col];
      const int dd = col & 63;
#pragma unroll
      for (int fi = 0; fi < 8; ++fi)
#pragma unroll
        for (int r = 0; r < 4; ++r) {
          const int row = rbase + fi * 16 + r;
          if (row < M) {
            float v = acc[fi][fj][r] + bv;
            if (z == 1) v = (v > 0.f) ? v + 1.f : __expf(v);
            const int bb = row / S, ss = row - bb * S;
            VT[((size_t)(bb * NH + hh) * DH + dd) * VSTRIDE + ss] = (f16)v;
          }
        }
    }
  }
}

// ---------------- output GEMMs (z=0 mean, z=1 cov), f32 out ---------------
struct OutArgs {
  const f16* A[2]; const f16* Bt[2]; const float* bias[2]; float* Y[2];
};

__global__ __launch_bounds__(512, 1) void gemm_out(OutArgs g) {
  __shared__ alignas(16) char lds[98304];
  const int swz = xcd_swizzle(blockIdx.x, 300);
  const int z = swz / 150;
  const int rest = swz - z * 150;
  const int x = rest / 3, y = rest - x * 3;
  const int m0 = x * 256, n0 = y * 256;

  f32x4 acc[8][4] = {};
  gemm_core(g.A[z], g.Bt[z], m0, n0, threadIdx.x, lds, acc);

  const int tid = threadIdx.x, w = tid >> 6, lane = tid & 63;
  const int l15 = lane & 15, lg = lane >> 4;
  const int wr = (w >> 2) * 128, wc = (w & 3) * 64;
  const int rbase = m0 + wr + lg * 4;
  float* Y = g.Y[z];
#pragma unroll
  for (int fj = 0; fj < 4; ++fj) {
    const int col = n0 + wc + l15 + fj * 16;
    const float bv = g.bias[z][col];
#pragma unroll
    for (int fi = 0; fi < 8; ++fi)
#pragma unroll
      for (int r = 0; r < 4; ++r) {
        const int row = rbase + fi * 16 + r;
        if (row < M) Y[(size_t)row * HID + col] = acc[fi][fj][r] + bv;
      }
  }
}

// ---------------- fused Wasserstein attention ----------------
__global__ __launch_bounds__(256, 2) void attn_kernel(
    const f16* __restrict__ mq, const f16* __restrict__ sq,
    const f16* __restrict__ mk, const f16* __restrict__ sk,
    const f16* __restrict__ vtm, const f16* __restrict__ vtc,
    const float* __restrict__ qterm, const float* __restrict__ kterm,
    f16* __restrict__ mean_ctx, f16* __restrict__ cov_ctx) {
  __shared__ char Pb[64 * 512];  // P[q][j] f16, XOR-swizzled rows
  __shared__ float qt_s[64];
  __shared__ float kt_s[256];
  __shared__ float red_m[4][64];
  __shared__ float red_s[4][64];

  const int swz = xcd_swizzle(blockIdx.x, 3072);
  const int qtile = swz & 3, bh = swz >> 2;
  const int h = bh % NH, b = bh / NH;
  const int s0 = qtile * 64;
  const int tid = threadIdx.x, w = tid >> 6, lane = tid & 63;
  const int l15 = lane & 15, lg = lane >> 4;

  const size_t base = (size_t)(b * S) * HID + (size_t)h * DH;
  const int tb = bh * S;

  // Q fragments (B-operand): row = s0+fi*16+l15, k = lg*8 (+32)
  f16x8 qmf[4][2], qsf[4][2];
#pragma unroll
  for (int fi = 0; fi < 4; ++fi) {
    const size_t o = base + (size_t)(s0 + fi * 16 + l15) * HID + lg * 8;
    qmf[fi][0] = *reinterpret_cast<const f16x8*>(mq + o);
    qmf[fi][1] = *reinterpret_cast<const f16x8*>(mq + o + 32);
    qsf[fi][0] = *reinterpret_cast<const f16x8*>(sq + o);
    qsf[fi][1] = *reinterpret_cast<const f16x8*>(sq + o + 32);
  }
  if (tid < 64) qt_s[tid] = (s0 + tid < S) ? qterm[tb + s0 + tid] : 0.f;
  kt_s[tid] = (tid < S) ? kterm[tb + tid] : 0.f;
  __syncthreads();

  // scores^T: acc[fj][fi], rows = K tokens (wave-owned 64), cols = Q tokens
  f32x4 acc[4][4] = {};
  __builtin_amdgcn_s_setprio(1);
#pragma unroll
  for (int fj = 0; fj < 4; ++fj) {
    const size_t o = base + (size_t)(w * 64 + fj * 16 + l15) * HID + lg * 8;
    const f16x8 a0 = *reinterpret_cast<const f16x8*>(mk + o);
    const f16x8 a1 = *reinterpret_cast<const f16x8*>(mk + o + 32);
    const f16x8 c0 = *reinterpret_cast<const f16x8*>(sk + o);
    const f16x8 c1 = *reinterpret_cast<const f16x8*>(sk + o + 32);
#pragma unroll
    for (int fi = 0; fi < 4; ++fi) {
      acc[fj][fi] = mfma16(a0, qmf[fi][0], acc[fj][fi]);
      acc[fj][fi] = mfma16(c0, qsf[fi][0], acc[fj][fi]);
      acc[fj][fi] = mfma16(a1, qmf[fi][1], acc[fj][fi]);
      acc[fj][fi] = mfma16(c1, qsf[fi][1], acc[fj][fi]);
    }
  }
  __builtin_amdgcn_s_setprio(0);

  // issue Vt loads early (independent of softmax) -> registers
  const int d = w * 16 + l15;
  const size_t vbase = ((size_t)bh * DH + d) * VSTRIDE + lg * 8;
  f16x8 vmr[7], vcr[7];
#pragma unroll
  for (int ks = 0; ks < 7; ++ks) {
    vmr[ks] = *reinterpret_cast<const f16x8*>(vtm + vbase + ks * 32);
    vcr[ks] = *reinterpret_cast<const f16x8*>(vtc + vbase + ks * 32);
  }

  // transform + wave-partial row max
#pragma unroll
  for (int fi = 0; fi < 4; ++fi) {
    const float qv = qt_s[fi * 16 + l15];
    float mx = -1e30f;
#pragma unroll
    for (int fj = 0; fj < 4; ++fj)
#pragma unroll
      for (int r = 0; r < 4; ++r) {
        const int j = w * 64 + fj * 16 + lg * 4 + r;
        float sv = acc[fj][fi][r] - qv - kt_s[j];
        if (j >= S) sv = -1e30f;
        acc[fj][fi][r] = sv;
        mx = fmaxf(mx, sv);
      }
    mx = fmaxf(mx, __shfl_xor(mx, 16, 64));
    mx = fmaxf(mx, __shfl_xor(mx, 32, 64));
    if (lg == 0) red_m[w][fi * 16 + l15] = mx;
  }
  __syncthreads();

  // exp (unnormalized) -> P (b64 writes), partial sums
#pragma unroll
  for (int fi = 0; fi < 4; ++fi) {
    const int q = fi * 16 + l15;
    const float m = fmaxf(fmaxf(red_m[0][q], red_m[1][q]),
                          fmaxf(red_m[2][q], red_m[3][q]));
    const int xr = (q & 7) << 4;
    float sum = 0.f;
#pragma unroll
    for (int fj = 0; fj < 4; ++fj) {
      f16x4 p4;
#pragma unroll
      for (int r = 0; r < 4; ++r) {
        const float e = __expf(acc[fj][fi][r] - m);
        sum += e;
        p4[r] = (f16)e;
      }
      *reinterpret_cast<f16x4*>(
          Pb + q * 512 + ((2 * (w * 64 + fj * 16 + lg * 4)) ^ xr)) = p4;
    }
    sum += __shfl_xor(sum, 16, 64);
    sum += __shfl_xor(sum, 32, 64);
    if (lg == 0) red_s[w][q] = sum;
  }
  __syncthreads();

  // PV: A = P rows (q), B = Vt rows (d) from registers
  f32x4 macc[4] = {}, cacc[4] = {};
  __builtin_amdgcn_s_setprio(1);
#pragma unroll
  for (int ks = 0; ks < 7; ++ks) {
#pragma unroll
    for (int fi = 0; fi < 4; ++fi) {
      const int q = fi * 16 + l15;
      const f16x8 pa = *reinterpret_cast<const f16x8*>(
          Pb + q * 512 + ((2 * (ks * 32 + lg * 8)) ^ ((q & 7) << 4)));
      macc[fi] = mfma16(pa, vmr[ks], macc[fi]);
      const f16x8 pq = pa * pa;
      cacc[fi] = mfma16(pq, vcr[ks], cacc[fi]);
    }
  }
  __builtin_amdgcn_s_setprio(0);

  // epilogue: normalize by row sums
#pragma unroll
  for (int fi = 0; fi < 4; ++fi)
#pragma unroll
    for (int r = 0; r < 4; ++r) {
      const int qo = fi * 16 + lg * 4 + r;
      const int srow = s0 + qo;
      if (srow < S) {
        const float tot = red_s[0][qo] + red_s[1][qo] + red_s[2][qo] + red_s[3][qo];
        const float inv = 1.f / tot;
        const size_t oidx = (size_t)(b * S + srow) * HID + h * DH + d;
        mean_ctx[oidx] = (f16)(macc[fi][r] * inv);
        cov_ctx[oidx] = (f16)(cacc[fi][r] * inv * inv);
      }
    }
}

extern "C" void kernel_launch(void* const* d_in, const int* in_sizes, int n_in,
                              void* d_out, int out_size, void* d_ws, size_t ws_size,
                              hipStream_t stream) {
  const float* in_mean = (const float*)d_in[0];
  const float* in_cov = (const float*)d_in[1];
  const float* Wmq = (const float*)d_in[2];  const float* bmq = (const float*)d_in[3];
  const float* Wcq = (const float*)d_in[4];  const float* bcq = (const float*)d_in[5];
  const float* Wmk = (const float*)d_in[6];  const float* bmk = (const float*)d_in[7];
  const float* Wck = (const float*)d_in[8];  const float* bck = (const float*)d_in[9];
  const float* Wmv = (const float*)d_in[10]; const float* bmv = (const float*)d_in[11];
  const float* Wcv = (const float*)d_in[12]; const float* bcv = (const float*)d_in[13];
  const float* Wmd = (const float*)d_in[14]; const float* bmd = (const float*)d_in[15];
  const float* Wcd = (const float*)d_in[16]; const float* bcd = (const float*)d_in[17];

  const size_t need = (2 * NPH + 8 * WSZ1 + 4 * MH + 2 * VTSZ) * sizeof(f16) +
                      2 * (size_t)BNS * sizeof(float);
  if (ws_size < need) return;

  f16* Xm = (f16*)d_ws;          // later: mean_ctx
  f16* Xc = Xm + NPH;            // later: cov_ctx
  f16* Wt = Xc + NPH;
  f16* mq = Wt + 8 * WSZ1;
  f16* mk = mq + MH;
  f16* sq = mk + MH;
  f16* sk = sq + MH;
  f16* vtm = sk + MH;
  f16* vtc = vtm + VTSZ;
  float* qterm = (float*)(vtc + VTSZ);
  float* kterm = qterm + BNS;
  f16* mean_ctx = Xm;
  f16* cov_ctx = Xc;

  float* out_mean = (float*)d_out;
  float* out_cov = out_mean + MH;

  dim3 blk(256);

  // zero Vt + qterm + kterm (contiguous region starting at vtm)
  const size_t zbytes = 2 * VTSZ * sizeof(f16) + 2 * (size_t)BNS * sizeof(float);
  const size_t n16 = zbytes / 16;
  zero_kernel<<<(int)((n16 + 255) / 256), blk, 0, stream>>>((char*)vtm, n16);

  cvt_x_kernel<<<(int)(NPH / 2048), blk, 0, stream>>>(in_mean, in_cov, Xm, Xc);

  WPtrs wp;
  wp.w[0] = Wmq; wp.w[1] = Wmk; wp.w[2] = Wmv;
  wp.w[3] = Wcq; wp.w[4] = Wck; wp.w[5] = Wcv;
  wp.w[6] = Wmd; wp.w[7] = Wcd;
  cvt_w_kernel<<<dim3(24, 24, 8), blk, 0, stream>>>(wp, Wt);

  ProjArgs pa;
  pa.A[0] = Xm; pa.A[1] = Xc;
  pa.Bt[0] = Wt; pa.Bt[1] = Wt + 3 * WSZ1;
  pa.bias[0][0] = bmq; pa.bias[0][1] = bmk; pa.bias[0][2] = bmv;
  pa.bias[1][0] = bcq; pa.bias[1][1] = bck; pa.bias[1][2] = bcv;
  pa.out0[0] = mq; pa.out0[1] = sq;
  pa.out1[0] = mk; pa.out1[1] = sk;
  pa.vt[0] = vtm; pa.vt[1] = vtc;
  pa.qterm = qterm; pa.kterm = kterm;
  gemm_proj<<<900, dim3(512), 0, stream>>>(pa);

  attn_kernel<<<3072, blk, 0, stream>>>(mq, sq, mk, sk, vtm, vtc,
                                        qterm, kterm, mean_ctx, cov_ctx);

  OutArgs oa;
  oa.A[0] = mean_ctx; oa.A[1] = cov_ctx;
  oa.Bt[0] = Wt + 6 * WSZ1; oa.Bt[1] = Wt + 7 * WSZ1;
  oa.bias[0] = bmd; oa.bias[1] = bcd;
  oa.Y[0] = out_mean; oa.Y[1] = out_cov;
  gemm_out<<<300, dim3(512), 0, stream>>>(oa);
}

// Round 8
// 369.234 us; speedup vs baseline: 1.1563x; 1.0118x over previous
//
#include <hip/hip_runtime.h>
#include <hip/hip_bf16.h>
#include <stdint.h>

typedef _Float16 f16;
typedef _Float16 f16x8 __attribute__((ext_vector_type(8)));
typedef _Float16 f16x4 __attribute__((ext_vector_type(4)));
typedef float f32x4 __attribute__((ext_vector_type(4)));

constexpr int B = 64, S = 197, HID = 768, NH = 12, DH = 64;
constexpr int M = B * S;          // 12608
constexpr int Mpad = 12800;       // 50*256
constexpr int BNS = B * NH * S;   // 151296
constexpr int VSTRIDE = 224;      // 7*32 >= 197
constexpr size_t NPH = (size_t)Mpad * HID;
constexpr size_t MH = (size_t)M * HID;
constexpr size_t WSZ1 = (size_t)HID * HID;
constexpr size_t VTSZ = (size_t)B * NH * DH * VSTRIDE;

__device__ __forceinline__ f32x4 mfma16(f16x8 a, f16x8 b, f32x4 c) {
  return __builtin_amdgcn_mfma_f32_16x16x32_f16(a, b, c, 0, 0, 0);
}

__device__ __forceinline__ void gload16(const void* g, void* l) {
  __builtin_amdgcn_global_load_lds(
      (const __attribute__((address_space(1))) void*)g,
      (__attribute__((address_space(3))) void*)l, 16, 0, 0);
}

// bijective XCD-aware swizzle (m204)
__device__ __forceinline__ int xcd_swizzle(int wg, int nwg) {
  const int q = nwg >> 3, r = nwg & 7;
  const int x = wg & 7, p = wg >> 3;
  return (x < r ? x * (q + 1) : r * (q + 1) + (x - r) * q) + p;
}

// ---------------- zero fill (16B) ----------------
__global__ __launch_bounds__(256) void zero_kernel(char* __restrict__ p, size_t n16) {
  const size_t i = (size_t)blockIdx.x * 256 + threadIdx.x;
  if (i < n16) reinterpret_cast<int4*>(p)[i] = int4{0, 0, 0, 0};
}

// ---------------- f32 -> f16 (padded, zero tail) ----------------
__global__ __launch_bounds__(256) void cvt_x_kernel(
    const float* __restrict__ xm, const float* __restrict__ xc,
    f16* __restrict__ ym, f16* __restrict__ yc) {
  const size_t i8 = ((size_t)blockIdx.x * 256 + threadIdx.x) * 8;
  f16x8 vm = {}, vc = {};
  if (i8 < MH) {
    const float4 a0 = *reinterpret_cast<const float4*>(xm + i8);
    const float4 a1 = *reinterpret_cast<const float4*>(xm + i8 + 4);
    const float4 b0 = *reinterpret_cast<const float4*>(xc + i8);
    const float4 b1 = *reinterpret_cast<const float4*>(xc + i8 + 4);
    vm[0] = (f16)a0.x; vm[1] = (f16)a0.y; vm[2] = (f16)a0.z; vm[3] = (f16)a0.w;
    vm[4] = (f16)a1.x; vm[5] = (f16)a1.y; vm[6] = (f16)a1.z; vm[7] = (f16)a1.w;
    vc[0] = (f16)b0.x; vc[1] = (f16)b0.y; vc[2] = (f16)b0.z; vc[3] = (f16)b0.w;
    vc[4] = (f16)b1.x; vc[5] = (f16)b1.y; vc[6] = (f16)b1.z; vc[7] = (f16)b1.w;
  }
  *reinterpret_cast<f16x8*>(ym + i8) = vm;
  *reinterpret_cast<f16x8*>(yc + i8) = vc;
}

// ---------------- W [k][n] f32 -> Wt [n][k] f16 ----------------
struct WPtrs { const float* w[8]; };

__global__ __launch_bounds__(256) void cvt_w_kernel(WPtrs p, f16* __restrict__ wt) {
  __shared__ float tile[32][33];
  const int z = blockIdx.z;
  const float* W = p.w[z];
  f16* Wt = wt + (size_t)z * WSZ1;
  const int k0 = blockIdx.x * 32, n0 = blockIdx.y * 32;
  const int tx = threadIdx.x & 31, ty = threadIdx.x >> 5;
#pragma unroll
  for (int i = 0; i < 4; ++i)
    tile[ty + i * 8][tx] = W[(size_t)(k0 + ty + i * 8) * HID + n0 + tx];
  __syncthreads();
#pragma unroll
  for (int i = 0; i < 4; ++i)
    Wt[(size_t)(n0 + ty + i * 8) * HID + k0 + tx] = (f16)tile[tx][ty + i * 8];
}

// ---------------- 8-phase MFMA GEMM core (256x256, 512 thr, K=768) --------
// T3+T4: 6 iterations x 8 phases, 2 K-steps (BK=64) per iteration.
// LDS: dbuf d in [d*64KB, d*64KB+64KB): A tile 256x64 f16 (rows 128 B) then
// B tile at +32KB. Slot swizzle: phys 16B-slot p of row r holds k-slot
// p ^ (r&7); staged with pre-swizzled per-lane global source (linear LDS
// dest), read at slot (ks*4+lg)^(l15&7). Counted vmcnt(4) at phases 3/7 only.
__device__ __forceinline__ void gemm_core(
    const f16* __restrict__ Abase, const f16* __restrict__ Btbase,
    int m0, int n0, int tid, char* lds, f32x4 (&acc)[8][4]) {
  const int w = tid >> 6, lane = tid & 63;
  const int l15 = lane & 15, lg = lane >> 4;
  const int wr = (w >> 2) * 128, wc = (w & 3) * 64;

  // staging source: lane covers row w*8 + (lane>>3) (+ h*128 + g*64), slot-swizzled
  const int lrow = w * 8 + (lane >> 3);
  const int lslot = ((lane & 7) ^ ((lane >> 3) & 7)) * 16;
  const char* gA = reinterpret_cast<const char*>(Abase + (size_t)(m0 + lrow) * HID) + lslot;
  const char* gB = reinterpret_cast<const char*>(Btbase + (size_t)(n0 + lrow) * HID) + lslot;
  const int wrow = w * 8;  // wave-uniform LDS row base (HW adds lane*16 = 8 rows)

  // fragment-read slot bytes for ks=0 / ks=1
  const int sK0 = (((0 + lg) ^ (l15 & 7)) * 16);
  const int sK1 = (((4 + lg) ^ (l15 & 7)) * 16);

  f16x8 af[8][2], bf[4][2];

#define STG_A(k, d, h, g)                                                   \
  gload16(gA + (size_t)((h) * 128 + (g) * 64) * 1536 + (k) * 128,           \
          lds + (d) * 65536 + ((h) * 128 + (g) * 64 + wrow) * 128)
#define STG_B(k, d, h, g)                                                   \
  gload16(gB + (size_t)((h) * 128 + (g) * 64) * 1536 + (k) * 128,           \
          lds + (d) * 65536 + 32768 + ((h) * 128 + (g) * 64 + wrow) * 128)
#define STG_AH(k, d, h) do { STG_A(k, d, h, 0); STG_A(k, d, h, 1); } while (0)
#define STG_BH(k, d, h) do { STG_B(k, d, h, 0); STG_B(k, d, h, 1); } while (0)

#define READS_P0(d)                                                          \
  do {                                                                       \
    const char* base_ = lds + (d) * 65536;                                   \
    _Pragma("unroll") for (int fi = 0; fi < 4; ++fi) {                       \
      af[fi][0] = *reinterpret_cast<const f16x8*>(                           \
          base_ + (wr + l15 + fi * 16) * 128 + sK0);                         \
      af[fi][1] = *reinterpret_cast<const f16x8*>(                           \
          base_ + (wr + l15 + fi * 16) * 128 + sK1);                         \
    }                                                                        \
    _Pragma("unroll") for (int fj = 0; fj < 4; ++fj)                         \
      bf[fj][0] = *reinterpret_cast<const f16x8*>(                           \
          base_ + 32768 + (wc + l15 + fj * 16) * 128 + sK0);                 \
  } while (0)
#define READS_P1(d)                                                          \
  do {                                                                       \
    const char* base_ = lds + (d) * 65536;                                   \
    _Pragma("unroll") for (int fi = 4; fi < 8; ++fi) {                       \
      af[fi][0] = *reinterpret_cast<const f16x8*>(                           \
          base_ + (wr + l15 + fi * 16) * 128 + sK0);                         \
      af[fi][1] = *reinterpret_cast<const f16x8*>(                           \
          base_ + (wr + l15 + fi * 16) * 128 + sK1);                         \
    }                                                                        \
    _Pragma("unroll") for (int fj = 0; fj < 4; ++fj)                         \
      bf[fj][1] = *reinterpret_cast<const f16x8*>(                           \
          base_ + 32768 + (wc + l15 + fj * 16) * 128 + sK1);                 \
  } while (0)

#define MFMA_Q(fib, ks)                                                      \
  do {                                                                       \
    __builtin_amdgcn_s_setprio(1);                                           \
    _Pragma("unroll") for (int fi = (fib); fi < (fib) + 4; ++fi)             \
      _Pragma("unroll") for (int fj = 0; fj < 4; ++fj)                       \
        acc[fi][fj] = mfma16(af[fi][ks], bf[fj][ks], acc[fi][fj]);           \
    __builtin_amdgcn_s_setprio(0);                                           \
  } while (0)

#define BAR asm volatile("s_barrier" ::: "memory")
#define LGK0 asm volatile("s_waitcnt lgkmcnt(0)" ::: "memory")
#define VMC4_BAR asm volatile("s_waitcnt vmcnt(4)\n\ts_barrier" ::: "memory")
#define VMC0_BAR asm volatile("s_waitcnt vmcnt(0)\n\ts_barrier" ::: "memory")

  // prologue: K-steps 0 -> dbuf0, 1 -> dbuf1 (16 loads); wait K-step 0
  STG_AH(0, 0, 0); STG_AH(0, 0, 1); STG_BH(0, 0, 0); STG_BH(0, 0, 1);
  STG_AH(1, 1, 0); STG_AH(1, 1, 1); STG_BH(1, 1, 0); STG_BH(1, 1, 1);
  asm volatile("s_waitcnt vmcnt(8)\n\ts_barrier" ::: "memory");

#pragma unroll
  for (int i = 0; i < 6; ++i) {
    const int k1 = 2 * i + 1, kn0 = 2 * i + 2, kn1 = 2 * i + 3;
    // Ph0
    READS_P0(0);
    if (i > 0) STG_BH(k1, 1, 0);
    BAR; LGK0; MFMA_Q(0, 0); BAR;
    // Ph1  (all dbuf0 reads complete past this phase's barrier)
    READS_P1(0);
    if (i > 0) STG_BH(k1, 1, 1);
    BAR; LGK0; MFMA_Q(4, 0); BAR;
    // Ph2
    if (i < 5) STG_AH(kn0, 0, 0);
    BAR; LGK0; MFMA_Q(0, 1); BAR;
    // Ph3  (end: wait k1 fully landed, keep kn0-A in flight)
    if (i < 5) STG_AH(kn0, 0, 1);
    BAR; LGK0; MFMA_Q(4, 1);
    if (i < 5) { VMC4_BAR; } else { VMC0_BAR; }
    // Ph4
    READS_P0(1);
    if (i < 5) STG_BH(kn0, 0, 0);
    BAR; LGK0; MFMA_Q(0, 0); BAR;
    // Ph5  (all dbuf1 reads complete past this phase's barrier)
    READS_P1(1);
    if (i < 5) STG_BH(kn0, 0, 1);
    BAR; LGK0; MFMA_Q(4, 0); BAR;
    // Ph6
    if (i < 5) STG_AH(kn1, 1, 0);
    BAR; LGK0; MFMA_Q(0, 1); BAR;
    // Ph7  (end: wait kn0 fully landed, keep kn1-A in flight)
    if (i < 5) STG_AH(kn1, 1, 1);
    BAR; LGK0; MFMA_Q(4, 1);
    if (i < 5) { VMC4_BAR; }
  }
#undef STG_A
#undef STG_B
#undef STG_AH
#undef STG_BH
#undef READS_P0
#undef READS_P1
#undef MFMA_Q
#undef BAR
#undef LGK0
#undef VMC4_BAR
#undef VMC0_BAR
}

// ---------------- projection GEMMs (z=0 mean, z=1 cov) ----------------
struct ProjArgs {
  const f16* A[2]; const f16* Bt[2];
  const float* bias[2][3];
  f16* out0[2];  // nsel 0: mq / sq   (scaled 0.5, M rows)
  f16* out1[2];  // nsel 1: mk / sk   (scaled 0.5, M rows)
  f16* vt[2];    // nsel 2: Vt mean / cov (transposed, unscaled)
  float* qterm; float* kterm;  // fused row sums (atomic)
};

__global__ __launch_bounds__(512, 2) void gemm_proj(ProjArgs g) {
  __shared__ alignas(16) char lds[131072];
  const int swz = xcd_swizzle(blockIdx.x, 900);
  const int z = swz / 450;
  const int rest = swz - z * 450;
  const int x = rest / 9, y = rest - x * 9;  // y fastest: A panel L2-reuse
  const int m0 = x * 256, n0 = y * 256;

  f32x4 acc[8][4] = {};
  gemm_core(g.A[z], g.Bt[z], m0, n0, threadIdx.x, lds, acc);

  const int tid = threadIdx.x, w = tid >> 6, lane = tid & 63;
  const int l15 = lane & 15, lg = lane >> 4;
  const int wr = (w >> 2) * 128, wc = (w & 3) * 64;
  const int nsel = n0 / 768;
  const int colbase = (n0 - nsel * 768) + wc;  // multiple of 64
  const int rbase = m0 + wr + lg * 4;
  const float* bias = g.bias[z][nsel];
  const int hh = colbase >> 6;

  if (nsel < 2) {
    f16* Y = nsel ? g.out1[z] : g.out0[z];
    float* term = nsel ? g.kterm : g.qterm;
    float bv4[4];
#pragma unroll
    for (int fj = 0; fj < 4; ++fj) bv4[fj] = bias[colbase + l15 + fj * 16];
#pragma unroll
    for (int fi = 0; fi < 8; ++fi) {
#pragma unroll
      for (int r = 0; r < 4; ++r) {
        const int row = rbase + fi * 16 + r;
        float ssum = 0.f;
#pragma unroll
        for (int fj = 0; fj < 4; ++fj) {
          float v = acc[fi][fj][r] + bv4[fj];
          if (z == 1) { v = (v > 0.f) ? v + 1.f : __expf(v); v = sqrtf(v); }
          const f16 st = (f16)(v * 0.5f);
          if (row < M) Y[(size_t)row * HID + colbase + l15 + fj * 16] = st;
          const float sf = (float)st;
          ssum = fmaf(sf, sf, ssum);
        }
        ssum += __shfl_xor(ssum, 1, 64);
        ssum += __shfl_xor(ssum, 2, 64);
        ssum += __shfl_xor(ssum, 4, 64);
        ssum += __shfl_xor(ssum, 8, 64);
        if (l15 == 0 && row < M) {
          const int bb = row / S, ss = row - bb * S;
          atomicAdd(&term[(bb * NH + hh) * S + ss], 0.5f * ssum);
        }
      }
    }
  } else {
    f16* VT = g.vt[z];
#pragma unroll
    for (int fj = 0; fj < 4; ++fj) {
      const int col = colbase + l15 + fj * 16;
      const float bv = bias[col];
      const int dd = col & 63;
#pragma unroll
      for (int fi = 0; fi < 8; ++fi)
#pragma unroll
        for (int r = 0; r < 4; ++r) {
          const int row = rbase + fi * 16 + r;
          if (row < M) {
            float v = acc[fi][fj][r] + bv;
            if (z == 1) v = (v > 0.f) ? v + 1.f : __expf(v);
            const int bb = row / S, ss = row - bb * S;
            VT[((size_t)(bb * NH + hh) * DH + dd) * VSTRIDE + ss] = (f16)v;
          }
        }
    }
  }
}

// ---------------- output GEMMs (z=0 mean, z=1 cov), f32 out ---------------
struct OutArgs {
  const f16* A[2]; const f16* Bt[2]; const float* bias[2]; float* Y[2];
};

__global__ __launch_bounds__(512, 2) void gemm_out(OutArgs g) {
  __shared__ alignas(16) char lds[131072];
  const int swz = xcd_swizzle(blockIdx.x, 300);
  const int z = swz / 150;
  const int rest = swz - z * 150;
  const int x = rest / 3, y = rest - x * 3;
  const int m0 = x * 256, n0 = y * 256;

  f32x4 acc[8][4] = {};
  gemm_core(g.A[z], g.Bt[z], m0, n0, threadIdx.x, lds, acc);

  const int tid = threadIdx.x, w = tid >> 6, lane = tid & 63;
  const int l15 = lane & 15, lg = lane >> 4;
  const int wr = (w >> 2) * 128, wc = (w & 3) * 64;
  const int rbase = m0 + wr + lg * 4;
  float* Y = g.Y[z];
#pragma unroll
  for (int fj = 0; fj < 4; ++fj) {
    const int col = n0 + wc + l15 + fj * 16;
    const float bv = g.bias[z][col];
#pragma unroll
    for (int fi = 0; fi < 8; ++fi)
#pragma unroll
      for (int r = 0; r < 4; ++r) {
        const int row = rbase + fi * 16 + r;
        if (row < M) Y[(size_t)row * HID + col] = acc[fi][fj][r] + bv;
      }
  }
}

// ---------------- fused Wasserstein attention ----------------
__global__ __launch_bounds__(256, 2) void attn_kernel(
    const f16* __restrict__ mq, const f16* __restrict__ sq,
    const f16* __restrict__ mk, const f16* __restrict__ sk,
    const f16* __restrict__ vtm, const f16* __restrict__ vtc,
    const float* __restrict__ qterm, const float* __restrict__ kterm,
    f16* __restrict__ mean_ctx, f16* __restrict__ cov_ctx) {
  __shared__ char Pb[64 * 512];  // P[q][j] f16, XOR-swizzled rows
  __shared__ float qt_s[64];
  __shared__ float kt_s[256];
  __shared__ float red_m[4][64];
  __shared__ float red_s[4][64];

  const int swz = xcd_swizzle(blockIdx.x, 3072);
  const int qtile = swz & 3, bh = swz >> 2;
  const int h = bh % NH, b = bh / NH;
  const int s0 = qtile * 64;
  const int tid = threadIdx.x, w = tid >> 6, lane = tid & 63;
  const int l15 = lane & 15, lg = lane >> 4;

  const size_t base = (size_t)(b * S) * HID + (size_t)h * DH;
  const int tb = bh * S;

  // Q fragments (B-operand): row = s0+fi*16+l15, k = lg*8 (+32)
  f16x8 qmf[4][2], qsf[4][2];
#pragma unroll
  for (int fi = 0; fi < 4; ++fi) {
    const size_t o = base + (size_t)(s0 + fi * 16 + l15) * HID + lg * 8;
    qmf[fi][0] = *reinterpret_cast<const f16x8*>(mq + o);
    qmf[fi][1] = *reinterpret_cast<const f16x8*>(mq + o + 32);
    qsf[fi][0] = *reinterpret_cast<const f16x8*>(sq + o);
    qsf[fi][1] = *reinterpret_cast<const f16x8*>(sq + o + 32);
  }
  if (tid < 64) qt_s[tid] = (s0 + tid < S) ? qterm[tb + s0 + tid] : 0.f;
  kt_s[tid] = (tid < S) ? kterm[tb + tid] : 0.f;
  __syncthreads();

  // scores^T: acc[fj][fi], rows = K tokens (wave-owned 64), cols = Q tokens
  f32x4 acc[4][4] = {};
  __builtin_amdgcn_s_setprio(1);
#pragma unroll
  for (int fj = 0; fj < 4; ++fj) {
    const size_t o = base + (size_t)(w * 64 + fj * 16 + l15) * HID + lg * 8;
    const f16x8 a0 = *reinterpret_cast<const f16x8*>(mk + o);
    const f16x8 a1 = *reinterpret_cast<const f16x8*>(mk + o + 32);
    const f16x8 c0 = *reinterpret_cast<const f16x8*>(sk + o);
    const f16x8 c1 = *reinterpret_cast<const f16x8*>(sk + o + 32);
#pragma unroll
    for (int fi = 0; fi < 4; ++fi) {
      acc[fj][fi] = mfma16(a0, qmf[fi][0], acc[fj][fi]);
      acc[fj][fi] = mfma16(c0, qsf[fi][0], acc[fj][fi]);
      acc[fj][fi] = mfma16(a1, qmf[fi][1], acc[fj][fi]);
      acc[fj][fi] = mfma16(c1, qsf[fi][1], acc[fj][fi]);
    }
  }
  __builtin_amdgcn_s_setprio(0);

  // issue Vt loads early (independent of softmax) -> registers
  const int d = w * 16 + l15;
  const size_t vbase = ((size_t)bh * DH + d) * VSTRIDE + lg * 8;
  f16x8 vmr[7], vcr[7];
#pragma unroll
  for (int ks = 0; ks < 7; ++ks) {
    vmr[ks] = *reinterpret_cast<const f16x8*>(vtm + vbase + ks * 32);
    vcr[ks] = *reinterpret_cast<const f16x8*>(vtc + vbase + ks * 32);
  }

  // transform + wave-partial row max
#pragma unroll
  for (int fi = 0; fi < 4; ++fi) {
    const float qv = qt_s[fi * 16 + l15];
    float mx = -1e30f;
#pragma unroll
    for (int fj = 0; fj < 4; ++fj)
#pragma unroll
      for (int r = 0; r < 4; ++r) {
        const int j = w * 64 + fj * 16 + lg * 4 + r;
        float sv = acc[fj][fi][r] - qv - kt_s[j];
        if (j >= S) sv = -1e30f;
        acc[fj][fi][r] = sv;
        mx = fmaxf(mx, sv);
      }
    mx = fmaxf(mx, __shfl_xor(mx, 16, 64));
    mx = fmaxf(mx, __shfl_xor(mx, 32, 64));
    if (lg == 0) red_m[w][fi * 16 + l15] = mx;
  }
  __syncthreads();

  // exp (unnormalized) -> P (b64 writes), partial sums
#pragma unroll
  for (int fi = 0; fi < 4; ++fi) {
    const int q = fi * 16 + l15;
    const float m = fmaxf(fmaxf(red_m[0][q], red_m[1][q]),
                          fmaxf(red_m[2][q], red_m[3][q]));
    const int xr = (q & 7) << 4;
    float sum = 0.f;
#pragma unroll
    for (int fj = 0; fj < 4; ++fj) {
      f16x4 p4;
#pragma unroll
      for (int r = 0; r < 4; ++r) {
        const float e = __expf(acc[fj][fi][r] - m);
        sum += e;
        p4[r] = (f16)e;
      }
      *reinterpret_cast<f16x4*>(
          Pb + q * 512 + ((2 * (w * 64 + fj * 16 + lg * 4)) ^ xr)) = p4;
    }
    sum += __shfl_xor(sum, 16, 64);
    sum += __shfl_xor(sum, 32, 64);
    if (lg == 0) red_s[w][q] = sum;
  }
  __syncthreads();

  // PV: A = P rows (q), B = Vt rows (d) from registers
  f32x4 macc[4] = {}, cacc[4] = {};
  __builtin_amdgcn_s_setprio(1);
#pragma unroll
  for (int ks = 0; ks < 7; ++ks) {
#pragma unroll
    for (int fi = 0; fi < 4; ++fi) {
      const int q = fi * 16 + l15;
      const f16x8 pa = *reinterpret_cast<const f16x8*>(
          Pb + q * 512 + ((2 * (ks * 32 + lg * 8)) ^ ((q & 7) << 4)));
      macc[fi] = mfma16(pa, vmr[ks], macc[fi]);
      const f16x8 pq = pa * pa;
      cacc[fi] = mfma16(pq, vcr[ks], cacc[fi]);
    }
  }
  __builtin_amdgcn_s_setprio(0);

  // epilogue: normalize by row sums
#pragma unroll
  for (int fi = 0; fi < 4; ++fi)
#pragma unroll
    for (int r = 0; r < 4; ++r) {
      const int qo = fi * 16 + lg * 4 + r;
      const int srow = s0 + qo;
      if (srow < S) {
        const float tot = red_s[0][qo] + red_s[1][qo] + red_s[2][qo] + red_s[3][qo];
        const float inv = 1.f / tot;
        const size_t oidx = (size_t)(b * S + srow) * HID + h * DH + d;
        mean_ctx[oidx] = (f16)(macc[fi][r] * inv);
        cov_ctx[oidx] = (f16)(cacc[fi][r] * inv * inv);
      }
    }
}

extern "C" void kernel_launch(void* const* d_in, const int* in_sizes, int n_in,
                              void* d_out, int out_size, void* d_ws, size_t ws_size,
                              hipStream_t stream) {
  const float* in_mean = (const float*)d_in[0];
  const float* in_cov = (const float*)d_in[1];
  const float* Wmq = (const float*)d_in[2];  const float* bmq = (const float*)d_in[3];
  const float* Wcq = (const float*)d_in[4];  const float* bcq = (const float*)d_in[5];
  const float* Wmk = (const float*)d_in[6];  const float* bmk = (const float*)d_in[7];
  const float* Wck = (const float*)d_in[8];  const float* bck = (const float*)d_in[9];
  const float* Wmv = (const float*)d_in[10]; const float* bmv = (const float*)d_in[11];
  const float* Wcv = (const float*)d_in[12]; const float* bcv = (const float*)d_in[13];
  const float* Wmd = (const float*)d_in[14]; const float* bmd = (const float*)d_in[15];
  const float* Wcd = (const float*)d_in[16]; const float* bcd = (const float*)d_in[17];

  const size_t need = (2 * NPH + 8 * WSZ1 + 4 * MH + 2 * VTSZ) * sizeof(f16) +
                      2 * (size_t)BNS * sizeof(float);
  if (ws_size < need) return;

  f16* Xm = (f16*)d_ws;          // later: mean_ctx
  f16* Xc = Xm + NPH;            // later: cov_ctx
  f16* Wt = Xc + NPH;
  f16* mq = Wt + 8 * WSZ1;
  f16* mk = mq + MH;
  f16* sq = mk + MH;
  f16* sk = sq + MH;
  f16* vtm = sk + MH;
  f16* vtc = vtm + VTSZ;
  float* qterm = (float*)(vtc + VTSZ);
  float* kterm = qterm + BNS;
  f16* mean_ctx = Xm;
  f16* cov_ctx = Xc;

  float* out_mean = (float*)d_out;
  float* out_cov = out_mean + MH;

  dim3 blk(256);

  // zero Vt + qterm + kterm (contiguous region starting at vtm)
  const size_t zbytes = 2 * VTSZ * sizeof(f16) + 2 * (size_t)BNS * sizeof(float);
  const size_t n16 = zbytes / 16;
  zero_kernel<<<(int)((n16 + 255) / 256), blk, 0, stream>>>((char*)vtm, n16);

  cvt_x_kernel<<<(int)(NPH / 2048), blk, 0, stream>>>(in_mean, in_cov, Xm, Xc);

  WPtrs wp;
  wp.w[0] = Wmq; wp.w[1] = Wmk; wp.w[2] = Wmv;
  wp.w[3] = Wcq; wp.w[4] = Wck; wp.w[5] = Wcv;
  wp.w[6] = Wmd; wp.w[7] = Wcd;
  cvt_w_kernel<<<dim3(24, 24, 8), blk, 0, stream>>>(wp, Wt);

  ProjArgs pa;
  pa.A[0] = Xm; pa.A[1] = Xc;
  pa.Bt[0] = Wt; pa.Bt[1] = Wt + 3 * WSZ1;
  pa.bias[0][0] = bmq; pa.bias[0][1] = bmk; pa.bias[0][2] = bmv;
  pa.bias[1][0] = bcq; pa.bias[1][1] = bck; pa.bias[1][2] = bcv;
  pa.out0[0] = mq; pa.out0[1] = sq;
  pa.out1[0] = mk; pa.out1[1] = sk;
  pa.vt[0] = vtm; pa.vt[1] = vtc;
  pa.qterm = qterm; pa.kterm = kterm;
  gemm_proj<<<900, dim3(512), 0, stream>>>(pa);

  attn_kernel<<<3072, blk, 0, stream>>>(mq, sq, mk, sk, vtm, vtc,
                                        qterm, kterm, mean_ctx, cov_ctx);

  OutArgs oa;
  oa.A[0] = mean_ctx; oa.A[1] = cov_ctx;
  oa.Bt[0] = Wt + 6 * WSZ1; oa.Bt[1] = Wt + 7 * WSZ1;
  oa.bias[0] = bmd; oa.bias[1] = bcd;
  oa.Y[0] = out_mean; oa.Y[1] = out_cov;
  gemm_out<<<300, dim3(512), 0, stream>>>(oa);
}

// Round 9
// 366.313 us; speedup vs baseline: 1.1655x; 1.0080x over previous
//
#include <hip/hip_runtime.h>
#include <hip/hip_bf16.h>
#include <stdint.h>

typedef _Float16 f16;
typedef _Float16 f16x8 __attribute__((ext_vector_type(8)));
typedef _Float16 f16x4 __attribute__((ext_vector_type(4)));
typedef float f32x4 __attribute__((ext_vector_type(4)));

constexpr int B = 64, S = 197, HID = 768, NH = 12, DH = 64;
constexpr int M = B * S;          // 12608
constexpr int Mpad = 12800;       // 100*128
constexpr int BNS = B * NH * S;   // 151296
constexpr int VSTRIDE = 224;      // 7*32 >= 197
constexpr size_t NPH = (size_t)Mpad * HID;
constexpr size_t MH = (size_t)M * HID;
constexpr size_t WSZ1 = (size_t)HID * HID;
constexpr size_t VTSZ = (size_t)B * NH * DH * VSTRIDE;

__device__ __forceinline__ f32x4 mfma16(f16x8 a, f16x8 b, f32x4 c) {
  return __builtin_amdgcn_mfma_f32_16x16x32_f16(a, b, c, 0, 0, 0);
}

__device__ __forceinline__ void gload16(const void* g, void* l) {
  __builtin_amdgcn_global_load_lds(
      (const __attribute__((address_space(1))) void*)g,
      (__attribute__((address_space(3))) void*)l, 16, 0, 0);
}

// bijective XCD-aware swizzle (m204)
__device__ __forceinline__ int xcd_swizzle(int wg, int nwg) {
  const int q = nwg >> 3, r = nwg & 7;
  const int x = wg & 7, p = wg >> 3;
  return (x < r ? x * (q + 1) : r * (q + 1) + (x - r) * q) + p;
}

// ---------------- zero fill (16B) ----------------
__global__ __launch_bounds__(256) void zero_kernel(char* __restrict__ p, size_t n16) {
  const size_t i = (size_t)blockIdx.x * 256 + threadIdx.x;
  if (i < n16) reinterpret_cast<int4*>(p)[i] = int4{0, 0, 0, 0};
}

// ---------------- f32 -> f16 (padded, zero tail) ----------------
__global__ __launch_bounds__(256) void cvt_x_kernel(
    const float* __restrict__ xm, const float* __restrict__ xc,
    f16* __restrict__ ym, f16* __restrict__ yc) {
  const size_t i8 = ((size_t)blockIdx.x * 256 + threadIdx.x) * 8;
  f16x8 vm = {}, vc = {};
  if (i8 < MH) {
    const float4 a0 = *reinterpret_cast<const float4*>(xm + i8);
    const float4 a1 = *reinterpret_cast<const float4*>(xm + i8 + 4);
    const float4 b0 = *reinterpret_cast<const float4*>(xc + i8);
    const float4 b1 = *reinterpret_cast<const float4*>(xc + i8 + 4);
    vm[0] = (f16)a0.x; vm[1] = (f16)a0.y; vm[2] = (f16)a0.z; vm[3] = (f16)a0.w;
    vm[4] = (f16)a1.x; vm[5] = (f16)a1.y; vm[6] = (f16)a1.z; vm[7] = (f16)a1.w;
    vc[0] = (f16)b0.x; vc[1] = (f16)b0.y; vc[2] = (f16)b0.z; vc[3] = (f16)b0.w;
    vc[4] = (f16)b1.x; vc[5] = (f16)b1.y; vc[6] = (f16)b1.z; vc[7] = (f16)b1.w;
  }
  *reinterpret_cast<f16x8*>(ym + i8) = vm;
  *reinterpret_cast<f16x8*>(yc + i8) = vc;
}

// ---------------- W [k][n] f32 -> Wt [n][k] f16 ----------------
struct WPtrs { const float* w[8]; };

__global__ __launch_bounds__(256) void cvt_w_kernel(WPtrs p, f16* __restrict__ wt) {
  __shared__ float tile[32][33];
  const int z = blockIdx.z;
  const float* W = p.w[z];
  f16* Wt = wt + (size_t)z * WSZ1;
  const int k0 = blockIdx.x * 32, n0 = blockIdx.y * 32;
  const int tx = threadIdx.x & 31, ty = threadIdx.x >> 5;
#pragma unroll
  for (int i = 0; i < 4; ++i)
    tile[ty + i * 8][tx] = W[(size_t)(k0 + ty + i * 8) * HID + n0 + tx];
  __syncthreads();
#pragma unroll
  for (int i = 0; i < 4; ++i)
    Wt[(size_t)(n0 + ty + i * 8) * HID + k0 + tx] = (f16)tile[tx][ty + i * 8];
}

// ---------------- MFMA GEMM core (128x256 tile, 512 thr, K=768) -----------
// BK=32, 3 LDS buffers (72 KB -> 2 blocks/CU), counted-vmcnt pipeline:
// iter t stages tile t+2 (3 loads), computes tile t, waits vmcnt(3), one
// s_barrier per K-tile. Slot swizzle (verified 0-conflict in R7): phys
// 16B-slot p of row r holds k-slot p ^ ((r>>1)&3); linear gload_lds dest +
// pre-swizzled per-lane global source; reads at slot (lg ^ (l15>>1))&3.
__device__ __forceinline__ void gemm_core(
    const f16* __restrict__ Abase, const f16* __restrict__ Btbase,
    int m0, int n0, int tid, char* lds, f32x4 (&acc)[4][4]) {
  const int w = tid >> 6, lane = tid & 63;
  const int l15 = lane & 15, lg = lane >> 4;
  const int wr = (w >> 2) * 64, wc = (w & 3) * 64;

  // staging: A rows w*16..+15 (1 load/lane), B rows w*32..+31 (2 loads/lane)
  const int arow = w * 16 + (lane >> 2);
  const int brow = w * 32 + (lane >> 2);
  const int scol = (((lane & 3) ^ ((lane >> 3) & 3)) * 16);  // pre-swizzled src
  const char* gA = reinterpret_cast<const char*>(Abase + (size_t)(m0 + arow) * HID) + scol;
  const char* gB = reinterpret_cast<const char*>(Btbase + (size_t)(n0 + brow) * HID) + scol;

  const int rslot = ((lg ^ (l15 >> 1)) & 3) * 16;

#define STAGE_TILE(T, BUF)                                               \
  do {                                                                   \
    const size_t off_ = (size_t)(T) * 64;                                \
    char* bp_ = lds + (BUF) * 24576;                                     \
    gload16(gA + off_, bp_ + w * 1024);                                  \
    gload16(gB + off_, bp_ + 8192 + w * 2048);                           \
    gload16(gB + off_ + (size_t)16 * 1536, bp_ + 8192 + w * 2048 + 1024);\
  } while (0)

  STAGE_TILE(0, 0);
  STAGE_TILE(1, 1);
  asm volatile("s_waitcnt vmcnt(3)\n\ts_barrier" ::: "memory");

#pragma unroll
  for (int t = 0; t < 24; ++t) {
    if (t + 2 < 24) STAGE_TILE(t + 2, (t + 2) % 3);

    const char* cb = lds + (t % 3) * 24576;
    f16x8 af[4], bf[4];
#pragma unroll
    for (int fi = 0; fi < 4; ++fi)
      af[fi] = *reinterpret_cast<const f16x8*>(cb + (wr + l15 + fi * 16) * 64 + rslot);
#pragma unroll
    for (int fj = 0; fj < 4; ++fj)
      bf[fj] = *reinterpret_cast<const f16x8*>(
          cb + 8192 + (wc + l15 + fj * 16) * 64 + rslot);

    __builtin_amdgcn_s_setprio(1);
#pragma unroll
    for (int fi = 0; fi < 4; ++fi)
#pragma unroll
      for (int fj = 0; fj < 4; ++fj)
        acc[fi][fj] = mfma16(af[fi], bf[fj], acc[fi][fj]);
    __builtin_amdgcn_s_setprio(0);

    if (t + 2 < 24) {
      asm volatile("s_waitcnt vmcnt(3)\n\ts_barrier" ::: "memory");
    } else if (t + 1 < 24) {
      asm volatile("s_waitcnt vmcnt(0)\n\ts_barrier" ::: "memory");
    }
  }
#undef STAGE_TILE
}

// ---------------- projection GEMMs (z=0 mean, z=1 cov) ----------------
struct ProjArgs {
  const f16* A[2]; const f16* Bt[2];
  const float* bias[2][3];
  f16* out0[2];  // nsel 0: mq / sq   (scaled 0.5, M rows)
  f16* out1[2];  // nsel 1: mk / sk   (scaled 0.5, M rows)
  f16* vt[2];    // nsel 2: Vt mean / cov (transposed, unscaled)
  float* qterm; float* kterm;  // fused row sums (atomic)
};

__global__ __launch_bounds__(512, 2) void gemm_proj(ProjArgs g) {
  __shared__ alignas(16) char lds[73728];
  const int swz = xcd_swizzle(blockIdx.x, 1800);
  const int z = swz / 900;
  const int rest = swz - z * 900;
  const int x = rest / 9, y = rest - x * 9;  // y fastest: A panel L2-reuse
  const int m0 = x * 128, n0 = y * 256;

  f32x4 acc[4][4] = {};
  gemm_core(g.A[z], g.Bt[z], m0, n0, threadIdx.x, lds, acc);

  const int tid = threadIdx.x, w = tid >> 6, lane = tid & 63;
  const int l15 = lane & 15, lg = lane >> 4;
  const int wr = (w >> 2) * 64, wc = (w & 3) * 64;
  const int nsel = n0 / 768;
  const int colbase = (n0 - nsel * 768) + wc;  // multiple of 64
  const int rbase = m0 + wr + lg * 4;
  const float* bias = g.bias[z][nsel];
  const int hh = colbase >> 6;

  if (nsel < 2) {
    f16* Y = nsel ? g.out1[z] : g.out0[z];
    float* term = nsel ? g.kterm : g.qterm;
    float bv4[4];
#pragma unroll
    for (int fj = 0; fj < 4; ++fj) bv4[fj] = bias[colbase + l15 + fj * 16];
#pragma unroll
    for (int fi = 0; fi < 4; ++fi) {
#pragma unroll
      for (int r = 0; r < 4; ++r) {
        const int row = rbase + fi * 16 + r;
        float ssum = 0.f;
#pragma unroll
        for (int fj = 0; fj < 4; ++fj) {
          float v = acc[fi][fj][r] + bv4[fj];
          if (z == 1) { v = (v > 0.f) ? v + 1.f : __expf(v); v = sqrtf(v); }
          const f16 st = (f16)(v * 0.5f);
          if (row < M) Y[(size_t)row * HID + colbase + l15 + fj * 16] = st;
          const float sf = (float)st;
          ssum = fmaf(sf, sf, ssum);
        }
        ssum += __shfl_xor(ssum, 1, 64);
        ssum += __shfl_xor(ssum, 2, 64);
        ssum += __shfl_xor(ssum, 4, 64);
        ssum += __shfl_xor(ssum, 8, 64);
        if (l15 == 0 && row < M) {
          const int bb = row / S, ss = row - bb * S;
          atomicAdd(&term[(bb * NH + hh) * S + ss], 0.5f * ssum);
        }
      }
    }
  } else {
    f16* VT = g.vt[z];
#pragma unroll
    for (int fj = 0; fj < 4; ++fj) {
      const int col = colbase + l15 + fj * 16;
      const float bv = bias[col];
      const int dd = col & 63;
#pragma unroll
      for (int fi = 0; fi < 4; ++fi)
#pragma unroll
        for (int r = 0; r < 4; ++r) {
          const int row = rbase + fi * 16 + r;
          if (row < M) {
            float v = acc[fi][fj][r] + bv;
            if (z == 1) v = (v > 0.f) ? v + 1.f : __expf(v);
            const int bb = row / S, ss = row - bb * S;
            VT[((size_t)(bb * NH + hh) * DH + dd) * VSTRIDE + ss] = (f16)v;
          }
        }
    }
  }
}

// ---------------- output GEMMs (z=0 mean, z=1 cov), f32 out ---------------
struct OutArgs {
  const f16* A[2]; const f16* Bt[2]; const float* bias[2]; float* Y[2];
};

__global__ __launch_bounds__(512, 2) void gemm_out(OutArgs g) {
  __shared__ alignas(16) char lds[73728];
  const int swz = xcd_swizzle(blockIdx.x, 600);
  const int z = swz / 300;
  const int rest = swz - z * 300;
  const int x = rest / 3, y = rest - x * 3;
  const int m0 = x * 128, n0 = y * 256;

  f32x4 acc[4][4] = {};
  gemm_core(g.A[z], g.Bt[z], m0, n0, threadIdx.x, lds, acc);

  const int tid = threadIdx.x, w = tid >> 6, lane = tid & 63;
  const int l15 = lane & 15, lg = lane >> 4;
  const int wr = (w >> 2) * 64, wc = (w & 3) * 64;
  const int rbase = m0 + wr + lg * 4;
  float* Y = g.Y[z];
#pragma unroll
  for (int fj = 0; fj < 4; ++fj) {
    const int col = n0 + wc + l15 + fj * 16;
    const float bv = g.bias[z][col];
#pragma unroll
    for (int fi = 0; fi < 4; ++fi)
#pragma unroll
      for (int r = 0; r < 4; ++r) {
        const int row = rbase + fi * 16 + r;
        if (row < M) Y[(size_t)row * HID + col] = acc[fi][fj][r] + bv;
      }
  }
}

// ---------------- fused Wasserstein attention ----------------
__global__ __launch_bounds__(256, 2) void attn_kernel(
    const f16* __restrict__ mq, const f16* __restrict__ sq,
    const f16* __restrict__ mk, const f16* __restrict__ sk,
    const f16* __restrict__ vtm, const f16* __restrict__ vtc,
    const float* __restrict__ qterm, const float* __restrict__ kterm,
    f16* __restrict__ mean_ctx, f16* __restrict__ cov_ctx) {
  __shared__ char Pb[64 * 512];  // P[q][j] f16, XOR-swizzled rows
  __shared__ float qt_s[64];
  __shared__ float kt_s[256];
  __shared__ float red_m[4][64];
  __shared__ float red_s[4][64];

  const int swz = xcd_swizzle(blockIdx.x, 3072);
  const int qtile = swz & 3, bh = swz >> 2;
  const int h = bh % NH, b = bh / NH;
  const int s0 = qtile * 64;
  const int tid = threadIdx.x, w = tid >> 6, lane = tid & 63;
  const int l15 = lane & 15, lg = lane >> 4;

  const size_t base = (size_t)(b * S) * HID + (size_t)h * DH;
  const int tb = bh * S;

  // Q fragments (B-operand): row = s0+fi*16+l15, k = lg*8 (+32)
  f16x8 qmf[4][2], qsf[4][2];
#pragma unroll
  for (int fi = 0; fi < 4; ++fi) {
    const size_t o = base + (size_t)(s0 + fi * 16 + l15) * HID + lg * 8;
    qmf[fi][0] = *reinterpret_cast<const f16x8*>(mq + o);
    qmf[fi][1] = *reinterpret_cast<const f16x8*>(mq + o + 32);
    qsf[fi][0] = *reinterpret_cast<const f16x8*>(sq + o);
    qsf[fi][1] = *reinterpret_cast<const f16x8*>(sq + o + 32);
  }
  if (tid < 64) qt_s[tid] = (s0 + tid < S) ? qterm[tb + s0 + tid] : 0.f;
  kt_s[tid] = (tid < S) ? kterm[tb + tid] : 0.f;
  __syncthreads();

  // scores^T: acc[fj][fi], rows = K tokens (wave-owned 64), cols = Q tokens
  f32x4 acc[4][4] = {};
  __builtin_amdgcn_s_setprio(1);
#pragma unroll
  for (int fj = 0; fj < 4; ++fj) {
    const size_t o = base + (size_t)(w * 64 + fj * 16 + l15) * HID + lg * 8;
    const f16x8 a0 = *reinterpret_cast<const f16x8*>(mk + o);
    const f16x8 a1 = *reinterpret_cast<const f16x8*>(mk + o + 32);
    const f16x8 c0 = *reinterpret_cast<const f16x8*>(sk + o);
    const f16x8 c1 = *reinterpret_cast<const f16x8*>(sk + o + 32);
#pragma unroll
    for (int fi = 0; fi < 4; ++fi) {
      acc[fj][fi] = mfma16(a0, qmf[fi][0], acc[fj][fi]);
      acc[fj][fi] = mfma16(c0, qsf[fi][0], acc[fj][fi]);
      acc[fj][fi] = mfma16(a1, qmf[fi][1], acc[fj][fi]);
      acc[fj][fi] = mfma16(c1, qsf[fi][1], acc[fj][fi]);
    }
  }
  __builtin_amdgcn_s_setprio(0);

  // issue Vt loads early (independent of softmax) -> registers
  const int d = w * 16 + l15;
  const size_t vbase = ((size_t)bh * DH + d) * VSTRIDE + lg * 8;
  f16x8 vmr[7], vcr[7];
#pragma unroll
  for (int ks = 0; ks < 7; ++ks) {
    vmr[ks] = *reinterpret_cast<const f16x8*>(vtm + vbase + ks * 32);
    vcr[ks] = *reinterpret_cast<const f16x8*>(vtc + vbase + ks * 32);
  }

  // transform + wave-partial row max
#pragma unroll
  for (int fi = 0; fi < 4; ++fi) {
    const float qv = qt_s[fi * 16 + l15];
    float mx = -1e30f;
#pragma unroll
    for (int fj = 0; fj < 4; ++fj)
#pragma unroll
      for (int r = 0; r < 4; ++r) {
        const int j = w * 64 + fj * 16 + lg * 4 + r;
        float sv = acc[fj][fi][r] - qv - kt_s[j];
        if (j >= S) sv = -1e30f;
        acc[fj][fi][r] = sv;
        mx = fmaxf(mx, sv);
      }
    mx = fmaxf(mx, __shfl_xor(mx, 16, 64));
    mx = fmaxf(mx, __shfl_xor(mx, 32, 64));
    if (lg == 0) red_m[w][fi * 16 + l15] = mx;
  }
  __syncthreads();

  // exp (unnormalized) -> P (b64 writes), partial sums
#pragma unroll
  for (int fi = 0; fi < 4; ++fi) {
    const int q = fi * 16 + l15;
    const float m = fmaxf(fmaxf(red_m[0][q], red_m[1][q]),
                          fmaxf(red_m[2][q], red_m[3][q]));
    const int xr = (q & 7) << 4;
    float sum = 0.f;
#pragma unroll
    for (int fj = 0; fj < 4; ++fj) {
      f16x4 p4;
#pragma unroll
      for (int r = 0; r < 4; ++r) {
        const float e = __expf(acc[fj][fi][r] - m);
        sum += e;
        p4[r] = (f16)e;
      }
      *reinterpret_cast<f16x4*>(
          Pb + q * 512 + ((2 * (w * 64 + fj * 16 + lg * 4)) ^ xr)) = p4;
    }
    sum += __shfl_xor(sum, 16, 64);
    sum += __shfl_xor(sum, 32, 64);
    if (lg == 0) red_s[w][q] = sum;
  }
  __syncthreads();

  // PV: A = P rows (q), B = Vt rows (d) from registers
  f32x4 macc[4] = {}, cacc[4] = {};
  __builtin_amdgcn_s_setprio(1);
#pragma unroll
  for (int ks = 0; ks < 7; ++ks) {
#pragma unroll
    for (int fi = 0; fi < 4; ++fi) {
      const int q = fi * 16 + l15;
      const f16x8 pa = *reinterpret_cast<const f16x8*>(
          Pb + q * 512 + ((2 * (ks * 32 + lg * 8)) ^ ((q & 7) << 4)));
      macc[fi] = mfma16(pa, vmr[ks], macc[fi]);
      const f16x8 pq = pa * pa;
      cacc[fi] = mfma16(pq, vcr[ks], cacc[fi]);
    }
  }
  __builtin_amdgcn_s_setprio(0);

  // epilogue: normalize by row sums
#pragma unroll
  for (int fi = 0; fi < 4; ++fi)
#pragma unroll
    for (int r = 0; r < 4; ++r) {
      const int qo = fi * 16 + lg * 4 + r;
      const int srow = s0 + qo;
      if (srow < S) {
        const float tot = red_s[0][qo] + red_s[1][qo] + red_s[2][qo] + red_s[3][qo];
        const float inv = 1.f / tot;
        const size_t oidx = (size_t)(b * S + srow) * HID + h * DH + d;
        mean_ctx[oidx] = (f16)(macc[fi][r] * inv);
        cov_ctx[oidx] = (f16)(cacc[fi][r] * inv * inv);
      }
    }
}

extern "C" void kernel_launch(void* const* d_in, const int* in_sizes, int n_in,
                              void* d_out, int out_size, void* d_ws, size_t ws_size,
                              hipStream_t stream) {
  const float* in_mean = (const float*)d_in[0];
  const float* in_cov = (const float*)d_in[1];
  const float* Wmq = (const float*)d_in[2];  const float* bmq = (const float*)d_in[3];
  const float* Wcq = (const float*)d_in[4];  const float* bcq = (const float*)d_in[5];
  const float* Wmk = (const float*)d_in[6];  const float* bmk = (const float*)d_in[7];
  const float* Wck = (const float*)d_in[8];  const float* bck = (const float*)d_in[9];
  const float* Wmv = (const float*)d_in[10]; const float* bmv = (const float*)d_in[11];
  const float* Wcv = (const float*)d_in[12]; const float* bcv = (const float*)d_in[13];
  const float* Wmd = (const float*)d_in[14]; const float* bmd = (const float*)d_in[15];
  const float* Wcd = (const float*)d_in[16]; const float* bcd = (const float*)d_in[17];

  const size_t need = (2 * NPH + 8 * WSZ1 + 4 * MH + 2 * VTSZ) * sizeof(f16) +
                      2 * (size_t)BNS * sizeof(float);
  if (ws_size < need) return;

  f16* Xm = (f16*)d_ws;          // later: mean_ctx
  f16* Xc = Xm + NPH;            // later: cov_ctx
  f16* Wt = Xc + NPH;
  f16* mq = Wt + 8 * WSZ1;
  f16* mk = mq + MH;
  f16* sq = mk + MH;
  f16* sk = sq + MH;
  f16* vtm = sk + MH;
  f16* vtc = vtm + VTSZ;
  float* qterm = (float*)(vtc + VTSZ);
  float* kterm = qterm + BNS;
  f16* mean_ctx = Xm;
  f16* cov_ctx = Xc;

  float* out_mean = (float*)d_out;
  float* out_cov = out_mean + MH;

  dim3 blk(256);

  // zero Vt + qterm + kterm (contiguous region starting at vtm)
  const size_t zbytes = 2 * VTSZ * sizeof(f16) + 2 * (size_t)BNS * sizeof(float);
  const size_t n16 = zbytes / 16;
  zero_kernel<<<(int)((n16 + 255) / 256), blk, 0, stream>>>((char*)vtm, n16);

  cvt_x_kernel<<<(int)(NPH / 2048), blk, 0, stream>>>(in_mean, in_cov, Xm, Xc);

  WPtrs wp;
  wp.w[0] = Wmq; wp.w[1] = Wmk; wp.w[2] = Wmv;
  wp.w[3] = Wcq; wp.w[4] = Wck; wp.w[5] = Wcv;
  wp.w[6] = Wmd; wp.w[7] = Wcd;
  cvt_w_kernel<<<dim3(24, 24, 8), blk, 0, stream>>>(wp, Wt);

  ProjArgs pa;
  pa.A[0] = Xm; pa.A[1] = Xc;
  pa.Bt[0] = Wt; pa.Bt[1] = Wt + 3 * WSZ1;
  pa.bias[0][0] = bmq; pa.bias[0][1] = bmk; pa.bias[0][2] = bmv;
  pa.bias[1][0] = bcq; pa.bias[1][1] = bck; pa.bias[1][2] = bcv;
  pa.out0[0] = mq; pa.out0[1] = sq;
  pa.out1[0] = mk; pa.out1[1] = sk;
  pa.vt[0] = vtm; pa.vt[1] = vtc;
  pa.qterm = qterm; pa.kterm = kterm;
  gemm_proj<<<1800, dim3(512), 0, stream>>>(pa);

  attn_kernel<<<3072, blk, 0, stream>>>(mq, sq, mk, sk, vtm, vtc,
                                        qterm, kterm, mean_ctx, cov_ctx);

  OutArgs oa;
  oa.A[0] = mean_ctx; oa.A[1] = cov_ctx;
  oa.Bt[0] = Wt + 6 * WSZ1; oa.Bt[1] = Wt + 7 * WSZ1;
  oa.bias[0] = bmd; oa.bias[1] = bcd;
  oa.Y[0] = out_mean; oa.Y[1] = out_cov;
  gemm_out<<<600, dim3(512), 0, stream>>>(oa);
}

// Round 10
// 366.170 us; speedup vs baseline: 1.1660x; 1.0004x over previous
//
#include <hip/hip_runtime.h>
#include <hip/hip_bf16.h>
#include <stdint.h>

typedef _Float16 f16;
typedef _Float16 f16x8 __attribute__((ext_vector_type(8)));
typedef _Float16 f16x4 __attribute__((ext_vector_type(4)));
typedef float f32x4 __attribute__((ext_vector_type(4)));

constexpr int B = 64, S = 197, HID = 768, NH = 12, DH = 64;
constexpr int M = B * S;          // 12608
constexpr int Mpad = 12800;       // 100*128
constexpr int BNS = B * NH * S;   // 151296
constexpr int VSTRIDE = 224;      // 7*32 >= 197
constexpr size_t NPH = (size_t)Mpad * HID;
constexpr size_t MH = (size_t)M * HID;
constexpr size_t WSZ1 = (size_t)HID * HID;
constexpr size_t VTSZ = (size_t)B * NH * DH * VSTRIDE;

__device__ __forceinline__ f32x4 mfma16(f16x8 a, f16x8 b, f32x4 c) {
  return __builtin_amdgcn_mfma_f32_16x16x32_f16(a, b, c, 0, 0, 0);
}

__device__ __forceinline__ void gload16(const void* g, void* l) {
  __builtin_amdgcn_global_load_lds(
      (const __attribute__((address_space(1))) void*)g,
      (__attribute__((address_space(3))) void*)l, 16, 0, 0);
}

// bijective XCD-aware swizzle (m204)
__device__ __forceinline__ int xcd_swizzle(int wg, int nwg) {
  const int q = nwg >> 3, r = nwg & 7;
  const int x = wg & 7, p = wg >> 3;
  return (x < r ? x * (q + 1) : r * (q + 1) + (x - r) * q) + p;
}

// ---------------- zero fill (16B) ----------------
__global__ __launch_bounds__(256) void zero_kernel(char* __restrict__ p, size_t n16) {
  const size_t i = (size_t)blockIdx.x * 256 + threadIdx.x;
  if (i < n16) reinterpret_cast<int4*>(p)[i] = int4{0, 0, 0, 0};
}

// ---------------- f32 -> f16 (padded, zero tail) ----------------
__global__ __launch_bounds__(256) void cvt_x_kernel(
    const float* __restrict__ xm, const float* __restrict__ xc,
    f16* __restrict__ ym, f16* __restrict__ yc) {
  const size_t i8 = ((size_t)blockIdx.x * 256 + threadIdx.x) * 8;
  f16x8 vm = {}, vc = {};
  if (i8 < MH) {
    const float4 a0 = *reinterpret_cast<const float4*>(xm + i8);
    const float4 a1 = *reinterpret_cast<const float4*>(xm + i8 + 4);
    const float4 b0 = *reinterpret_cast<const float4*>(xc + i8);
    const float4 b1 = *reinterpret_cast<const float4*>(xc + i8 + 4);
    vm[0] = (f16)a0.x; vm[1] = (f16)a0.y; vm[2] = (f16)a0.z; vm[3] = (f16)a0.w;
    vm[4] = (f16)a1.x; vm[5] = (f16)a1.y; vm[6] = (f16)a1.z; vm[7] = (f16)a1.w;
    vc[0] = (f16)b0.x; vc[1] = (f16)b0.y; vc[2] = (f16)b0.z; vc[3] = (f16)b0.w;
    vc[4] = (f16)b1.x; vc[5] = (f16)b1.y; vc[6] = (f16)b1.z; vc[7] = (f16)b1.w;
  }
  *reinterpret_cast<f16x8*>(ym + i8) = vm;
  *reinterpret_cast<f16x8*>(yc + i8) = vc;
}

// ---------------- W [k][n] f32 -> Wt [n][k] f16 ----------------
struct WPtrs { const float* w[8]; };

__global__ __launch_bounds__(256) void cvt_w_kernel(WPtrs p, f16* __restrict__ wt) {
  __shared__ float tile[32][33];
  const int z = blockIdx.z;
  const float* W = p.w[z];
  f16* Wt = wt + (size_t)z * WSZ1;
  const int k0 = blockIdx.x * 32, n0 = blockIdx.y * 32;
  const int tx = threadIdx.x & 31, ty = threadIdx.x >> 5;
#pragma unroll
  for (int i = 0; i < 4; ++i)
    tile[ty + i * 8][tx] = W[(size_t)(k0 + ty + i * 8) * HID + n0 + tx];
  __syncthreads();
#pragma unroll
  for (int i = 0; i < 4; ++i)
    Wt[(size_t)(n0 + ty + i * 8) * HID + k0 + tx] = (f16)tile[tx][ty + i * 8];
}

// ---------------- MFMA GEMM core (128x256 tile, 512 thr, K=768) -----------
// r9 core, unchanged: BK=32, 3 LDS buffers, counted-vmcnt pipeline, verified
// 0-conflict slot swizzle.
__device__ __forceinline__ void gemm_core(
    const f16* __restrict__ Abase, const f16* __restrict__ Btbase,
    int m0, int n0, int tid, char* lds, f32x4 (&acc)[4][4]) {
  const int w = tid >> 6, lane = tid & 63;
  const int l15 = lane & 15, lg = lane >> 4;
  const int wr = (w >> 2) * 64, wc = (w & 3) * 64;

  const int arow = w * 16 + (lane >> 2);
  const int brow = w * 32 + (lane >> 2);
  const int scol = (((lane & 3) ^ ((lane >> 3) & 3)) * 16);  // pre-swizzled src
  const char* gA = reinterpret_cast<const char*>(Abase + (size_t)(m0 + arow) * HID) + scol;
  const char* gB = reinterpret_cast<const char*>(Btbase + (size_t)(n0 + brow) * HID) + scol;

  const int rslot = ((lg ^ (l15 >> 1)) & 3) * 16;

#define STAGE_TILE(T, BUF)                                               \
  do {                                                                   \
    const size_t off_ = (size_t)(T) * 64;                                \
    char* bp_ = lds + (BUF) * 24576;                                     \
    gload16(gA + off_, bp_ + w * 1024);                                  \
    gload16(gB + off_, bp_ + 8192 + w * 2048);                           \
    gload16(gB + off_ + (size_t)16 * 1536, bp_ + 8192 + w * 2048 + 1024);\
  } while (0)

  STAGE_TILE(0, 0);
  STAGE_TILE(1, 1);
  asm volatile("s_waitcnt vmcnt(3)\n\ts_barrier" ::: "memory");

#pragma unroll
  for (int t = 0; t < 24; ++t) {
    if (t + 2 < 24) STAGE_TILE(t + 2, (t + 2) % 3);

    const char* cb = lds + (t % 3) * 24576;
    f16x8 af[4], bf[4];
#pragma unroll
    for (int fi = 0; fi < 4; ++fi)
      af[fi] = *reinterpret_cast<const f16x8*>(cb + (wr + l15 + fi * 16) * 64 + rslot);
#pragma unroll
    for (int fj = 0; fj < 4; ++fj)
      bf[fj] = *reinterpret_cast<const f16x8*>(
          cb + 8192 + (wc + l15 + fj * 16) * 64 + rslot);

    __builtin_amdgcn_s_setprio(1);
#pragma unroll
    for (int fi = 0; fi < 4; ++fi)
#pragma unroll
      for (int fj = 0; fj < 4; ++fj)
        acc[fi][fj] = mfma16(af[fi], bf[fj], acc[fi][fj]);
    __builtin_amdgcn_s_setprio(0);

    if (t + 2 < 24) {
      asm volatile("s_waitcnt vmcnt(3)\n\ts_barrier" ::: "memory");
    } else if (t + 1 < 24) {
      asm volatile("s_waitcnt vmcnt(0)\n\ts_barrier" ::: "memory");
    }
  }
#undef STAGE_TILE
}

// ---------------- projection GEMMs, z-split (Z=0 mean, Z=1 cov) -----------
struct ProjArgs {
  const f16* A[2]; const f16* Bt[2];
  const float* bias[2][3];
  f16* out0[2];  // nsel 0: mq / sq   (scaled 0.5, M rows)
  f16* out1[2];  // nsel 1: mk / sk   (scaled 0.5, M rows)
  f16* vt[2];    // nsel 2: Vt mean / cov (transposed, unscaled)
  float* qterm; float* kterm;  // fused row sums (atomic)
};

template <int Z>
__global__ __launch_bounds__(512, 2) void gemm_proj(ProjArgs g) {
  __shared__ alignas(16) char lds[73728];
  const int swz = xcd_swizzle(blockIdx.x, 900);
  const int x = swz / 9, y = swz - x * 9;  // y fastest: A panel L2-reuse
  const int m0 = x * 128, n0 = y * 256;

  f32x4 acc[4][4] = {};
  gemm_core(g.A[Z], g.Bt[Z], m0, n0, threadIdx.x, lds, acc);

  const int tid = threadIdx.x, w = tid >> 6, lane = tid & 63;
  const int l15 = lane & 15, lg = lane >> 4;
  const int wr = (w >> 2) * 64, wc = (w & 3) * 64;
  const int nsel = n0 / 768;
  const int colbase = (n0 - nsel * 768) + wc;  // multiple of 64
  const int rbase = m0 + wr + lg * 4;
  const float* bias = g.bias[Z][nsel];

  if (nsel < 2) {
    const int hh = colbase >> 6;
    f16* Y = nsel ? g.out1[Z] : g.out0[Z];
    float* term = nsel ? g.kterm : g.qterm;
    float bv4[4];
#pragma unroll
    for (int fj = 0; fj < 4; ++fj) bv4[fj] = bias[colbase + l15 + fj * 16];
#pragma unroll
    for (int fi = 0; fi < 4; ++fi) {
#pragma unroll
      for (int r = 0; r < 4; ++r) {
        const int row = rbase + fi * 16 + r;
        float ssum = 0.f;
#pragma unroll
        for (int fj = 0; fj < 4; ++fj) {
          float v = acc[fi][fj][r] + bv4[fj];
          if (Z == 1) { v = (v > 0.f) ? v + 1.f : __expf(v); v = sqrtf(v); }
          const f16 st = (f16)(v * 0.5f);
          if (row < M) Y[(size_t)row * HID + colbase + l15 + fj * 16] = st;
          const float sf = (float)st;
          ssum = fmaf(sf, sf, ssum);
        }
        ssum += __shfl_xor(ssum, 1, 64);
        ssum += __shfl_xor(ssum, 2, 64);
        ssum += __shfl_xor(ssum, 4, 64);
        ssum += __shfl_xor(ssum, 8, 64);
        if (l15 == 0 && row < M) {
          const int bb = row / S, ss = row - bb * S;
          atomicAdd(&term[(bb * NH + hh) * S + ss], 0.5f * ssum);
        }
      }
    }
  } else {
    // ---- V projection: transpose through LDS, coalesced ss-major stores ----
    f16* VT = g.vt[Z];
    f16* LT = reinterpret_cast<f16*>(lds);  // LT[col][136], 256x136 f16 = 68KB
    __syncthreads();  // gemm_core LDS reads done block-wide
#pragma unroll
    for (int fj = 0; fj < 4; ++fj) {
      const int c = wc + l15 + fj * 16;               // local col 0..255
      const float bv = bias[colbase - wc + c];        // bias[col in 0..767]
#pragma unroll
      for (int fi = 0; fi < 4; ++fi)
#pragma unroll
        for (int r = 0; r < 4; ++r) {
          const int rl = wr - (wr & 64) + 0;  // placeholder (wr in 0..64)
          (void)rl;
          float v = acc[fi][fj][r] + bv;
          if (Z == 1) v = (v > 0.f) ? v + 1.f : __expf(v);
          const int row_local = wr + lg * 4 + fi * 16 + r;  // 0..127
          LT[(size_t)c * 136 + row_local] = (f16)v;
        }
    }
    __syncthreads();
    // phase 2: wave w covers cols w*... rows = lane; 4 col-groups of 64
    const int rh = w >> 2;            // row half 0/1
    const int cw = w & 3;             // col quarter
    const int row_local = rh * 64 + lane;
    const int grow = m0 + row_local;
    if (grow < M) {
      const int bb = grow / S;
      const int ss = grow - bb * S;
      const int vb = n0 - 1536;  // V-col base of this block (0,256,512)
#pragma unroll 8
      for (int k = 0; k < 64; ++k) {
        const int c = cw * 64 + k;            // local col
        const int vcol = vb + c;
        const int hh = vcol >> 6, dd = vcol & 63;
        const f16 v = LT[(size_t)c * 136 + row_local];
        VT[((size_t)(bb * NH + hh) * DH + dd) * VSTRIDE + ss] = v;
      }
    }
  }
}

// ---------------- output GEMMs, z-split, f32 out ---------------
struct OutArgs {
  const f16* A[2]; const f16* Bt[2]; const float* bias[2]; float* Y[2];
};

template <int Z>
__global__ __launch_bounds__(512, 2) void gemm_out(OutArgs g) {
  __shared__ alignas(16) char lds[73728];
  const int swz = xcd_swizzle(blockIdx.x, 300);
  const int x = swz / 3, y = swz - x * 3;
  const int m0 = x * 128, n0 = y * 256;

  f32x4 acc[4][4] = {};
  gemm_core(g.A[Z], g.Bt[Z], m0, n0, threadIdx.x, lds, acc);

  const int tid = threadIdx.x, w = tid >> 6, lane = tid & 63;
  const int l15 = lane & 15, lg = lane >> 4;
  const int wr = (w >> 2) * 64, wc = (w & 3) * 64;
  const int rbase = m0 + wr + lg * 4;
  float* Y = g.Y[Z];
#pragma unroll
  for (int fj = 0; fj < 4; ++fj) {
    const int col = n0 + wc + l15 + fj * 16;
    const float bv = g.bias[Z][col];
#pragma unroll
    for (int fi = 0; fi < 4; ++fi)
#pragma unroll
      for (int r = 0; r < 4; ++r) {
        const int row = rbase + fi * 16 + r;
        if (row < M) Y[(size_t)row * HID + col] = acc[fi][fj][r] + bv;
      }
  }
}

// ---------------- fused Wasserstein attention ----------------
__global__ __launch_bounds__(256, 2) void attn_kernel(
    const f16* __restrict__ mq, const f16* __restrict__ sq,
    const f16* __restrict__ mk, const f16* __restrict__ sk,
    const f16* __restrict__ vtm, const f16* __restrict__ vtc,
    const float* __restrict__ qterm, const float* __restrict__ kterm,
    f16* __restrict__ mean_ctx, f16* __restrict__ cov_ctx) {
  __shared__ char Pb[64 * 512];  // P[q][j] f16, XOR-swizzled rows
  __shared__ float qt_s[64];
  __shared__ float kt_s[256];
  __shared__ float red_m[4][64];
  __shared__ float red_s[4][64];

  const int swz = xcd_swizzle(blockIdx.x, 3072);
  const int qtile = swz & 3, bh = swz >> 2;
  const int h = bh % NH, b = bh / NH;
  const int s0 = qtile * 64;
  const int tid = threadIdx.x, w = tid >> 6, lane = tid & 63;
  const int l15 = lane & 15, lg = lane >> 4;

  const size_t base = (size_t)(b * S) * HID + (size_t)h * DH;
  const int tb = bh * S;

  // Q fragments (B-operand): row = s0+fi*16+l15, k = lg*8 (+32)
  f16x8 qmf[4][2], qsf[4][2];
#pragma unroll
  for (int fi = 0; fi < 4; ++fi) {
    const size_t o = base + (size_t)(s0 + fi * 16 + l15) * HID + lg * 8;
    qmf[fi][0] = *reinterpret_cast<const f16x8*>(mq + o);
    qmf[fi][1] = *reinterpret_cast<const f16x8*>(mq + o + 32);
    qsf[fi][0] = *reinterpret_cast<const f16x8*>(sq + o);
    qsf[fi][1] = *reinterpret_cast<const f16x8*>(sq + o + 32);
  }
  if (tid < 64) qt_s[tid] = (s0 + tid < S) ? qterm[tb + s0 + tid] : 0.f;
  kt_s[tid] = (tid < S) ? kterm[tb + tid] : 0.f;
  __syncthreads();

  // scores^T: acc[fj][fi], rows = K tokens (wave-owned 64), cols = Q tokens
  f32x4 acc[4][4] = {};
  __builtin_amdgcn_s_setprio(1);
#pragma unroll
  for (int fj = 0; fj < 4; ++fj) {
    const size_t o = base + (size_t)(w * 64 + fj * 16 + l15) * HID + lg * 8;
    const f16x8 a0 = *reinterpret_cast<const f16x8*>(mk + o);
    const f16x8 a1 = *reinterpret_cast<const f16x8*>(mk + o + 32);
    const f16x8 c0 = *reinterpret_cast<const f16x8*>(sk + o);
    const f16x8 c1 = *reinterpret_cast<const f16x8*>(sk + o + 32);
#pragma unroll
    for (int fi = 0; fi < 4; ++fi) {
      acc[fj][fi] = mfma16(a0, qmf[fi][0], acc[fj][fi]);
      acc[fj][fi] = mfma16(c0, qsf[fi][0], acc[fj][fi]);
      acc[fj][fi] = mfma16(a1, qmf[fi][1], acc[fj][fi]);
      acc[fj][fi] = mfma16(c1, qsf[fi][1], acc[fj][fi]);
    }
  }
  __builtin_amdgcn_s_setprio(0);

  // issue Vt loads early (independent of softmax) -> registers
  const int d = w * 16 + l15;
  const size_t vbase = ((size_t)bh * DH + d) * VSTRIDE + lg * 8;
  f16x8 vmr[7], vcr[7];
#pragma unroll
  for (int ks = 0; ks < 7; ++ks) {
    vmr[ks] = *reinterpret_cast<const f16x8*>(vtm + vbase + ks * 32);
    vcr[ks] = *reinterpret_cast<const f16x8*>(vtc + vbase + ks * 32);
  }

  // transform + wave-partial row max
#pragma unroll
  for (int fi = 0; fi < 4; ++fi) {
    const float qv = qt_s[fi * 16 + l15];
    float mx = -1e30f;
#pragma unroll
    for (int fj = 0; fj < 4; ++fj)
#pragma unroll
      for (int r = 0; r < 4; ++r) {
        const int j = w * 64 + fj * 16 + lg * 4 + r;
        float sv = acc[fj][fi][r] - qv - kt_s[j];
        if (j >= S) sv = -1e30f;
        acc[fj][fi][r] = sv;
        mx = fmaxf(mx, sv);
      }
    mx = fmaxf(mx, __shfl_xor(mx, 16, 64));
    mx = fmaxf(mx, __shfl_xor(mx, 32, 64));
    if (lg == 0) red_m[w][fi * 16 + l15] = mx;
  }
  __syncthreads();

  // exp (unnormalized) -> P (b64 writes), partial sums
#pragma unroll
  for (int fi = 0; fi < 4; ++fi) {
    const int q = fi * 16 + l15;
    const float m = fmaxf(fmaxf(red_m[0][q], red_m[1][q]),
                          fmaxf(red_m[2][q], red_m[3][q]));
    const int xr = (q & 7) << 4;
    float sum = 0.f;
#pragma unroll
    for (int fj = 0; fj < 4; ++fj) {
      f16x4 p4;
#pragma unroll
      for (int r = 0; r < 4; ++r) {
        const float e = __expf(acc[fj][fi][r] - m);
        sum += e;
        p4[r] = (f16)e;
      }
      *reinterpret_cast<f16x4*>(
          Pb + q * 512 + ((2 * (w * 64 + fj * 16 + lg * 4)) ^ xr)) = p4;
    }
    sum += __shfl_xor(sum, 16, 64);
    sum += __shfl_xor(sum, 32, 64);
    if (lg == 0) red_s[w][q] = sum;
  }
  __syncthreads();

  // PV: A = P rows (q), B = Vt rows (d) from registers
  f32x4 macc[4] = {}, cacc[4] = {};
  __builtin_amdgcn_s_setprio(1);
#pragma unroll
  for (int ks = 0; ks < 7; ++ks) {
#pragma unroll
    for (int fi = 0; fi < 4; ++fi) {
      const int q = fi * 16 + l15;
      const f16x8 pa = *reinterpret_cast<const f16x8*>(
          Pb + q * 512 + ((2 * (ks * 32 + lg * 8)) ^ ((q & 7) << 4)));
      macc[fi] = mfma16(pa, vmr[ks], macc[fi]);
      const f16x8 pq = pa * pa;
      cacc[fi] = mfma16(pq, vcr[ks], cacc[fi]);
    }
  }
  __builtin_amdgcn_s_setprio(0);

  // epilogue: normalize by row sums
#pragma unroll
  for (int fi = 0; fi < 4; ++fi)
#pragma unroll
    for (int r = 0; r < 4; ++r) {
      const int qo = fi * 16 + lg * 4 + r;
      const int srow = s0 + qo;
      if (srow < S) {
        const float tot = red_s[0][qo] + red_s[1][qo] + red_s[2][qo] + red_s[3][qo];
        const float inv = 1.f / tot;
        const size_t oidx = (size_t)(b * S + srow) * HID + h * DH + d;
        mean_ctx[oidx] = (f16)(macc[fi][r] * inv);
        cov_ctx[oidx] = (f16)(cacc[fi][r] * inv * inv);
      }
    }
}

extern "C" void kernel_launch(void* const* d_in, const int* in_sizes, int n_in,
                              void* d_out, int out_size, void* d_ws, size_t ws_size,
                              hipStream_t stream) {
  const float* in_mean = (const float*)d_in[0];
  const float* in_cov = (const float*)d_in[1];
  const float* Wmq = (const float*)d_in[2];  const float* bmq = (const float*)d_in[3];
  const float* Wcq = (const float*)d_in[4];  const float* bcq = (const float*)d_in[5];
  const float* Wmk = (const float*)d_in[6];  const float* bmk = (const float*)d_in[7];
  const float* Wck = (const float*)d_in[8];  const float* bck = (const float*)d_in[9];
  const float* Wmv = (const float*)d_in[10]; const float* bmv = (const float*)d_in[11];
  const float* Wcv = (const float*)d_in[12]; const float* bcv = (const float*)d_in[13];
  const float* Wmd = (const float*)d_in[14]; const float* bmd = (const float*)d_in[15];
  const float* Wcd = (const float*)d_in[16]; const float* bcd = (const float*)d_in[17];

  const size_t need = (2 * NPH + 8 * WSZ1 + 4 * MH + 2 * VTSZ) * sizeof(f16) +
                      2 * (size_t)BNS * sizeof(float);
  if (ws_size < need) return;

  f16* Xm = (f16*)d_ws;          // later: mean_ctx
  f16* Xc = Xm + NPH;            // later: cov_ctx
  f16* Wt = Xc + NPH;
  f16* mq = Wt + 8 * WSZ1;
  f16* mk = mq + MH;
  f16* sq = mk + MH;
  f16* sk = sq + MH;
  f16* vtm = sk + MH;
  f16* vtc = vtm + VTSZ;
  float* qterm = (float*)(vtc + VTSZ);
  float* kterm = qterm + BNS;
  f16* mean_ctx = Xm;
  f16* cov_ctx = Xc;

  float* out_mean = (float*)d_out;
  float* out_cov = out_mean + MH;

  dim3 blk(256);

  // zero Vt + qterm + kterm (contiguous region starting at vtm)
  const size_t zbytes = 2 * VTSZ * sizeof(f16) + 2 * (size_t)BNS * sizeof(float);
  const size_t n16 = zbytes / 16;
  zero_kernel<<<(int)((n16 + 255) / 256), blk, 0, stream>>>((char*)vtm, n16);

  cvt_x_kernel<<<(int)(NPH / 2048), blk, 0, stream>>>(in_mean, in_cov, Xm, Xc);

  WPtrs wp;
  wp.w[0] = Wmq; wp.w[1] = Wmk; wp.w[2] = Wmv;
  wp.w[3] = Wcq; wp.w[4] = Wck; wp.w[5] = Wcv;
  wp.w[6] = Wmd; wp.w[7] = Wcd;
  cvt_w_kernel<<<dim3(24, 24, 8), blk, 0, stream>>>(wp, Wt);

  ProjArgs pa;
  pa.A[0] = Xm; pa.A[1] = Xc;
  pa.Bt[0] = Wt; pa.Bt[1] = Wt + 3 * WSZ1;
  pa.bias[0][0] = bmq; pa.bias[0][1] = bmk; pa.bias[0][2] = bmv;
  pa.bias[1][0] = bcq; pa.bias[1][1] = bck; pa.bias[1][2] = bcv;
  pa.out0[0] = mq; pa.out0[1] = sq;
  pa.out1[0] = mk; pa.out1[1] = sk;
  pa.vt[0] = vtm; pa.vt[1] = vtc;
  pa.qterm = qterm; pa.kterm = kterm;
  gemm_proj<0><<<900, dim3(512), 0, stream>>>(pa);
  gemm_proj<1><<<900, dim3(512), 0, stream>>>(pa);

  attn_kernel<<<3072, blk, 0, stream>>>(mq, sq, mk, sk, vtm, vtc,
                                        qterm, kterm, mean_ctx, cov_ctx);

  OutArgs oa;
  oa.A[0] = mean_ctx; oa.A[1] = cov_ctx;
  oa.Bt[0] = Wt + 6 * WSZ1; oa.Bt[1] = Wt + 7 * WSZ1;
  oa.bias[0] = bmd; oa.bias[1] = bcd;
  oa.Y[0] = out_mean; oa.Y[1] = out_cov;
  gemm_out<0><<<300, dim3(512), 0, stream>>>(oa);
  gemm_out<1><<<300, dim3(512), 0, stream>>>(oa);
}

// Round 11
// 351.737 us; speedup vs baseline: 1.2138x; 1.0410x over previous
//
#include <hip/hip_runtime.h>
#include <hip/hip_bf16.h>
#include <stdint.h>

typedef _Float16 f16;
typedef _Float16 f16x8 __attribute__((ext_vector_type(8)));
typedef _Float16 f16x4 __attribute__((ext_vector_type(4)));
typedef float f32x4 __attribute__((ext_vector_type(4)));

constexpr int B = 64, S = 197, HID = 768, NH = 12, DH = 64;
constexpr int M = B * S;          // 12608
constexpr int Mpad = 12800;       // 100*128
constexpr int BNS = B * NH * S;   // 151296
constexpr int VSTRIDE = 224;      // 7*32 >= 197
constexpr size_t NPH = (size_t)Mpad * HID;
constexpr size_t MH = (size_t)M * HID;
constexpr size_t WSZ1 = (size_t)HID * HID;
constexpr size_t VTSZ = (size_t)B * NH * DH * VSTRIDE;

// 0.5 * sqrt(log2(e)) — folds the exp->exp2 conversion into the stored scale
#define QK_SCALE 0.6005612f

__device__ __forceinline__ f32x4 mfma16(f16x8 a, f16x8 b, f32x4 c) {
  return __builtin_amdgcn_mfma_f32_16x16x32_f16(a, b, c, 0, 0, 0);
}

__device__ __forceinline__ void gload16(const void* g, void* l) {
  __builtin_amdgcn_global_load_lds(
      (const __attribute__((address_space(1))) void*)g,
      (__attribute__((address_space(3))) void*)l, 16, 0, 0);
}

// bijective XCD-aware swizzle (m204)
__device__ __forceinline__ int xcd_swizzle(int wg, int nwg) {
  const int q = nwg >> 3, r = nwg & 7;
  const int x = wg & 7, p = wg >> 3;
  return (x < r ? x * (q + 1) : r * (q + 1) + (x - r) * q) + p;
}

// ---------------- fused prep: zero Vt/terms + cvt X + transpose W ---------
struct WPtrs { const float* w[8]; };
struct PrepArgs {
  char* zp; size_t zn16;          // zero region
  const float* xm; const float* xc; f16* ym; f16* yc;
  WPtrs wp; f16* wt;
};

__global__ __launch_bounds__(256) void prep_kernel(PrepArgs p) {
  __shared__ float tile[32][33];
  const int nz = (int)((p.zn16 + 255) / 256);
  const int nc = (int)(NPH / 2048);
  const int bid = blockIdx.x;
  if (bid < nz) {
    const size_t i = (size_t)bid * 256 + threadIdx.x;
    if (i < p.zn16) reinterpret_cast<int4*>(p.zp)[i] = int4{0, 0, 0, 0};
  } else if (bid < nz + nc) {
    const size_t i8 = ((size_t)(bid - nz) * 256 + threadIdx.x) * 8;
    f16x8 vm = {}, vc = {};
    if (i8 < MH) {
      const float4 a0 = *reinterpret_cast<const float4*>(p.xm + i8);
      const float4 a1 = *reinterpret_cast<const float4*>(p.xm + i8 + 4);
      const float4 b0 = *reinterpret_cast<const float4*>(p.xc + i8);
      const float4 b1 = *reinterpret_cast<const float4*>(p.xc + i8 + 4);
      vm[0] = (f16)a0.x; vm[1] = (f16)a0.y; vm[2] = (f16)a0.z; vm[3] = (f16)a0.w;
      vm[4] = (f16)a1.x; vm[5] = (f16)a1.y; vm[6] = (f16)a1.z; vm[7] = (f16)a1.w;
      vc[0] = (f16)b0.x; vc[1] = (f16)b0.y; vc[2] = (f16)b0.z; vc[3] = (f16)b0.w;
      vc[4] = (f16)b1.x; vc[5] = (f16)b1.y; vc[6] = (f16)b1.z; vc[7] = (f16)b1.w;
    }
    *reinterpret_cast<f16x8*>(p.ym + i8) = vm;
    *reinterpret_cast<f16x8*>(p.yc + i8) = vc;
  } else {
    const int t = bid - nz - nc;          // 0..4607
    const int z = t / 576;                // 24*24
    const int rest = t - z * 576;
    const int kx = rest / 24, ny = rest - kx * 24;
    const float* W = p.wp.w[z];
    f16* Wt = p.wt + (size_t)z * WSZ1;
    const int k0 = kx * 32, n0 = ny * 32;
    const int tx = threadIdx.x & 31, ty = threadIdx.x >> 5;
#pragma unroll
    for (int i = 0; i < 4; ++i)
      tile[ty + i * 8][tx] = W[(size_t)(k0 + ty + i * 8) * HID + n0 + tx];
    __syncthreads();
#pragma unroll
    for (int i = 0; i < 4; ++i)
      Wt[(size_t)(n0 + ty + i * 8) * HID + k0 + tx] = (f16)tile[tx][ty + i * 8];
  }
}

// ---------------- MFMA GEMM core (128x256 tile, 512 thr, K=768) -----------
// r9/r10 core, unchanged: BK=32, 3 LDS buffers, counted-vmcnt pipeline,
// verified 0-conflict slot swizzle.
__device__ __forceinline__ void gemm_core(
    const f16* __restrict__ Abase, const f16* __restrict__ Btbase,
    int m0, int n0, int tid, char* lds, f32x4 (&acc)[4][4]) {
  const int w = tid >> 6, lane = tid & 63;
  const int l15 = lane & 15, lg = lane >> 4;
  const int wr = (w >> 2) * 64, wc = (w & 3) * 64;

  const int arow = w * 16 + (lane >> 2);
  const int brow = w * 32 + (lane >> 2);
  const int scol = (((lane & 3) ^ ((lane >> 3) & 3)) * 16);  // pre-swizzled src
  const char* gA = reinterpret_cast<const char*>(Abase + (size_t)(m0 + arow) * HID) + scol;
  const char* gB = reinterpret_cast<const char*>(Btbase + (size_t)(n0 + brow) * HID) + scol;

  const int rslot = ((lg ^ (l15 >> 1)) & 3) * 16;

#define STAGE_TILE(T, BUF)                                               \
  do {                                                                   \
    const size_t off_ = (size_t)(T) * 64;                                \
    char* bp_ = lds + (BUF) * 24576;                                     \
    gload16(gA + off_, bp_ + w * 1024);                                  \
    gload16(gB + off_, bp_ + 8192 + w * 2048);                           \
    gload16(gB + off_ + (size_t)16 * 1536, bp_ + 8192 + w * 2048 + 1024);\
  } while (0)

  STAGE_TILE(0, 0);
  STAGE_TILE(1, 1);
  asm volatile("s_waitcnt vmcnt(3)\n\ts_barrier" ::: "memory");

#pragma unroll
  for (int t = 0; t < 24; ++t) {
    if (t + 2 < 24) STAGE_TILE(t + 2, (t + 2) % 3);

    const char* cb = lds + (t % 3) * 24576;
    f16x8 af[4], bf[4];
#pragma unroll
    for (int fi = 0; fi < 4; ++fi)
      af[fi] = *reinterpret_cast<const f16x8*>(cb + (wr + l15 + fi * 16) * 64 + rslot);
#pragma unroll
    for (int fj = 0; fj < 4; ++fj)
      bf[fj] = *reinterpret_cast<const f16x8*>(
          cb + 8192 + (wc + l15 + fj * 16) * 64 + rslot);

    __builtin_amdgcn_s_setprio(1);
#pragma unroll
    for (int fi = 0; fi < 4; ++fi)
#pragma unroll
      for (int fj = 0; fj < 4; ++fj)
        acc[fi][fj] = mfma16(af[fi], bf[fj], acc[fi][fj]);
    __builtin_amdgcn_s_setprio(0);

    if (t + 2 < 24) {
      asm volatile("s_waitcnt vmcnt(3)\n\ts_barrier" ::: "memory");
    } else if (t + 1 < 24) {
      asm volatile("s_waitcnt vmcnt(0)\n\ts_barrier" ::: "memory");
    }
  }
#undef STAGE_TILE
}

// ---------------- projection GEMMs, z-split (Z=0 mean, Z=1 cov) -----------
struct ProjArgs {
  const f16* A[2]; const f16* Bt[2];
  const float* bias[2][3];
  f16* out0[2];  // nsel 0: mq / sq   (scaled QK_SCALE, M rows)
  f16* out1[2];  // nsel 1: mk / sk   (scaled QK_SCALE, M rows)
  f16* vt[2];    // nsel 2: Vt mean / cov (transposed, unscaled)
  float* qterm; float* kterm;  // fused row sums (atomic)
};

template <int Z>
__global__ __launch_bounds__(512, 2) void gemm_proj(ProjArgs g) {
  __shared__ alignas(16) char lds[73728];
  const int swz = xcd_swizzle(blockIdx.x, 900);
  const int x = swz / 9, y = swz - x * 9;  // y fastest: A panel L2-reuse
  const int m0 = x * 128, n0 = y * 256;

  f32x4 acc[4][4] = {};
  gemm_core(g.A[Z], g.Bt[Z], m0, n0, threadIdx.x, lds, acc);

  const int tid = threadIdx.x, w = tid >> 6, lane = tid & 63;
  const int l15 = lane & 15, lg = lane >> 4;
  const int wr = (w >> 2) * 64, wc = (w & 3) * 64;
  const int nsel = n0 / 768;
  const int colbase = (n0 - nsel * 768) + wc;  // multiple of 64
  const int rbase = m0 + wr + lg * 4;
  const float* bias = g.bias[Z][nsel];

  if (nsel < 2) {
    const int hh = colbase >> 6;
    f16* Y = nsel ? g.out1[Z] : g.out0[Z];
    float* term = nsel ? g.kterm : g.qterm;
    float bv4[4];
#pragma unroll
    for (int fj = 0; fj < 4; ++fj) bv4[fj] = bias[colbase + l15 + fj * 16];
#pragma unroll
    for (int fi = 0; fi < 4; ++fi) {
#pragma unroll
      for (int r = 0; r < 4; ++r) {
        const int row = rbase + fi * 16 + r;
        float ssum = 0.f;
#pragma unroll
        for (int fj = 0; fj < 4; ++fj) {
          float v = acc[fi][fj][r] + bv4[fj];
          if (Z == 1) { v = (v > 0.f) ? v + 1.f : __expf(v); v = sqrtf(v); }
          const f16 st = (f16)(v * QK_SCALE);
          if (row < M) Y[(size_t)row * HID + colbase + l15 + fj * 16] = st;
          const float sf = (float)st;
          ssum = fmaf(sf, sf, ssum);
        }
        ssum += __shfl_xor(ssum, 1, 64);
        ssum += __shfl_xor(ssum, 2, 64);
        ssum += __shfl_xor(ssum, 4, 64);
        ssum += __shfl_xor(ssum, 8, 64);
        if (l15 == 0 && row < M) {
          const int bb = row / S, ss = row - bb * S;
          atomicAdd(&term[(bb * NH + hh) * S + ss], 0.5f * ssum);
        }
      }
    }
  } else {
    // ---- V projection: transpose through LDS, coalesced ss-major stores ----
    f16* VT = g.vt[Z];
    f16* LT = reinterpret_cast<f16*>(lds);  // LT[col][136], 256x136 f16 = 68KB
    __syncthreads();  // gemm_core LDS reads done block-wide
#pragma unroll
    for (int fj = 0; fj < 4; ++fj) {
      const int c = wc + l15 + fj * 16;               // local col 0..255
      const float bv = bias[colbase - wc + c];        // bias[col in 0..767]
#pragma unroll
      for (int fi = 0; fi < 4; ++fi)
#pragma unroll
        for (int r = 0; r < 4; ++r) {
          float v = acc[fi][fj][r] + bv;
          if (Z == 1) v = (v > 0.f) ? v + 1.f : __expf(v);
          const int row_local = wr + lg * 4 + fi * 16 + r;  // 0..127
          LT[(size_t)c * 136 + row_local] = (f16)v;
        }
    }
    __syncthreads();
    const int rh = w >> 2;            // row half 0/1
    const int cw = w & 3;             // col quarter
    const int row_local = rh * 64 + lane;
    const int grow = m0 + row_local;
    if (grow < M) {
      const int bb = grow / S;
      const int ss = grow - bb * S;
      const int vb = n0 - 1536;  // V-col base of this block (0,256,512)
#pragma unroll 8
      for (int k = 0; k < 64; ++k) {
        const int c = cw * 64 + k;            // local col
        const int vcol = vb + c;
        const int hh = vcol >> 6, dd = vcol & 63;
        const f16 v = LT[(size_t)c * 136 + row_local];
        VT[((size_t)(bb * NH + hh) * DH + dd) * VSTRIDE + ss] = v;
      }
    }
  }
}

// ---------------- output GEMMs, z-split, f32 out ---------------
struct OutArgs {
  const f16* A[2]; const f16* Bt[2]; const float* bias[2]; float* Y[2];
};

template <int Z>
__global__ __launch_bounds__(512, 2) void gemm_out(OutArgs g) {
  __shared__ alignas(16) char lds[73728];
  const int swz = xcd_swizzle(blockIdx.x, 300);
  const int x = swz / 3, y = swz - x * 3;
  const int m0 = x * 128, n0 = y * 256;

  f32x4 acc[4][4] = {};
  gemm_core(g.A[Z], g.Bt[Z], m0, n0, threadIdx.x, lds, acc);

  const int tid = threadIdx.x, w = tid >> 6, lane = tid & 63;
  const int l15 = lane & 15, lg = lane >> 4;
  const int wr = (w >> 2) * 64, wc = (w & 3) * 64;
  const int rbase = m0 + wr + lg * 4;
  float* Y = g.Y[Z];
#pragma unroll
  for (int fj = 0; fj < 4; ++fj) {
    const int col = n0 + wc + l15 + fj * 16;
    const float bv = g.bias[Z][col];
#pragma unroll
    for (int fi = 0; fi < 4; ++fi)
#pragma unroll
      for (int r = 0; r < 4; ++r) {
        const int row = rbase + fi * 16 + r;
        if (row < M) Y[(size_t)row * HID + col] = acc[fi][fj][r] + bv;
      }
  }
}

// ---------------- fused Wasserstein attention ----------------
__global__ __launch_bounds__(256, 2) void attn_kernel(
    const f16* __restrict__ mq, const f16* __restrict__ sq,
    const f16* __restrict__ mk, const f16* __restrict__ sk,
    const f16* __restrict__ vtm, const f16* __restrict__ vtc,
    const float* __restrict__ qterm, const float* __restrict__ kterm,
    f16* __restrict__ mean_ctx, f16* __restrict__ cov_ctx) {
  __shared__ char Pb[64 * 512];  // P[q][j] f16, XOR-swizzled rows
  __shared__ float qt_s[64];
  __shared__ float kt_s[256];
  __shared__ float red_m[4][64];
  __shared__ float red_s[4][64];

  const int swz = xcd_swizzle(blockIdx.x, 3072);
  const int qtile = swz & 3, bh = swz >> 2;
  const int h = bh % NH, b = bh / NH;
  const int s0 = qtile * 64;
  const int tid = threadIdx.x, w = tid >> 6, lane = tid & 63;
  const int l15 = lane & 15, lg = lane >> 4;

  const size_t base = (size_t)(b * S) * HID + (size_t)h * DH;
  const int tb = bh * S;

  // Q fragments (B-operand): row = s0+fi*16+l15, k = lg*8 (+32)
  f16x8 qmf[4][2], qsf[4][2];
#pragma unroll
  for (int fi = 0; fi < 4; ++fi) {
    const size_t o = base + (size_t)(s0 + fi * 16 + l15) * HID + lg * 8;
    qmf[fi][0] = *reinterpret_cast<const f16x8*>(mq + o);
    qmf[fi][1] = *reinterpret_cast<const f16x8*>(mq + o + 32);
    qsf[fi][0] = *reinterpret_cast<const f16x8*>(sq + o);
    qsf[fi][1] = *reinterpret_cast<const f16x8*>(sq + o + 32);
  }
  if (tid < 64) qt_s[tid] = (s0 + tid < S) ? qterm[tb + s0 + tid] : 0.f;
  kt_s[tid] = (tid < S) ? kterm[tb + tid] : 0.f;
  __syncthreads();

  // scores^T (log2 domain): acc[fj][fi], rows = K tokens, cols = Q tokens
  f32x4 acc[4][4] = {};
  __builtin_amdgcn_s_setprio(1);
#pragma unroll
  for (int fj = 0; fj < 4; ++fj) {
    const size_t o = base + (size_t)(w * 64 + fj * 16 + l15) * HID + lg * 8;
    const f16x8 a0 = *reinterpret_cast<const f16x8*>(mk + o);
    const f16x8 a1 = *reinterpret_cast<const f16x8*>(mk + o + 32);
    const f16x8 c0 = *reinterpret_cast<const f16x8*>(sk + o);
    const f16x8 c1 = *reinterpret_cast<const f16x8*>(sk + o + 32);
#pragma unroll
    for (int fi = 0; fi < 4; ++fi) {
      acc[fj][fi] = mfma16(a0, qmf[fi][0], acc[fj][fi]);
      acc[fj][fi] = mfma16(c0, qsf[fi][0], acc[fj][fi]);
      acc[fj][fi] = mfma16(a1, qmf[fi][1], acc[fj][fi]);
      acc[fj][fi] = mfma16(c1, qsf[fi][1], acc[fj][fi]);
    }
  }
  __builtin_amdgcn_s_setprio(0);

  // transform + wave-partial row max
#pragma unroll
  for (int fi = 0; fi < 4; ++fi) {
    const float qv = qt_s[fi * 16 + l15];
    float mx = -1e30f;
#pragma unroll
    for (int fj = 0; fj < 4; ++fj)
#pragma unroll
      for (int r = 0; r < 4; ++r) {
        const int j = w * 64 + fj * 16 + lg * 4 + r;
        float sv = acc[fj][fi][r] - qv - kt_s[j];
        if (j >= S) sv = -1e30f;
        acc[fj][fi][r] = sv;
        mx = fmaxf(mx, sv);
      }
    mx = fmaxf(mx, __shfl_xor(mx, 16, 64));
    mx = fmaxf(mx, __shfl_xor(mx, 32, 64));
    if (lg == 0) red_m[w][fi * 16 + l15] = mx;
  }
  __syncthreads();

  // issue first 2 Vt slices (hide under exp phase)
  const int d = w * 16 + l15;
  const size_t vbase = ((size_t)bh * DH + d) * VSTRIDE + lg * 8;
  f16x8 vm0 = *reinterpret_cast<const f16x8*>(vtm + vbase);
  f16x8 vc0 = *reinterpret_cast<const f16x8*>(vtc + vbase);
  f16x8 vm1 = *reinterpret_cast<const f16x8*>(vtm + vbase + 32);
  f16x8 vc1 = *reinterpret_cast<const f16x8*>(vtc + vbase + 32);

  // exp2 (unnormalized) -> P (b64 writes), partial sums
#pragma unroll
  for (int fi = 0; fi < 4; ++fi) {
    const int q = fi * 16 + l15;
    const float m = fmaxf(fmaxf(red_m[0][q], red_m[1][q]),
                          fmaxf(red_m[2][q], red_m[3][q]));
    const int xr = (q & 7) << 4;
    float sum = 0.f;
#pragma unroll
    for (int fj = 0; fj < 4; ++fj) {
      f16x4 p4;
#pragma unroll
      for (int r = 0; r < 4; ++r) {
        const float e = exp2f(acc[fj][fi][r] - m);
        sum += e;
        p4[r] = (f16)e;
      }
      *reinterpret_cast<f16x4*>(
          Pb + q * 512 + ((2 * (w * 64 + fj * 16 + lg * 4)) ^ xr)) = p4;
    }
    sum += __shfl_xor(sum, 16, 64);
    sum += __shfl_xor(sum, 32, 64);
    if (lg == 0) red_s[w][q] = sum;
  }
  __syncthreads();

  // PV: A = P rows (q) from LDS, B = Vt rows (d) 2-deep JIT pipeline
  f32x4 macc[4] = {}, cacc[4] = {};
  f16x8 vmN, vcN;
#pragma unroll
  for (int ks = 0; ks < 7; ++ks) {
    if (ks + 2 < 7) {
      vmN = *reinterpret_cast<const f16x8*>(vtm + vbase + (ks + 2) * 32);
      vcN = *reinterpret_cast<const f16x8*>(vtc + vbase + (ks + 2) * 32);
    }
    __builtin_amdgcn_s_setprio(1);
#pragma unroll
    for (int fi = 0; fi < 4; ++fi) {
      const int q = fi * 16 + l15;
      const f16x8 pa = *reinterpret_cast<const f16x8*>(
          Pb + q * 512 + ((2 * (ks * 32 + lg * 8)) ^ ((q & 7) << 4)));
      macc[fi] = mfma16(pa, vm0, macc[fi]);
      const f16x8 pq = pa * pa;
      cacc[fi] = mfma16(pq, vc0, cacc[fi]);
    }
    __builtin_amdgcn_s_setprio(0);
    vm0 = vm1; vc0 = vc1;
    vm1 = vmN; vc1 = vcN;
  }

  // epilogue: normalize by row sums
#pragma unroll
  for (int fi = 0; fi < 4; ++fi)
#pragma unroll
    for (int r = 0; r < 4; ++r) {
      const int qo = fi * 16 + lg * 4 + r;
      const int srow = s0 + qo;
      if (srow < S) {
        const float tot = red_s[0][qo] + red_s[1][qo] + red_s[2][qo] + red_s[3][qo];
        const float inv = 1.f / tot;
        const size_t oidx = (size_t)(b * S + srow) * HID + h * DH + d;
        mean_ctx[oidx] = (f16)(macc[fi][r] * inv);
        cov_ctx[oidx] = (f16)(cacc[fi][r] * inv * inv);
      }
    }
}

extern "C" void kernel_launch(void* const* d_in, const int* in_sizes, int n_in,
                              void* d_out, int out_size, void* d_ws, size_t ws_size,
                              hipStream_t stream) {
  const float* in_mean = (const float*)d_in[0];
  const float* in_cov = (const float*)d_in[1];
  const float* Wmq = (const float*)d_in[2];  const float* bmq = (const float*)d_in[3];
  const float* Wcq = (const float*)d_in[4];  const float* bcq = (const float*)d_in[5];
  const float* Wmk = (const float*)d_in[6];  const float* bmk = (const float*)d_in[7];
  const float* Wck = (const float*)d_in[8];  const float* bck = (const float*)d_in[9];
  const float* Wmv = (const float*)d_in[10]; const float* bmv = (const float*)d_in[11];
  const float* Wcv = (const float*)d_in[12]; const float* bcv = (const float*)d_in[13];
  const float* Wmd = (const float*)d_in[14]; const float* bmd = (const float*)d_in[15];
  const float* Wcd = (const float*)d_in[16]; const float* bcd = (const float*)d_in[17];

  const size_t need = (2 * NPH + 8 * WSZ1 + 4 * MH + 2 * VTSZ) * sizeof(f16) +
                      2 * (size_t)BNS * sizeof(float);
  if (ws_size < need) return;

  f16* Xm = (f16*)d_ws;          // later: mean_ctx
  f16* Xc = Xm + NPH;            // later: cov_ctx
  f16* Wt = Xc + NPH;
  f16* mq = Wt + 8 * WSZ1;
  f16* mk = mq + MH;
  f16* sq = mk + MH;
  f16* sk = sq + MH;
  f16* vtm = sk + MH;
  f16* vtc = vtm + VTSZ;
  float* qterm = (float*)(vtc + VTSZ);
  float* kterm = qterm + BNS;
  f16* mean_ctx = Xm;
  f16* cov_ctx = Xc;

  float* out_mean = (float*)d_out;
  float* out_cov = out_mean + MH;

  dim3 blk(256);

  // fused prep: zero Vt+terms, cvt X, transpose W
  PrepArgs pp;
  pp.zp = (char*)vtm;
  pp.zn16 = (2 * VTSZ * sizeof(f16) + 2 * (size_t)BNS * sizeof(float)) / 16;
  pp.xm = in_mean; pp.xc = in_cov; pp.ym = Xm; pp.yc = Xc;
  pp.wp.w[0] = Wmq; pp.wp.w[1] = Wmk; pp.wp.w[2] = Wmv;
  pp.wp.w[3] = Wcq; pp.wp.w[4] = Wck; pp.wp.w[5] = Wcv;
  pp.wp.w[6] = Wmd; pp.wp.w[7] = Wcd;
  pp.wt = Wt;
  const int nz = (int)((pp.zn16 + 255) / 256);
  const int nc = (int)(NPH / 2048);
  prep_kernel<<<nz + nc + 4608, blk, 0, stream>>>(pp);

  ProjArgs pa;
  pa.A[0] = Xm; pa.A[1] = Xc;
  pa.Bt[0] = Wt; pa.Bt[1] = Wt + 3 * WSZ1;
  pa.bias[0][0] = bmq; pa.bias[0][1] = bmk; pa.bias[0][2] = bmv;
  pa.bias[1][0] = bcq; pa.bias[1][1] = bck; pa.bias[1][2] = bcv;
  pa.out0[0] = mq; pa.out0[1] = sq;
  pa.out1[0] = mk; pa.out1[1] = sk;
  pa.vt[0] = vtm; pa.vt[1] = vtc;
  pa.qterm = qterm; pa.kterm = kterm;
  gemm_proj<0><<<900, dim3(512), 0, stream>>>(pa);
  gemm_proj<1><<<900, dim3(512), 0, stream>>>(pa);

  attn_kernel<<<3072, blk, 0, stream>>>(mq, sq, mk, sk, vtm, vtc,
                                        qterm, kterm, mean_ctx, cov_ctx);

  OutArgs oa;
  oa.A[0] = mean_ctx; oa.A[1] = cov_ctx;
  oa.Bt[0] = Wt + 6 * WSZ1; oa.Bt[1] = Wt + 7 * WSZ1;
  oa.bias[0] = bmd; oa.bias[1] = bcd;
  oa.Y[0] = out_mean; oa.Y[1] = out_cov;
  gemm_out<0><<<300, dim3(512), 0, stream>>>(oa);
  gemm_out<1><<<300, dim3(512), 0, stream>>>(oa);
}

// Round 12
// 323.744 us; speedup vs baseline: 1.3188x; 1.0865x over previous
//
#include <hip/hip_runtime.h>
#include <hip/hip_bf16.h>
#include <stdint.h>

typedef _Float16 f16;
typedef _Float16 f16x8 __attribute__((ext_vector_type(8)));
typedef _Float16 f16x4 __attribute__((ext_vector_type(4)));
typedef float f32x4 __attribute__((ext_vector_type(4)));

constexpr int B = 64, S = 197, HID = 768, NH = 12, DH = 64;
constexpr int M = B * S;          // 12608
constexpr int Mpad = 12800;       // 100*128
constexpr int BNS = B * NH * S;   // 151296
constexpr int VSTRIDE = 224;      // 7*32 >= 197
constexpr size_t NPH = (size_t)Mpad * HID;
constexpr size_t MH = (size_t)M * HID;
constexpr size_t WSZ1 = (size_t)HID * HID;
constexpr size_t VTSZ = (size_t)B * NH * DH * VSTRIDE;

// 0.5 * sqrt(log2(e)) — folds the exp->exp2 conversion into the stored scale
#define QK_SCALE 0.6005612f

__device__ __forceinline__ f32x4 mfma16(f16x8 a, f16x8 b, f32x4 c) {
  return __builtin_amdgcn_mfma_f32_16x16x32_f16(a, b, c, 0, 0, 0);
}

__device__ __forceinline__ void gload16(const void* g, void* l) {
  __builtin_amdgcn_global_load_lds(
      (const __attribute__((address_space(1))) void*)g,
      (__attribute__((address_space(3))) void*)l, 16, 0, 0);
}

// bijective XCD-aware swizzle (m204)
__device__ __forceinline__ int xcd_swizzle(int wg, int nwg) {
  const int q = nwg >> 3, r = nwg & 7;
  const int x = wg & 7, p = wg >> 3;
  return (x < r ? x * (q + 1) : r * (q + 1) + (x - r) * q) + p;
}

// ---------------- fused prep: zero terms + Vt pad + cvt X + transpose W ---
struct WPtrs { const float* w[8]; };
struct PrepArgs {
  char* zp; size_t zn16;          // qterm/kterm zero region (16B units)
  char* padp;                     // vtm base (vtc contiguous after)
  const float* xm; const float* xc; f16* ym; f16* yc;
  WPtrs wp; f16* wt;
};

constexpr int PREP_NQ = 296;     // ceil(75648/256)
constexpr int PREP_NP = 1536;    // 98304 rows * 4 chunks / 256
constexpr int PREP_NC = 4800;    // NPH/2048
constexpr int PREP_NW = 4608;    // 8*24*24

__global__ __launch_bounds__(256) void prep_kernel(PrepArgs p) {
  __shared__ float tile[32][33];
  const int bid = blockIdx.x;
  if (bid < PREP_NQ) {
    const size_t i = (size_t)bid * 256 + threadIdx.x;
    if (i < p.zn16) reinterpret_cast<int4*>(p.zp)[i] = int4{0, 0, 0, 0};
  } else if (bid < PREP_NQ + PREP_NP) {
    // zero Vt pad stripes: ss in [192,224) of every [buf][bh][d] row
    const int g = (bid - PREP_NQ) * 256 + threadIdx.x;  // < 393216
    const int row = g >> 2, part = g & 3;               // row < 98304
    *reinterpret_cast<int4*>(p.padp + (size_t)row * 448 + 384 + part * 16) =
        int4{0, 0, 0, 0};
  } else if (bid < PREP_NQ + PREP_NP + PREP_NC) {
    const size_t i8 = ((size_t)(bid - PREP_NQ - PREP_NP) * 256 + threadIdx.x) * 8;
    f16x8 vm = {}, vc = {};
    if (i8 < MH) {
      const float4 a0 = *reinterpret_cast<const float4*>(p.xm + i8);
      const float4 a1 = *reinterpret_cast<const float4*>(p.xm + i8 + 4);
      const float4 b0 = *reinterpret_cast<const float4*>(p.xc + i8);
      const float4 b1 = *reinterpret_cast<const float4*>(p.xc + i8 + 4);
      vm[0] = (f16)a0.x; vm[1] = (f16)a0.y; vm[2] = (f16)a0.z; vm[3] = (f16)a0.w;
      vm[4] = (f16)a1.x; vm[5] = (f16)a1.y; vm[6] = (f16)a1.z; vm[7] = (f16)a1.w;
      vc[0] = (f16)b0.x; vc[1] = (f16)b0.y; vc[2] = (f16)b0.z; vc[3] = (f16)b0.w;
      vc[4] = (f16)b1.x; vc[5] = (f16)b1.y; vc[6] = (f16)b1.z; vc[7] = (f16)b1.w;
    }
    *reinterpret_cast<f16x8*>(p.ym + i8) = vm;
    *reinterpret_cast<f16x8*>(p.yc + i8) = vc;
  } else {
    const int t = bid - PREP_NQ - PREP_NP - PREP_NC;  // 0..4607
    const int z = t / 576;
    const int rest = t - z * 576;
    const int kx = rest / 24, ny = rest - kx * 24;
    const float* W = p.wp.w[z];
    f16* Wt = p.wt + (size_t)z * WSZ1;
    const int k0 = kx * 32, n0 = ny * 32;
    const int tx = threadIdx.x & 31, ty = threadIdx.x >> 5;
#pragma unroll
    for (int i = 0; i < 4; ++i)
      tile[ty + i * 8][tx] = W[(size_t)(k0 + ty + i * 8) * HID + n0 + tx];
    __syncthreads();
#pragma unroll
    for (int i = 0; i < 4; ++i)
      Wt[(size_t)(n0 + ty + i * 8) * HID + k0 + tx] = (f16)tile[tx][ty + i * 8];
  }
}

// ---------------- MFMA GEMM core (128x256 tile, 512 thr, K=768) -----------
// r9/r10 core, unchanged: BK=32, 3 LDS buffers, counted-vmcnt pipeline,
// verified 0-conflict slot swizzle.
__device__ __forceinline__ void gemm_core(
    const f16* __restrict__ Abase, const f16* __restrict__ Btbase,
    int m0, int n0, int tid, char* lds, f32x4 (&acc)[4][4]) {
  const int w = tid >> 6, lane = tid & 63;
  const int l15 = lane & 15, lg = lane >> 4;
  const int wr = (w >> 2) * 64, wc = (w & 3) * 64;

  const int arow = w * 16 + (lane >> 2);
  const int brow = w * 32 + (lane >> 2);
  const int scol = (((lane & 3) ^ ((lane >> 3) & 3)) * 16);  // pre-swizzled src
  const char* gA = reinterpret_cast<const char*>(Abase + (size_t)(m0 + arow) * HID) + scol;
  const char* gB = reinterpret_cast<const char*>(Btbase + (size_t)(n0 + brow) * HID) + scol;

  const int rslot = ((lg ^ (l15 >> 1)) & 3) * 16;

#define STAGE_TILE(T, BUF)                                               \
  do {                                                                   \
    const size_t off_ = (size_t)(T) * 64;                                \
    char* bp_ = lds + (BUF) * 24576;                                     \
    gload16(gA + off_, bp_ + w * 1024);                                  \
    gload16(gB + off_, bp_ + 8192 + w * 2048);                           \
    gload16(gB + off_ + (size_t)16 * 1536, bp_ + 8192 + w * 2048 + 1024);\
  } while (0)

  STAGE_TILE(0, 0);
  STAGE_TILE(1, 1);
  asm volatile("s_waitcnt vmcnt(3)\n\ts_barrier" ::: "memory");

#pragma unroll
  for (int t = 0; t < 24; ++t) {
    if (t + 2 < 24) STAGE_TILE(t + 2, (t + 2) % 3);

    const char* cb = lds + (t % 3) * 24576;
    f16x8 af[4], bf[4];
#pragma unroll
    for (int fi = 0; fi < 4; ++fi)
      af[fi] = *reinterpret_cast<const f16x8*>(cb + (wr + l15 + fi * 16) * 64 + rslot);
#pragma unroll
    for (int fj = 0; fj < 4; ++fj)
      bf[fj] = *reinterpret_cast<const f16x8*>(
          cb + 8192 + (wc + l15 + fj * 16) * 64 + rslot);

    __builtin_amdgcn_s_setprio(1);
#pragma unroll
    for (int fi = 0; fi < 4; ++fi)
#pragma unroll
      for (int fj = 0; fj < 4; ++fj)
        acc[fi][fj] = mfma16(af[fi], bf[fj], acc[fi][fj]);
    __builtin_amdgcn_s_setprio(0);

    if (t + 2 < 24) {
      asm volatile("s_waitcnt vmcnt(3)\n\ts_barrier" ::: "memory");
    } else if (t + 1 < 24) {
      asm volatile("s_waitcnt vmcnt(0)\n\ts_barrier" ::: "memory");
    }
  }
#undef STAGE_TILE
}

// ---------------- projection GEMMs, merged z (XCD-chunk keeps z pure) -----
struct ProjArgs {
  const f16* A[2]; const f16* Bt[2];
  const float* bias[2][3];
  f16* out0[2];  // nsel 0: mq / sq   (scaled QK_SCALE, M rows)
  f16* out1[2];  // nsel 1: mk / sk   (scaled QK_SCALE, M rows)
  f16* vt[2];    // nsel 2: Vt mean / cov (transposed, unscaled)
  float* qterm; float* kterm;  // fused row sums (atomic)
};

__global__ __launch_bounds__(512, 2) void gemm_proj(ProjArgs g) {
  __shared__ alignas(16) char lds[73728];
  const int swz = xcd_swizzle(blockIdx.x, 1800);
  const int z = swz / 900;                 // XCDs 0-3 -> z=0, 4-7 -> z=1
  const int rest = swz - z * 900;
  const int x = rest / 9, y = rest - x * 9;  // y fastest: A panel L2-reuse
  const int m0 = x * 128, n0 = y * 256;

  f32x4 acc[4][4] = {};
  gemm_core(g.A[z], g.Bt[z], m0, n0, threadIdx.x, lds, acc);

  const int tid = threadIdx.x, w = tid >> 6, lane = tid & 63;
  const int l15 = lane & 15, lg = lane >> 4;
  const int wr = (w >> 2) * 64, wc = (w & 3) * 64;
  const int nsel = n0 / 768;
  const int colbase = (n0 - nsel * 768) + wc;  // multiple of 64
  const int rbase = m0 + wr + lg * 4;
  const float* bias = g.bias[z][nsel];

  if (nsel < 2) {
    const int hh = colbase >> 6;
    f16* Y = nsel ? g.out1[z] : g.out0[z];
    float* term = nsel ? g.kterm : g.qterm;
    float bv4[4];
#pragma unroll
    for (int fj = 0; fj < 4; ++fj) bv4[fj] = bias[colbase + l15 + fj * 16];
#pragma unroll
    for (int fi = 0; fi < 4; ++fi) {
#pragma unroll
      for (int r = 0; r < 4; ++r) {
        const int row = rbase + fi * 16 + r;
        float ssum = 0.f;
#pragma unroll
        for (int fj = 0; fj < 4; ++fj) {
          float v = acc[fi][fj][r] + bv4[fj];
          if (z == 1) { v = (v > 0.f) ? v + 1.f : __expf(v); v = sqrtf(v); }
          const f16 st = (f16)(v * QK_SCALE);
          if (row < M) Y[(size_t)row * HID + colbase + l15 + fj * 16] = st;
          const float sf = (float)st;
          ssum = fmaf(sf, sf, ssum);
        }
        ssum += __shfl_xor(ssum, 1, 64);
        ssum += __shfl_xor(ssum, 2, 64);
        ssum += __shfl_xor(ssum, 4, 64);
        ssum += __shfl_xor(ssum, 8, 64);
        if (l15 == 0 && row < M) {
          const int bb = row / S, ss = row - bb * S;
          atomicAdd(&term[(bb * NH + hh) * S + ss], 0.5f * ssum);
        }
      }
    }
  } else {
    // ---- V projection: transpose through LDS, coalesced ss-major stores ----
    f16* VT = g.vt[z];
    f16* LT = reinterpret_cast<f16*>(lds);  // LT[col][136], 256x136 f16 = 68KB
    __syncthreads();  // gemm_core LDS reads done block-wide
#pragma unroll
    for (int fj = 0; fj < 4; ++fj) {
      const int c = wc + l15 + fj * 16;               // local col 0..255
      const float bv = bias[colbase - wc + c];        // bias[col in 0..767]
#pragma unroll
      for (int fi = 0; fi < 4; ++fi)
#pragma unroll
        for (int r = 0; r < 4; ++r) {
          float v = acc[fi][fj][r] + bv;
          if (z == 1) v = (v > 0.f) ? v + 1.f : __expf(v);
          const int row_local = wr + lg * 4 + fi * 16 + r;  // 0..127
          LT[(size_t)c * 136 + row_local] = (f16)v;
        }
    }
    __syncthreads();
    const int rh = w >> 2;            // row half 0/1
    const int cw = w & 3;             // col quarter
    const int row_local = rh * 64 + lane;
    const int grow = m0 + row_local;
    if (grow < M) {
      const int bb = grow / S;
      const int ss = grow - bb * S;
      const int vb = n0 - 1536;  // V-col base of this block (0,256,512)
#pragma unroll 8
      for (int k = 0; k < 64; ++k) {
        const int c = cw * 64 + k;            // local col
        const int vcol = vb + c;
        const int hh = vcol >> 6, dd = vcol & 63;
        const f16 v = LT[(size_t)c * 136 + row_local];
        VT[((size_t)(bb * NH + hh) * DH + dd) * VSTRIDE + ss] = v;
      }
    }
  }
}

// ---------------- output GEMMs, merged z, f32 out ---------------
struct OutArgs {
  const f16* A[2]; const f16* Bt[2]; const float* bias[2]; float* Y[2];
};

__global__ __launch_bounds__(512, 2) void gemm_out(OutArgs g) {
  __shared__ alignas(16) char lds[73728];
  const int swz = xcd_swizzle(blockIdx.x, 600);
  const int z = swz / 300;                 // XCDs 0-3 -> z=0, 4-7 -> z=1
  const int rest = swz - z * 300;
  const int x = rest / 3, y = rest - x * 3;
  const int m0 = x * 128, n0 = y * 256;

  f32x4 acc[4][4] = {};
  gemm_core(g.A[z], g.Bt[z], m0, n0, threadIdx.x, lds, acc);

  const int tid = threadIdx.x, w = tid >> 6, lane = tid & 63;
  const int l15 = lane & 15, lg = lane >> 4;
  const int wr = (w >> 2) * 64, wc = (w & 3) * 64;
  const int rbase = m0 + wr + lg * 4;
  float* Y = g.Y[z];
#pragma unroll
  for (int fj = 0; fj < 4; ++fj) {
    const int col = n0 + wc + l15 + fj * 16;
    const float bv = g.bias[z][col];
#pragma unroll
    for (int fi = 0; fi < 4; ++fi)
#pragma unroll
      for (int r = 0; r < 4; ++r) {
        const int row = rbase + fi * 16 + r;
        if (row < M) Y[(size_t)row * HID + col] = acc[fi][fj][r] + bv;
      }
  }
}

// ---------------- fused Wasserstein attention ----------------
__global__ __launch_bounds__(256, 2) void attn_kernel(
    const f16* __restrict__ mq, const f16* __restrict__ sq,
    const f16* __restrict__ mk, const f16* __restrict__ sk,
    const f16* __restrict__ vtm, const f16* __restrict__ vtc,
    const float* __restrict__ qterm, const float* __restrict__ kterm,
    f16* __restrict__ mean_ctx, f16* __restrict__ cov_ctx) {
  __shared__ char Pb[64 * 512];  // P[q][j] f16, XOR-swizzled rows
  __shared__ float qt_s[64];
  __shared__ float kt_s[256];
  __shared__ float red_m[4][64];
  __shared__ float red_s[4][64];

  const int swz = xcd_swizzle(blockIdx.x, 3072);
  const int qtile = swz & 3, bh = swz >> 2;
  const int h = bh % NH, b = bh / NH;
  const int s0 = qtile * 64;
  const int tid = threadIdx.x, w = tid >> 6, lane = tid & 63;
  const int l15 = lane & 15, lg = lane >> 4;

  const size_t base = (size_t)(b * S) * HID + (size_t)h * DH;
  const int tb = bh * S;

  // Q fragments (B-operand): row = s0+fi*16+l15, k = lg*8 (+32)
  f16x8 qmf[4][2], qsf[4][2];
#pragma unroll
  for (int fi = 0; fi < 4; ++fi) {
    const size_t o = base + (size_t)(s0 + fi * 16 + l15) * HID + lg * 8;
    qmf[fi][0] = *reinterpret_cast<const f16x8*>(mq + o);
    qmf[fi][1] = *reinterpret_cast<const f16x8*>(mq + o + 32);
    qsf[fi][0] = *reinterpret_cast<const f16x8*>(sq + o);
    qsf[fi][1] = *reinterpret_cast<const f16x8*>(sq + o + 32);
  }
  if (tid < 64) qt_s[tid] = (s0 + tid < S) ? qterm[tb + s0 + tid] : 0.f;
  kt_s[tid] = (tid < S) ? kterm[tb + tid] : 0.f;
  __syncthreads();

  // scores^T (log2 domain): acc[fj][fi], rows = K tokens, cols = Q tokens
  f32x4 acc[4][4] = {};
  __builtin_amdgcn_s_setprio(1);
#pragma unroll
  for (int fj = 0; fj < 4; ++fj) {
    const size_t o = base + (size_t)(w * 64 + fj * 16 + l15) * HID + lg * 8;
    const f16x8 a0 = *reinterpret_cast<const f16x8*>(mk + o);
    const f16x8 a1 = *reinterpret_cast<const f16x8*>(mk + o + 32);
    const f16x8 c0 = *reinterpret_cast<const f16x8*>(sk + o);
    const f16x8 c1 = *reinterpret_cast<const f16x8*>(sk + o + 32);
#pragma unroll
    for (int fi = 0; fi < 4; ++fi) {
      acc[fj][fi] = mfma16(a0, qmf[fi][0], acc[fj][fi]);
      acc[fj][fi] = mfma16(c0, qsf[fi][0], acc[fj][fi]);
      acc[fj][fi] = mfma16(a1, qmf[fi][1], acc[fj][fi]);
      acc[fj][fi] = mfma16(c1, qsf[fi][1], acc[fj][fi]);
    }
  }
  __builtin_amdgcn_s_setprio(0);

  // transform + wave-partial row max
#pragma unroll
  for (int fi = 0; fi < 4; ++fi) {
    const float qv = qt_s[fi * 16 + l15];
    float mx = -1e30f;
#pragma unroll
    for (int fj = 0; fj < 4; ++fj)
#pragma unroll
      for (int r = 0; r < 4; ++r) {
        const int j = w * 64 + fj * 16 + lg * 4 + r;
        float sv = acc[fj][fi][r] - qv - kt_s[j];
        if (j >= S) sv = -1e30f;
        acc[fj][fi][r] = sv;
        mx = fmaxf(mx, sv);
      }
    mx = fmaxf(mx, __shfl_xor(mx, 16, 64));
    mx = fmaxf(mx, __shfl_xor(mx, 32, 64));
    if (lg == 0) red_m[w][fi * 16 + l15] = mx;
  }
  __syncthreads();

  // issue first 2 Vt slices (hide under exp phase)
  const int d = w * 16 + l15;
  const size_t vbase = ((size_t)bh * DH + d) * VSTRIDE + lg * 8;
  f16x8 vm0 = *reinterpret_cast<const f16x8*>(vtm + vbase);
  f16x8 vc0 = *reinterpret_cast<const f16x8*>(vtc + vbase);
  f16x8 vm1 = *reinterpret_cast<const f16x8*>(vtm + vbase + 32);
  f16x8 vc1 = *reinterpret_cast<const f16x8*>(vtc + vbase + 32);

  // exp2 (unnormalized) -> P (b64 writes), partial sums
#pragma unroll
  for (int fi = 0; fi < 4; ++fi) {
    const int q = fi * 16 + l15;
    const float m = fmaxf(fmaxf(red_m[0][q], red_m[1][q]),
                          fmaxf(red_m[2][q], red_m[3][q]));
    const int xr = (q & 7) << 4;
    float sum = 0.f;
#pragma unroll
    for (int fj = 0; fj < 4; ++fj) {
      f16x4 p4;
#pragma unroll
      for (int r = 0; r < 4; ++r) {
        const float e = exp2f(acc[fj][fi][r] - m);
        sum += e;
        p4[r] = (f16)e;
      }
      *reinterpret_cast<f16x4*>(
          Pb + q * 512 + ((2 * (w * 64 + fj * 16 + lg * 4)) ^ xr)) = p4;
    }
    sum += __shfl_xor(sum, 16, 64);
    sum += __shfl_xor(sum, 32, 64);
    if (lg == 0) red_s[w][q] = sum;
  }
  __syncthreads();

  // PV: A = P rows (q) from LDS, B = Vt rows (d) 2-deep JIT pipeline
  f32x4 macc[4] = {}, cacc[4] = {};
  f16x8 vmN, vcN;
#pragma unroll
  for (int ks = 0; ks < 7; ++ks) {
    if (ks + 2 < 7) {
      vmN = *reinterpret_cast<const f16x8*>(vtm + vbase + (ks + 2) * 32);
      vcN = *reinterpret_cast<const f16x8*>(vtc + vbase + (ks + 2) * 32);
    }
    __builtin_amdgcn_s_setprio(1);
#pragma unroll
    for (int fi = 0; fi < 4; ++fi) {
      const int q = fi * 16 + l15;
      const f16x8 pa = *reinterpret_cast<const f16x8*>(
          Pb + q * 512 + ((2 * (ks * 32 + lg * 8)) ^ ((q & 7) << 4)));
      macc[fi] = mfma16(pa, vm0, macc[fi]);
      const f16x8 pq = pa * pa;
      cacc[fi] = mfma16(pq, vc0, cacc[fi]);
    }
    __builtin_amdgcn_s_setprio(0);
    vm0 = vm1; vc0 = vc1;
    vm1 = vmN; vc1 = vcN;
  }

  // epilogue: normalize by row sums
#pragma unroll
  for (int fi = 0; fi < 4; ++fi)
#pragma unroll
    for (int r = 0; r < 4; ++r) {
      const int qo = fi * 16 + lg * 4 + r;
      const int srow = s0 + qo;
      if (srow < S) {
        const float tot = red_s[0][qo] + red_s[1][qo] + red_s[2][qo] + red_s[3][qo];
        const float inv = 1.f / tot;
        const size_t oidx = (size_t)(b * S + srow) * HID + h * DH + d;
        mean_ctx[oidx] = (f16)(macc[fi][r] * inv);
        cov_ctx[oidx] = (f16)(cacc[fi][r] * inv * inv);
      }
    }
}

extern "C" void kernel_launch(void* const* d_in, const int* in_sizes, int n_in,
                              void* d_out, int out_size, void* d_ws, size_t ws_size,
                              hipStream_t stream) {
  const float* in_mean = (const float*)d_in[0];
  const float* in_cov = (const float*)d_in[1];
  const float* Wmq = (const float*)d_in[2];  const float* bmq = (const float*)d_in[3];
  const float* Wcq = (const float*)d_in[4];  const float* bcq = (const float*)d_in[5];
  const float* Wmk = (const float*)d_in[6];  const float* bmk = (const float*)d_in[7];
  const float* Wck = (const float*)d_in[8];  const float* bck = (const float*)d_in[9];
  const float* Wmv = (const float*)d_in[10]; const float* bmv = (const float*)d_in[11];
  const float* Wcv = (const float*)d_in[12]; const float* bcv = (const float*)d_in[13];
  const float* Wmd = (const float*)d_in[14]; const float* bmd = (const float*)d_in[15];
  const float* Wcd = (const float*)d_in[16]; const float* bcd = (const float*)d_in[17];

  const size_t need = (2 * NPH + 8 * WSZ1 + 4 * MH + 2 * VTSZ) * sizeof(f16) +
                      2 * (size_t)BNS * sizeof(float);
  if (ws_size < need) return;

  f16* Xm = (f16*)d_ws;          // later: mean_ctx
  f16* Xc = Xm + NPH;            // later: cov_ctx
  f16* Wt = Xc + NPH;
  f16* mq = Wt + 8 * WSZ1;
  f16* mk = mq + MH;
  f16* sq = mk + MH;
  f16* sk = sq + MH;
  f16* vtm = sk + MH;
  f16* vtc = vtm + VTSZ;
  float* qterm = (float*)(vtc + VTSZ);
  float* kterm = qterm + BNS;
  f16* mean_ctx = Xm;
  f16* cov_ctx = Xc;

  float* out_mean = (float*)d_out;
  float* out_cov = out_mean + MH;

  dim3 blk(256);

  // fused prep: zero qterm/kterm + Vt pad stripes, cvt X, transpose W
  PrepArgs pp;
  pp.zp = (char*)qterm;
  pp.zn16 = (2 * (size_t)BNS * sizeof(float)) / 16;  // 75648
  pp.padp = (char*)vtm;
  pp.xm = in_mean; pp.xc = in_cov; pp.ym = Xm; pp.yc = Xc;
  pp.wp.w[0] = Wmq; pp.wp.w[1] = Wmk; pp.wp.w[2] = Wmv;
  pp.wp.w[3] = Wcq; pp.wp.w[4] = Wck; pp.wp.w[5] = Wcv;
  pp.wp.w[6] = Wmd; pp.wp.w[7] = Wcd;
  pp.wt = Wt;
  prep_kernel<<<PREP_NQ + PREP_NP + PREP_NC + PREP_NW, blk, 0, stream>>>(pp);

  ProjArgs pa;
  pa.A[0] = Xm; pa.A[1] = Xc;
  pa.Bt[0] = Wt; pa.Bt[1] = Wt + 3 * WSZ1;
  pa.bias[0][0] = bmq; pa.bias[0][1] = bmk; pa.bias[0][2] = bmv;
  pa.bias[1][0] = bcq; pa.bias[1][1] = bck; pa.bias[1][2] = bcv;
  pa.out0[0] = mq; pa.out0[1] = sq;
  pa.out1[0] = mk; pa.out1[1] = sk;
  pa.vt[0] = vtm; pa.vt[1] = vtc;
  pa.qterm = qterm; pa.kterm = kterm;
  gemm_proj<<<1800, dim3(512), 0, stream>>>(pa);

  attn_kernel<<<3072, blk, 0, stream>>>(mq, sq, mk, sk, vtm, vtc,
                                        qterm, kterm, mean_ctx, cov_ctx);

  OutArgs oa;
  oa.A[0] = mean_ctx; oa.A[1] = cov_ctx;
  oa.Bt[0] = Wt + 6 * WSZ1; oa.Bt[1] = Wt + 7 * WSZ1;
  oa.bias[0] = bmd; oa.bias[1] = bcd;
  oa.Y[0] = out_mean; oa.Y[1] = out_cov;
  gemm_out<<<600, dim3(512), 0, stream>>>(oa);
}